// Round 1
// baseline (7531.783 us; speedup 1.0000x reference)
//
#include <hip/hip_runtime.h>
#include <cstddef>

// ---------------------------------------------------------------------------
// FPNIoUNetHR forward — fp32 correctness-first implementation.
// S=64 seqs, C=256 ch, H=W=36, N=16 proposals.
// ---------------------------------------------------------------------------

static __device__ __forceinline__ float hat_int(float x) {
  float u = fminf(1.f, fmaxf(-1.f, x));
  float a = 0.5f * (1.f + u) * (1.f + u);
  float b = 0.5f + u - 0.5f * u * u;
  return (u <= 0.f) ? a : b;
}

// ---- repack conv weights [OC=256][C=256][3][3] -> wT[(t*256+c)*256 + oc] ---
__global__ void k_repack(const float* __restrict__ w, float* __restrict__ wT) {
  int i = blockIdx.x * 256 + threadIdx.x;   // i < 2304*256
  int oc = i & 255;
  int k  = i >> 8;        // t*256 + c
  int t  = k >> 8;
  int c  = k & 255;
  wT[i] = w[(oc * 256 + c) * 9 + t];
}

// ---- 3x3 conv (pad 1) as implicit GEMM: y[s][oc][hw] = conv + bias --------
// grid (21 p-tiles, 4 oc-tiles, 64 images), 256 threads, 64x64 tile, 4x4/thr
__global__ __launch_bounds__(256) void k_conv3x3(
    const float* __restrict__ feat, const float* __restrict__ wT,
    const float* __restrict__ bias, float* __restrict__ y) {
  const int s  = blockIdx.z;
  const int m0 = blockIdx.y * 64;
  const int p0 = blockIdx.x * 64;
  const int tid = threadIdx.x;
  const int lk = tid >> 6;        // 0..3
  const int lp = tid & 63;        // 0..63
  const int tx = tid & 15, ty = tid >> 4;
  __shared__ float As[16][64];
  __shared__ float Bs[16][64];
  float acc[4][4] = {};
  const int p = p0 + lp;
  const int h = p / 36, w0 = p % 36;
  const float* fs = feat + (size_t)s * 256 * 1296;
  for (int t = 0; t < 9; ++t) {
    const int ih = h + t / 3 - 1;
    const int iw = w0 + t % 3 - 1;
    const bool ok = (p < 1296) & ((unsigned)ih < 36u) & ((unsigned)iw < 36u);
    const int baddr = ih * 36 + iw;
    const float* wb = wT + (size_t)t * 256 * 256 + m0;
    for (int cb = 0; cb < 256; cb += 16) {
#pragma unroll
      for (int r = 0; r < 4; ++r) {
        int kk = lk * 4 + r;
        As[kk][lp] = wb[(size_t)(cb + kk) * 256 + lp];
        Bs[kk][lp] = ok ? fs[(size_t)(cb + kk) * 1296 + baddr] : 0.f;
      }
      __syncthreads();
#pragma unroll
      for (int kk = 0; kk < 16; ++kk) {
        float4 a4 = *reinterpret_cast<const float4*>(&As[kk][ty * 4]);
        float4 b4 = *reinterpret_cast<const float4*>(&Bs[kk][tx * 4]);
        float av[4] = {a4.x, a4.y, a4.z, a4.w};
        float bv[4] = {b4.x, b4.y, b4.z, b4.w};
#pragma unroll
        for (int i = 0; i < 4; ++i)
#pragma unroll
          for (int j = 0; j < 4; ++j)
            acc[i][j] = fmaf(av[i], bv[j], acc[i][j]);
      }
      __syncthreads();
    }
  }
#pragma unroll
  for (int i = 0; i < 4; ++i) {
    const int oc = m0 + ty * 4 + i;
    const float b = bias[oc];
    float* yo = y + ((size_t)s * 256 + oc) * 1296;
#pragma unroll
    for (int j = 0; j < 4; ++j) {
      int pp = p0 + tx * 4 + j;
      if (pp < 1296) yo[pp] = acc[i][j] + b;
    }
  }
}

// ---- per-channel BN stats over (s, hw): 256 blocks, one channel each ------
__global__ void k_chan_stats(const float* __restrict__ y,
                             float* __restrict__ mean, float* __restrict__ istd) {
  const int c = blockIdx.x, tid = threadIdx.x;
  float s = 0.f, ss = 0.f;
  for (int img = 0; img < 64; ++img) {
    const float* p = y + ((size_t)img * 256 + c) * 1296;
    for (int i = tid; i < 1296; i += 256) { float v = p[i]; s += v; ss += v * v; }
  }
  __shared__ float rs[256], rss[256];
  rs[tid] = s; rss[tid] = ss;
  __syncthreads();
  for (int o = 128; o > 0; o >>= 1) {
    if (tid < o) { rs[tid] += rs[tid + o]; rss[tid] += rss[tid + o]; }
    __syncthreads();
  }
  if (tid == 0) {
    float m = rs[0] * (1.f / 82944.f);
    float var = rss[0] * (1.f / 82944.f) - m * m;
    mean[c] = m;
    istd[c] = rsqrtf(var + 1e-5f);
  }
}

// ---- BN+ReLU elementwise on conv tensor (float4, in place) ----------------
__global__ void k_bn_relu_conv(float* __restrict__ y, const float* __restrict__ mean,
                               const float* __restrict__ istd, const float* __restrict__ g,
                               const float* __restrict__ be) {
  int i = blockIdx.x * 256 + threadIdx.x;   // float4 index; grid exact
  int c = (i / 324) & 255;
  float sc = istd[c] * g[c];
  float sh = be[c] - mean[c] * sc;
  float4 v = reinterpret_cast<float4*>(y)[i];
  v.x = fmaxf(fmaf(v.x, sc, sh), 0.f);
  v.y = fmaxf(fmaf(v.y, sc, sh), 0.f);
  v.z = fmaxf(fmaf(v.z, sc, sh), 0.f);
  v.w = fmaxf(fmaf(v.w, sc, sh), 0.f);
  reinterpret_cast<float4*>(y)[i] = v;
}

// ---- PrRoI separable weights: one thread per roi --------------------------
__global__ void k_wxy(const float* __restrict__ rois, int ntot, int P,
                      float* __restrict__ Wx, float* __restrict__ Wy,
                      float* __restrict__ area) {
  int idx = blockIdx.x * blockDim.x + threadIdx.x;
  if (idx >= ntot) return;
  float rx = rois[idx * 4 + 0], ry = rois[idx * 4 + 1];
  float rw = rois[idx * 4 + 2], rh = rois[idx * 4 + 3];
  float x1 = rx * 0.125f, y1 = ry * 0.125f;
  float x2 = (rx + rw) * 0.125f, y2 = (ry + rh) * 0.125f;
  float bw = (x2 - x1) / P, bh = (y2 - y1) / P;
  area[idx] = bw * bh;
  for (int q = 0; q < P; ++q) {
    float xlo = x1 + q * bw, ylo = y1 + q * bh;
    for (int g = 0; g < 36; ++g) {
      float fg = (float)g;
      Wx[(idx * P + q) * 36 + g] = hat_int(xlo + bw - fg) - hat_int(xlo - fg);
      Wy[(idx * P + q) * 36 + g] = hat_int(ylo + bh - fg) - hat_int(ylo - fg);
    }
  }
}

// ---- PrRoI pool: block=(s,n), thread=channel ------------------------------
// MOD=false: out[s*6400 + c*25 + p*5 + q]        (feeds f1r GEMM)
// MOD=true : out[(s*16+n)*12544 + c*49 + p*7 + q] * modulation[s][c]
template <int P, bool MOD>
__global__ __launch_bounds__(256) void k_pool(
    const float* __restrict__ feat, const float* __restrict__ Wx,
    const float* __restrict__ Wy, const float* __restrict__ area,
    const float* __restrict__ mod, float* __restrict__ out, int N) {
  const int s = blockIdx.x, n = blockIdx.y;
  const int idx = s * N + n;
  const int c = threadIdx.x;
  __shared__ float sWx[P * 36], sWy[P * 36];
  for (int i = threadIdx.x; i < P * 36; i += 256) {
    sWx[i] = Wx[(size_t)idx * P * 36 + i];
    sWy[i] = Wy[(size_t)idx * P * 36 + i];
  }
  __syncthreads();
  const float* f = feat + ((size_t)s * 256 + c) * 1296;
  float o[P][P];
#pragma unroll
  for (int a = 0; a < P; ++a)
#pragma unroll
    for (int b = 0; b < P; ++b) o[a][b] = 0.f;
  for (int h = 0; h < 36; ++h) {
    float row[36];
#pragma unroll
    for (int w = 0; w < 36; ++w) row[w] = f[h * 36 + w];
    float colsum[P];
#pragma unroll
    for (int q = 0; q < P; ++q) {
      float v = 0.f;
#pragma unroll
      for (int w = 0; w < 36; ++w) v = fmaf(sWx[q * 36 + w], row[w], v);
      colsum[q] = v;
    }
#pragma unroll
    for (int p = 0; p < P; ++p) {
      float wy = sWy[p * 36 + h];
#pragma unroll
      for (int q = 0; q < P; ++q) o[p][q] = fmaf(wy, colsum[q], o[p][q]);
    }
  }
  float a = area[idx];
  float inv = (a > 0.f) ? 1.f / fmaxf(a, 1e-12f) : 0.f;
  float msc;
  if (MOD) msc = mod[s * 256 + c] * inv; else msc = inv;
  if (MOD) {
    float* op = out + (size_t)idx * 12544 + c * 49;
#pragma unroll
    for (int p = 0; p < P; ++p)
#pragma unroll
      for (int q = 0; q < P; ++q) op[p * P + q] = o[p][q] * msc;
  } else {
    float* op = out + (size_t)s * 6400 + c * 25;
#pragma unroll
    for (int p = 0; p < P; ++p)
#pragma unroll
      for (int q = 0; q < P; ++q) op[p * P + q] = o[p][q] * msc;
  }
}

// ---- generic fp32 GEMM: out[m][n] = sum_k A[m][k]*B[n][k] + bias[n] -------
// grid (N/64, M/64), 256 threads, 64x64 tile, BK=16, 4x4/thr
__global__ __launch_bounds__(256) void k_gemm(
    const float* __restrict__ A, const float* __restrict__ B,
    const float* __restrict__ bias, float* __restrict__ out, int K, int N) {
  const int n0 = blockIdx.x * 64;
  const int m0 = blockIdx.y * 64;
  const int tid = threadIdx.x;
  const int lk = tid & 15;
  const int lr = tid >> 4;
  const int tx = tid & 15, ty = tid >> 4;
  __shared__ float As[16][68];
  __shared__ float Bs[16][68];
  float acc[4][4] = {};
  for (int kb = 0; kb < K; kb += 16) {
#pragma unroll
    for (int r = 0; r < 4; ++r) {
      As[lk][r * 16 + lr] = A[(size_t)(m0 + r * 16 + lr) * K + kb + lk];
      Bs[lk][r * 16 + lr] = B[(size_t)(n0 + r * 16 + lr) * K + kb + lk];
    }
    __syncthreads();
#pragma unroll
    for (int kk = 0; kk < 16; ++kk) {
      float4 a4 = *reinterpret_cast<const float4*>(&As[kk][ty * 4]);
      float4 b4 = *reinterpret_cast<const float4*>(&Bs[kk][tx * 4]);
      float av[4] = {a4.x, a4.y, a4.z, a4.w};
      float bv[4] = {b4.x, b4.y, b4.z, b4.w};
#pragma unroll
      for (int i = 0; i < 4; ++i)
#pragma unroll
        for (int j = 0; j < 4; ++j)
          acc[i][j] = fmaf(av[i], bv[j], acc[i][j]);
    }
    __syncthreads();
  }
#pragma unroll
  for (int i = 0; i < 4; ++i) {
    float* op = out + (size_t)(m0 + ty * 4 + i) * N + n0;
#pragma unroll
    for (int j = 0; j < 4; ++j)
      op[tx * 4 + j] = acc[i][j] + bias[n0 + tx * 4 + j];
  }
}

// ---- FC BN stats over batch dim: one thread per column --------------------
__global__ void k_fc_stats(const float* __restrict__ y, int M, int Nf,
                           float* __restrict__ mean, float* __restrict__ istd) {
  int col = blockIdx.x * 256 + threadIdx.x;
  if (col >= Nf) return;
  float s = 0.f, ss = 0.f;
  for (int m = 0; m < M; ++m) {
    float v = y[(size_t)m * Nf + col];
    s += v; ss += v * v;
  }
  float mu = s / (float)M;
  float var = ss / (float)M - mu * mu;
  mean[col] = mu;
  istd[col] = rsqrtf(var + 1e-5f);
}

// ---- FC BN+ReLU elementwise (in place) ------------------------------------
__global__ void k_fc_bn_relu(float* __restrict__ y, const float* __restrict__ mean,
                             const float* __restrict__ istd, const float* __restrict__ g,
                             const float* __restrict__ be, int total, int Nf) {
  int i = blockIdx.x * 256 + threadIdx.x;
  if (i >= total) return;
  int col = i % Nf;
  float sc = istd[col] * g[col];
  float sh = be[col] - mean[col] * sc;
  y[i] = fmaxf(fmaf(y[i], sc, sh), 0.f);
}

// ---- IoU head: out[r] = dot(x[r], w) + b ----------------------------------
__global__ void k_iou(const float* __restrict__ x, const float* __restrict__ w,
                      const float* __restrict__ b, float* __restrict__ out) {
  const int r = blockIdx.x, tid = threadIdx.x;
  float s = 0.f;
  for (int k = tid; k < 1024; k += 256) s = fmaf(x[(size_t)r * 1024 + k], w[k], s);
  __shared__ float red[256];
  red[tid] = s;
  __syncthreads();
  for (int o = 128; o > 0; o >>= 1) {
    if (tid < o) red[tid] += red[tid + o];
    __syncthreads();
  }
  if (tid == 0) out[r] = red[0] + b[0];
}

// ---------------------------------------------------------------------------
// Workspace layout (float offsets)
// ---------------------------------------------------------------------------
static const size_t O_A    = 0;          // 21,233,664  conv buf / X
static const size_t O_B    = 21233664;   // 21,233,664  conv buf
static const size_t O_WT   = 42467328;   //    589,824  repacked conv weights
static const size_t O_PR   = 43057152;   //    409,600  pooled_r [64][6400]
static const size_t O_Y1   = 43466752;   //  1,048,576  fc buf 1
static const size_t O_Y2   = 44515328;   //  1,048,576  fc buf 2
static const size_t O_MOD  = 45563904;   //     16,384  modulation [64][256]
static const size_t O_WXR  = 45580288;   //     11,520
static const size_t O_WYR  = 45591808;   //     11,520
static const size_t O_ARR  = 45603328;   //         64
static const size_t O_WXT  = 45603392;   //    258,048
static const size_t O_WYT  = 45861440;   //    258,048
static const size_t O_ART  = 46119488;   //      1,024
static const size_t O_MEAN = 46120512;   //      1,024
static const size_t O_ISTD = 46121536;   //      1,024
// total 46,122,560 floats = 184.5 MB

extern "C" void kernel_launch(void* const* d_in, const int* in_sizes, int n_in,
                              void* d_out, int out_size, void* d_ws, size_t ws_size,
                              hipStream_t stream) {
  (void)in_sizes; (void)n_in; (void)out_size; (void)ws_size;
  const float* feat1  = (const float*)d_in[0];
  const float* feat2  = (const float*)d_in[1];
  const float* bb1    = (const float*)d_in[2];
  const float* props  = (const float*)d_in[3];
  const float* w_c1r  = (const float*)d_in[4];
  const float* b_c1r  = (const float*)d_in[5];
  const float* g_c1r  = (const float*)d_in[6];
  const float* be_c1r = (const float*)d_in[7];
  const float* w_c1t  = (const float*)d_in[8];
  const float* b_c1t  = (const float*)d_in[9];
  const float* g_c1t  = (const float*)d_in[10];
  const float* be_c1t = (const float*)d_in[11];
  const float* w_c2t  = (const float*)d_in[12];
  const float* b_c2t  = (const float*)d_in[13];
  const float* g_c2t  = (const float*)d_in[14];
  const float* be_c2t = (const float*)d_in[15];
  const float* w_f1r  = (const float*)d_in[16];
  const float* b_f1r  = (const float*)d_in[17];
  const float* g_f1r  = (const float*)d_in[18];
  const float* be_f1r = (const float*)d_in[19];
  const float* w_f2r  = (const float*)d_in[20];
  const float* b_f2r  = (const float*)d_in[21];
  const float* g_f2r  = (const float*)d_in[22];
  const float* be_f2r = (const float*)d_in[23];
  const float* w_f1rt = (const float*)d_in[24];
  const float* b_f1rt = (const float*)d_in[25];
  const float* g_f1rt = (const float*)d_in[26];
  const float* be_f1rt= (const float*)d_in[27];
  const float* w_f2rt = (const float*)d_in[28];
  const float* b_f2rt = (const float*)d_in[29];
  const float* g_f2rt = (const float*)d_in[30];
  const float* be_f2rt= (const float*)d_in[31];
  const float* w_iou  = (const float*)d_in[32];
  const float* b_iou  = (const float*)d_in[33];

  float* ws   = (float*)d_ws;
  float* A    = ws + O_A;
  float* Bf   = ws + O_B;
  float* WT   = ws + O_WT;
  float* PR   = ws + O_PR;
  float* Y1   = ws + O_Y1;
  float* Y2   = ws + O_Y2;
  float* MODp = ws + O_MOD;
  float* WXR  = ws + O_WXR;
  float* WYR  = ws + O_WYR;
  float* ARR  = ws + O_ARR;
  float* WXT  = ws + O_WXT;
  float* WYT  = ws + O_WYT;
  float* ART  = ws + O_ART;
  float* MEAN = ws + O_MEAN;
  float* ISTD = ws + O_ISTD;

  const dim3 convGrid(21, 4, 64);

  // ===== get_modulation branch =====
  k_repack<<<2304, 256, 0, stream>>>(w_c1r, WT);
  k_conv3x3<<<convGrid, 256, 0, stream>>>(feat1, WT, b_c1r, A);
  k_chan_stats<<<256, 256, 0, stream>>>(A, MEAN, ISTD);
  k_bn_relu_conv<<<20736, 256, 0, stream>>>(A, MEAN, ISTD, g_c1r, be_c1r);

  k_wxy<<<1, 64, 0, stream>>>(bb1, 64, 5, WXR, WYR, ARR);
  k_pool<5, false><<<dim3(64, 1), 256, 0, stream>>>(A, WXR, WYR, ARR, nullptr, PR, 1);

  k_gemm<<<dim3(16, 1), 256, 0, stream>>>(PR, w_f1r, b_f1r, Y1, 6400, 1024);
  k_fc_stats<<<4, 256, 0, stream>>>(Y1, 64, 1024, MEAN, ISTD);
  k_fc_bn_relu<<<256, 256, 0, stream>>>(Y1, MEAN, ISTD, g_f1r, be_f1r, 64 * 1024, 1024);

  k_gemm<<<dim3(4, 1), 256, 0, stream>>>(Y1, w_f2r, b_f2r, MODp, 1024, 256);
  k_fc_stats<<<1, 256, 0, stream>>>(MODp, 64, 256, MEAN, ISTD);
  k_fc_bn_relu<<<64, 256, 0, stream>>>(MODp, MEAN, ISTD, g_f2r, be_f2r, 64 * 256, 256);

  // ===== get_iou_feat branch =====
  k_repack<<<2304, 256, 0, stream>>>(w_c1t, WT);
  k_conv3x3<<<convGrid, 256, 0, stream>>>(feat2, WT, b_c1t, A);
  k_chan_stats<<<256, 256, 0, stream>>>(A, MEAN, ISTD);
  k_bn_relu_conv<<<20736, 256, 0, stream>>>(A, MEAN, ISTD, g_c1t, be_c1t);

  k_repack<<<2304, 256, 0, stream>>>(w_c2t, WT);
  k_conv3x3<<<convGrid, 256, 0, stream>>>(A, WT, b_c2t, Bf);
  k_chan_stats<<<256, 256, 0, stream>>>(Bf, MEAN, ISTD);
  k_bn_relu_conv<<<20736, 256, 0, stream>>>(Bf, MEAN, ISTD, g_c2t, be_c2t);

  // ===== predict_iou =====
  k_wxy<<<16, 64, 0, stream>>>(props, 1024, 7, WXT, WYT, ART);
  k_pool<7, true><<<dim3(64, 16), 256, 0, stream>>>(Bf, WXT, WYT, ART, MODp, A, 16);

  k_gemm<<<dim3(16, 16), 256, 0, stream>>>(A, w_f1rt, b_f1rt, Y1, 12544, 1024);
  k_fc_stats<<<4, 256, 0, stream>>>(Y1, 1024, 1024, MEAN, ISTD);
  k_fc_bn_relu<<<4096, 256, 0, stream>>>(Y1, MEAN, ISTD, g_f1rt, be_f1rt, 1024 * 1024, 1024);

  k_gemm<<<dim3(16, 16), 256, 0, stream>>>(Y1, w_f2rt, b_f2rt, Y2, 1024, 1024);
  k_fc_stats<<<4, 256, 0, stream>>>(Y2, 1024, 1024, MEAN, ISTD);
  k_fc_bn_relu<<<4096, 256, 0, stream>>>(Y2, MEAN, ISTD, g_f2rt, be_f2rt, 1024 * 1024, 1024);

  k_iou<<<1024, 256, 0, stream>>>(Y2, w_iou, b_iou, (float*)d_out);
}

// Round 2
// 3018.036 us; speedup vs baseline: 2.4956x; 2.4956x over previous
//
#include <hip/hip_runtime.h>
#include <cstddef>

// ---------------------------------------------------------------------------
// FPNIoUNetHR forward — round 2: f16 MFMA for the 3 convs + f1rt GEMM.
// S=64, C=256, H=W=36, N=16.
// ---------------------------------------------------------------------------

typedef _Float16 f16;
typedef __attribute__((ext_vector_type(8))) _Float16 f16x8;
typedef __attribute__((ext_vector_type(4))) float f32x4;

__device__ __forceinline__ void gload16(const void* g, void* l) {
  __builtin_amdgcn_global_load_lds((const __attribute__((address_space(1))) void*)g,
                                   (__attribute__((address_space(3))) void*)l, 16, 0, 0);
}

static __device__ __forceinline__ float hat_int(float x) {
  float u = fminf(1.f, fmaxf(-1.f, x));
  float a = 0.5f * (1.f + u) * (1.f + u);
  float b = 0.5f + u - 0.5f * u * u;
  return (u <= 0.f) ? a : b;
}

// ---- zero the 148 border positions of FT per image ------------------------
__global__ void k_border(f16* __restrict__ FT) {
  const int img = blockIdx.x;
  f16* base = FT + (size_t)img * 1444 * 256;
  for (int i = threadIdx.x; i < 148 * 256; i += 256) {
    int b = i >> 8, c = i & 255;
    int r, cc;
    if (b < 38)       { r = 0;          cc = b; }
    else if (b < 76)  { r = 37;         cc = b - 38; }
    else if (b < 112) { r = b - 76 + 1; cc = 0; }
    else              { r = b - 112 + 1; cc = 37; }
    base[(r * 38 + cc) * 256 + c] = (f16)0.f;
  }
}

// ---- pad + (optional BN+ReLU) + CHW->HWC f16 convert ----------------------
// src [64][256][36][36] fp32 -> FT [64][1444(38x38)][256] f16 (interior only)
template <bool BN>
__global__ void k_pad(const float* __restrict__ src, f16* __restrict__ FT,
                      const float* __restrict__ mean, const float* __restrict__ istd,
                      const float* __restrict__ g, const float* __restrict__ be) {
  const int img = blockIdx.x, h = blockIdx.y, c = threadIdx.x;
  float sc = 1.f, sh = 0.f;
  if (BN) { sc = istd[c] * g[c]; sh = be[c] - mean[c] * sc; }
  const float* sp = src + ((size_t)img * 256 + c) * 1296 + h * 36;
  f16* op = FT + ((size_t)img * 1444 + (h + 1) * 38 + 1) * 256 + c;
#pragma unroll 4
  for (int w = 0; w < 36; ++w) {
    float v = sp[w];
    if (BN) v = fmaxf(fmaf(v, sc, sh), 0.f);
    op[w * 256] = (f16)v;
  }
}

// ---- conv weights [256][256][3][3] fp32 -> [oc][t*256+c] f16 --------------
__global__ void k_repack_w(const float* __restrict__ w, f16* __restrict__ o) {
  int i = blockIdx.x * 256 + threadIdx.x;   // < 589,824
  int oc = i / 2304;
  int k = i - oc * 2304;
  int t = k >> 8, c = k & 255;
  o[i] = (f16)w[(oc * 256 + c) * 9 + t];
}

// ---- flat fp32 -> f16 convert --------------------------------------------
__global__ void k_cvt_f16(const float* __restrict__ s, f16* __restrict__ o, int n) {
  int i = blockIdx.x * 256 + threadIdx.x;
  if (i < n) o[i] = (f16)s[i];
}

// ---- 3x3 conv via MFMA implicit GEMM --------------------------------------
// FT [64][1444][256] f16 (HWC padded), W [256][2304] f16 (k = t*256+c),
// y [64][256][1296] fp32 (+bias). Grid: 1408 blocks (11 pt x 2 oct x 64 img,
// XCD-swizzled), 256 threads. 128x128 tile, BK=32, 16 MFMA/step/wave.
__global__ __launch_bounds__(256) void k_conv_mfma(
    const f16* __restrict__ FT, const f16* __restrict__ W,
    const float* __restrict__ bias, float* __restrict__ y) {
  __shared__ f16x8 sA[512];
  __shared__ f16x8 sB[512];
  const int bid = blockIdx.x;
  const int orig = (bid & 7) * 176 + (bid >> 3);   // bijective: 1408 % 8 == 0
  const int img = orig / 22;
  const int rem = orig - img * 22;
  const int oct = rem / 11;
  const int pt  = rem - oct * 11;
  const int m0 = oct * 128;
  const int p0 = pt * 128;
  const int tid = threadIdx.x;
  const int lane = tid & 63;
  const int wv = tid >> 6;
  const int wr = wv >> 1, wc = wv & 1;

  const f16* aBase = W + (size_t)(m0 + lane) * 2304 + wv * 8;
  const f16* ftImg = FT + (size_t)img * 1444 * 256;
  int pos0 = p0 + lane;
  int pc0 = min(pos0, 1295);
  int pc1 = min(pos0 + 64, 1295);
  int pb0 = ((pc0 / 36) * 38 + (pc0 % 36)) * 256;
  int pb1 = ((pc1 / 36) * 38 + (pc1 % 36)) * 256;

  char* lA = (char*)sA + wv * 2048 + lane * 16;
  char* lB = (char*)sB + wv * 2048 + lane * 16;

  f32x4 acc[4][4] = {};

  for (int ks = 0; ks < 72; ++ks) {
    const int k0 = ks * 32;
    const int t = k0 >> 8;
    const int dy = t / 3, dx = t - dy * 3;
    const int c0 = k0 & 255;
    const int tap = (dy * 38 + dx) * 256 + c0 + wv * 8;
    gload16(aBase + k0, lA);
    gload16(aBase + 64 * 2304 + k0, lA + 1024);
    gload16(ftImg + pb0 + tap, lB);
    gload16(ftImg + pb1 + tap, lB + 1024);
    __syncthreads();
    f16x8 af[4], bf[4];
#pragma unroll
    for (int i = 0; i < 4; ++i) {
      af[i] = sA[((lane >> 4) << 7) + wr * 64 + i * 16 + (lane & 15)];
      bf[i] = sB[((lane >> 4) << 7) + wc * 64 + i * 16 + (lane & 15)];
    }
#pragma unroll
    for (int i = 0; i < 4; ++i)
#pragma unroll
      for (int j = 0; j < 4; ++j)
        acc[i][j] = __builtin_amdgcn_mfma_f32_16x16x32_f16(af[i], bf[j], acc[i][j], 0, 0, 0);
    __syncthreads();
  }

  const int colb = p0 + wc * 64 + (lane & 15);
  const int rowb = m0 + wr * 64 + ((lane >> 4) << 2);
#pragma unroll
  for (int i = 0; i < 4; ++i) {
#pragma unroll
    for (int j = 0; j < 4; ++j) {
      const int col = colb + j * 16;
      if (col < 1296) {
#pragma unroll
        for (int r = 0; r < 4; ++r) {
          const int oc = rowb + i * 16 + r;
          y[((size_t)img * 256 + oc) * 1296 + col] = acc[i][j][r] + bias[oc];
        }
      }
    }
  }
}

// ---- f16 MFMA GEMM: out[m][n] = sum_k A[m][k]*B[n][k] + bias[n] -----------
// A [M][K] f16, B [N][K] f16, K % 32 == 0, M,N % 128 == 0.
__global__ __launch_bounds__(256) void k_gemm_f16(
    const f16* __restrict__ A, const f16* __restrict__ B,
    const float* __restrict__ bias, float* __restrict__ out, int K, int Nout) {
  __shared__ f16x8 sA[512];
  __shared__ f16x8 sB[512];
  const int n0 = blockIdx.x * 128, m0 = blockIdx.y * 128;
  const int tid = threadIdx.x;
  const int lane = tid & 63;
  const int wv = tid >> 6;
  const int wr = wv >> 1, wc = wv & 1;

  const f16* aBase = A + (size_t)(m0 + lane) * K + wv * 8;
  const f16* bBase = B + (size_t)(n0 + lane) * K + wv * 8;
  char* lA = (char*)sA + wv * 2048 + lane * 16;
  char* lB = (char*)sB + wv * 2048 + lane * 16;

  f32x4 acc[4][4] = {};

  for (int k0 = 0; k0 < K; k0 += 32) {
    gload16(aBase + k0, lA);
    gload16(aBase + (size_t)64 * K + k0, lA + 1024);
    gload16(bBase + k0, lB);
    gload16(bBase + (size_t)64 * K + k0, lB + 1024);
    __syncthreads();
    f16x8 af[4], bf[4];
#pragma unroll
    for (int i = 0; i < 4; ++i) {
      af[i] = sA[((lane >> 4) << 7) + wr * 64 + i * 16 + (lane & 15)];
      bf[i] = sB[((lane >> 4) << 7) + wc * 64 + i * 16 + (lane & 15)];
    }
#pragma unroll
    for (int i = 0; i < 4; ++i)
#pragma unroll
      for (int j = 0; j < 4; ++j)
        acc[i][j] = __builtin_amdgcn_mfma_f32_16x16x32_f16(af[i], bf[j], acc[i][j], 0, 0, 0);
    __syncthreads();
  }

  const int colb = n0 + wc * 64 + (lane & 15);
  const int rowb = m0 + wr * 64 + ((lane >> 4) << 2);
#pragma unroll
  for (int i = 0; i < 4; ++i) {
#pragma unroll
    for (int j = 0; j < 4; ++j) {
      const int col = colb + j * 16;
#pragma unroll
      for (int r = 0; r < 4; ++r) {
        const int row = rowb + i * 16 + r;
        out[(size_t)row * Nout + col] = acc[i][j][r] + bias[col];
      }
    }
  }
}

// ---- per-channel BN stats over (s, hw) ------------------------------------
__global__ void k_chan_stats(const float* __restrict__ y,
                             float* __restrict__ mean, float* __restrict__ istd) {
  const int c = blockIdx.x, tid = threadIdx.x;
  float s = 0.f, ss = 0.f;
  for (int img = 0; img < 64; ++img) {
    const float* p = y + ((size_t)img * 256 + c) * 1296;
    for (int i = tid; i < 1296; i += 256) { float v = p[i]; s += v; ss += v * v; }
  }
  __shared__ float rs[256], rss[256];
  rs[tid] = s; rss[tid] = ss;
  __syncthreads();
  for (int o = 128; o > 0; o >>= 1) {
    if (tid < o) { rs[tid] += rs[tid + o]; rss[tid] += rss[tid + o]; }
    __syncthreads();
  }
  if (tid == 0) {
    float m = rs[0] * (1.f / 82944.f);
    float var = rss[0] * (1.f / 82944.f) - m * m;
    mean[c] = m;
    istd[c] = rsqrtf(var + 1e-5f);
  }
}

// ---- BN+ReLU elementwise on conv tensor (float4, in place) ----------------
__global__ void k_bn_relu_conv(float* __restrict__ y, const float* __restrict__ mean,
                               const float* __restrict__ istd, const float* __restrict__ g,
                               const float* __restrict__ be) {
  int i = blockIdx.x * 256 + threadIdx.x;
  int c = (i / 324) & 255;
  float sc = istd[c] * g[c];
  float sh = be[c] - mean[c] * sc;
  float4 v = reinterpret_cast<float4*>(y)[i];
  v.x = fmaxf(fmaf(v.x, sc, sh), 0.f);
  v.y = fmaxf(fmaf(v.y, sc, sh), 0.f);
  v.z = fmaxf(fmaf(v.z, sc, sh), 0.f);
  v.w = fmaxf(fmaf(v.w, sc, sh), 0.f);
  reinterpret_cast<float4*>(y)[i] = v;
}

// ---- PrRoI separable weights ----------------------------------------------
__global__ void k_wxy(const float* __restrict__ rois, int ntot, int P,
                      float* __restrict__ Wx, float* __restrict__ Wy,
                      float* __restrict__ area) {
  int idx = blockIdx.x * blockDim.x + threadIdx.x;
  if (idx >= ntot) return;
  float rx = rois[idx * 4 + 0], ry = rois[idx * 4 + 1];
  float rw = rois[idx * 4 + 2], rh = rois[idx * 4 + 3];
  float x1 = rx * 0.125f, y1 = ry * 0.125f;
  float x2 = (rx + rw) * 0.125f, y2 = (ry + rh) * 0.125f;
  float bw = (x2 - x1) / P, bh = (y2 - y1) / P;
  area[idx] = bw * bh;
  for (int q = 0; q < P; ++q) {
    float xlo = x1 + q * bw, ylo = y1 + q * bh;
    for (int g = 0; g < 36; ++g) {
      float fg = (float)g;
      Wx[(idx * P + q) * 36 + g] = hat_int(xlo + bw - fg) - hat_int(xlo - fg);
      Wy[(idx * P + q) * 36 + g] = hat_int(ylo + bh - fg) - hat_int(ylo - fg);
    }
  }
}

// ---- PrRoI pool: block=(s,n), thread=channel ------------------------------
template <int P, bool MOD>
__global__ __launch_bounds__(256) void k_pool(
    const float* __restrict__ feat, const float* __restrict__ Wx,
    const float* __restrict__ Wy, const float* __restrict__ area,
    const float* __restrict__ mod, float* __restrict__ outF,
    f16* __restrict__ outH, int N) {
  const int s = blockIdx.x, n = blockIdx.y;
  const int idx = s * N + n;
  const int c = threadIdx.x;
  __shared__ float sWx[P * 36], sWy[P * 36];
  for (int i = threadIdx.x; i < P * 36; i += 256) {
    sWx[i] = Wx[(size_t)idx * P * 36 + i];
    sWy[i] = Wy[(size_t)idx * P * 36 + i];
  }
  __syncthreads();
  const float* f = feat + ((size_t)s * 256 + c) * 1296;
  float o[P][P];
#pragma unroll
  for (int a = 0; a < P; ++a)
#pragma unroll
    for (int b = 0; b < P; ++b) o[a][b] = 0.f;
  for (int h = 0; h < 36; ++h) {
    float row[36];
#pragma unroll
    for (int w = 0; w < 36; ++w) row[w] = f[h * 36 + w];
    float colsum[P];
#pragma unroll
    for (int q = 0; q < P; ++q) {
      float v = 0.f;
#pragma unroll
      for (int w = 0; w < 36; ++w) v = fmaf(sWx[q * 36 + w], row[w], v);
      colsum[q] = v;
    }
#pragma unroll
    for (int p = 0; p < P; ++p) {
      float wy = sWy[p * 36 + h];
#pragma unroll
      for (int q = 0; q < P; ++q) o[p][q] = fmaf(wy, colsum[q], o[p][q]);
    }
  }
  float a = area[idx];
  float inv = (a > 0.f) ? 1.f / fmaxf(a, 1e-12f) : 0.f;
  float msc = MOD ? (mod[s * 256 + c] * inv) : inv;
  if (MOD) {
    f16* op = outH + (size_t)idx * 12544 + c * 49;
#pragma unroll
    for (int p = 0; p < P; ++p)
#pragma unroll
      for (int q = 0; q < P; ++q) op[p * P + q] = (f16)(o[p][q] * msc);
  } else {
    float* op = outF + (size_t)s * 6400 + c * 25;
#pragma unroll
    for (int p = 0; p < P; ++p)
#pragma unroll
      for (int q = 0; q < P; ++q) op[p * P + q] = o[p][q] * msc;
  }
}

// ---- generic fp32 GEMM (small FCs): out[m][n] = A[m]·B[n] + bias[n] -------
__global__ __launch_bounds__(256) void k_gemm(
    const float* __restrict__ A, const float* __restrict__ B,
    const float* __restrict__ bias, float* __restrict__ out, int K, int N) {
  const int n0 = blockIdx.x * 64;
  const int m0 = blockIdx.y * 64;
  const int tid = threadIdx.x;
  const int lk = tid & 15;
  const int lr = tid >> 4;
  const int tx = tid & 15, ty = tid >> 4;
  __shared__ float As[16][68];
  __shared__ float Bs[16][68];
  float acc[4][4] = {};
  for (int kb = 0; kb < K; kb += 16) {
#pragma unroll
    for (int r = 0; r < 4; ++r) {
      As[lk][r * 16 + lr] = A[(size_t)(m0 + r * 16 + lr) * K + kb + lk];
      Bs[lk][r * 16 + lr] = B[(size_t)(n0 + r * 16 + lr) * K + kb + lk];
    }
    __syncthreads();
#pragma unroll
    for (int kk = 0; kk < 16; ++kk) {
      float4 a4 = *reinterpret_cast<const float4*>(&As[kk][ty * 4]);
      float4 b4 = *reinterpret_cast<const float4*>(&Bs[kk][tx * 4]);
      float av[4] = {a4.x, a4.y, a4.z, a4.w};
      float bv[4] = {b4.x, b4.y, b4.z, b4.w};
#pragma unroll
      for (int i = 0; i < 4; ++i)
#pragma unroll
        for (int j = 0; j < 4; ++j)
          acc[i][j] = fmaf(av[i], bv[j], acc[i][j]);
    }
    __syncthreads();
  }
#pragma unroll
  for (int i = 0; i < 4; ++i) {
    float* op = out + (size_t)(m0 + ty * 4 + i) * N + n0;
#pragma unroll
    for (int j = 0; j < 4; ++j)
      op[tx * 4 + j] = acc[i][j] + bias[n0 + tx * 4 + j];
  }
}

// ---- FC BN stats over batch dim -------------------------------------------
__global__ void k_fc_stats(const float* __restrict__ y, int M, int Nf,
                           float* __restrict__ mean, float* __restrict__ istd) {
  int col = blockIdx.x * 256 + threadIdx.x;
  if (col >= Nf) return;
  float s = 0.f, ss = 0.f;
  for (int m = 0; m < M; ++m) {
    float v = y[(size_t)m * Nf + col];
    s += v; ss += v * v;
  }
  float mu = s / (float)M;
  float var = ss / (float)M - mu * mu;
  mean[col] = mu;
  istd[col] = rsqrtf(var + 1e-5f);
}

// ---- FC BN+ReLU elementwise (in place) ------------------------------------
__global__ void k_fc_bn_relu(float* __restrict__ y, const float* __restrict__ mean,
                             const float* __restrict__ istd, const float* __restrict__ g,
                             const float* __restrict__ be, int total, int Nf) {
  int i = blockIdx.x * 256 + threadIdx.x;
  if (i >= total) return;
  int col = i % Nf;
  float sc = istd[col] * g[col];
  float sh = be[col] - mean[col] * sc;
  y[i] = fmaxf(fmaf(y[i], sc, sh), 0.f);
}

// ---- IoU head -------------------------------------------------------------
__global__ void k_iou(const float* __restrict__ x, const float* __restrict__ w,
                      const float* __restrict__ b, float* __restrict__ out) {
  const int r = blockIdx.x, tid = threadIdx.x;
  float s = 0.f;
  for (int k = tid; k < 1024; k += 256) s = fmaf(x[(size_t)r * 1024 + k], w[k], s);
  __shared__ float red[256];
  red[tid] = s;
  __syncthreads();
  for (int o = 128; o > 0; o >>= 1) {
    if (tid < o) red[tid] += red[tid + o];
    __syncthreads();
  }
  if (tid == 0) out[r] = red[0] + b[0];
}

// ---------------------------------------------------------------------------
// Workspace layout (float offsets). Total 42,845,760 floats = 171.4 MB.
// ---------------------------------------------------------------------------
static const size_t O_A    = 0;           // 21,233,664  conv out fp32
static const size_t O_FT   = 21233664;    // 11,829,248  f16 padded HWC / Ph overlay
static const size_t O_WC   = 33062912;    //    294,912  conv weights f16
static const size_t O_WF   = 33357824;    //  6,422,528  f1rt weights f16
static const size_t O_PR   = 39780352;    //    409,600
static const size_t O_Y1   = 40189952;    //  1,048,576
static const size_t O_Y2   = 41238528;    //  1,048,576
static const size_t O_MOD  = 42287104;    //     16,384
static const size_t O_WXR  = 42303488;    //     11,520
static const size_t O_WYR  = 42315008;    //     11,520
static const size_t O_ARR  = 42326528;    //         64
static const size_t O_WXT  = 42326592;    //    258,048
static const size_t O_WYT  = 42584640;    //    258,048
static const size_t O_ART  = 42842688;    //      1,024
static const size_t O_MEAN = 42843712;    //      1,024
static const size_t O_ISTD = 42844736;    //      1,024

extern "C" void kernel_launch(void* const* d_in, const int* in_sizes, int n_in,
                              void* d_out, int out_size, void* d_ws, size_t ws_size,
                              hipStream_t stream) {
  (void)in_sizes; (void)n_in; (void)out_size; (void)ws_size;
  const float* feat1  = (const float*)d_in[0];
  const float* feat2  = (const float*)d_in[1];
  const float* bb1    = (const float*)d_in[2];
  const float* props  = (const float*)d_in[3];
  const float* w_c1r  = (const float*)d_in[4];
  const float* b_c1r  = (const float*)d_in[5];
  const float* g_c1r  = (const float*)d_in[6];
  const float* be_c1r = (const float*)d_in[7];
  const float* w_c1t  = (const float*)d_in[8];
  const float* b_c1t  = (const float*)d_in[9];
  const float* g_c1t  = (const float*)d_in[10];
  const float* be_c1t = (const float*)d_in[11];
  const float* w_c2t  = (const float*)d_in[12];
  const float* b_c2t  = (const float*)d_in[13];
  const float* g_c2t  = (const float*)d_in[14];
  const float* be_c2t = (const float*)d_in[15];
  const float* w_f1r  = (const float*)d_in[16];
  const float* b_f1r  = (const float*)d_in[17];
  const float* g_f1r  = (const float*)d_in[18];
  const float* be_f1r = (const float*)d_in[19];
  const float* w_f2r  = (const float*)d_in[20];
  const float* b_f2r  = (const float*)d_in[21];
  const float* g_f2r  = (const float*)d_in[22];
  const float* be_f2r = (const float*)d_in[23];
  const float* w_f1rt = (const float*)d_in[24];
  const float* b_f1rt = (const float*)d_in[25];
  const float* g_f1rt = (const float*)d_in[26];
  const float* be_f1rt= (const float*)d_in[27];
  const float* w_f2rt = (const float*)d_in[28];
  const float* b_f2rt = (const float*)d_in[29];
  const float* g_f2rt = (const float*)d_in[30];
  const float* be_f2rt= (const float*)d_in[31];
  const float* w_iou  = (const float*)d_in[32];
  const float* b_iou  = (const float*)d_in[33];

  float* ws   = (float*)d_ws;
  float* A    = ws + O_A;
  f16*   FT   = (f16*)(ws + O_FT);
  f16*   WC   = (f16*)(ws + O_WC);
  f16*   WF   = (f16*)(ws + O_WF);
  f16*   Ph   = FT;                 // pooled_t f16 overlays FT (dead by then)
  float* PR   = ws + O_PR;
  float* Y1   = ws + O_Y1;
  float* Y2   = ws + O_Y2;
  float* MODp = ws + O_MOD;
  float* WXR  = ws + O_WXR;
  float* WYR  = ws + O_WYR;
  float* ARR  = ws + O_ARR;
  float* WXT  = ws + O_WXT;
  float* WYT  = ws + O_WYT;
  float* ART  = ws + O_ART;
  float* MEAN = ws + O_MEAN;
  float* ISTD = ws + O_ISTD;

  // ===== get_modulation branch =====
  k_border<<<64, 256, 0, stream>>>(FT);
  k_repack_w<<<2304, 256, 0, stream>>>(w_c1r, WC);
  k_pad<false><<<dim3(64, 36), 256, 0, stream>>>(feat1, FT, nullptr, nullptr, nullptr, nullptr);
  k_conv_mfma<<<1408, 256, 0, stream>>>(FT, WC, b_c1r, A);
  k_chan_stats<<<256, 256, 0, stream>>>(A, MEAN, ISTD);
  k_bn_relu_conv<<<20736, 256, 0, stream>>>(A, MEAN, ISTD, g_c1r, be_c1r);

  k_wxy<<<1, 64, 0, stream>>>(bb1, 64, 5, WXR, WYR, ARR);
  k_pool<5, false><<<dim3(64, 1), 256, 0, stream>>>(A, WXR, WYR, ARR, nullptr, PR, nullptr, 1);

  k_gemm<<<dim3(16, 1), 256, 0, stream>>>(PR, w_f1r, b_f1r, Y1, 6400, 1024);
  k_fc_stats<<<4, 256, 0, stream>>>(Y1, 64, 1024, MEAN, ISTD);
  k_fc_bn_relu<<<256, 256, 0, stream>>>(Y1, MEAN, ISTD, g_f1r, be_f1r, 64 * 1024, 1024);

  k_gemm<<<dim3(4, 1), 256, 0, stream>>>(Y1, w_f2r, b_f2r, MODp, 1024, 256);
  k_fc_stats<<<1, 256, 0, stream>>>(MODp, 64, 256, MEAN, ISTD);
  k_fc_bn_relu<<<64, 256, 0, stream>>>(MODp, MEAN, ISTD, g_f2r, be_f2r, 64 * 256, 256);

  // ===== get_iou_feat branch =====
  k_repack_w<<<2304, 256, 0, stream>>>(w_c1t, WC);
  k_pad<false><<<dim3(64, 36), 256, 0, stream>>>(feat2, FT, nullptr, nullptr, nullptr, nullptr);
  k_conv_mfma<<<1408, 256, 0, stream>>>(FT, WC, b_c1t, A);
  k_chan_stats<<<256, 256, 0, stream>>>(A, MEAN, ISTD);
  k_pad<true><<<dim3(64, 36), 256, 0, stream>>>(A, FT, MEAN, ISTD, g_c1t, be_c1t);

  k_repack_w<<<2304, 256, 0, stream>>>(w_c2t, WC);
  k_conv_mfma<<<1408, 256, 0, stream>>>(FT, WC, b_c2t, A);
  k_chan_stats<<<256, 256, 0, stream>>>(A, MEAN, ISTD);
  k_bn_relu_conv<<<20736, 256, 0, stream>>>(A, MEAN, ISTD, g_c2t, be_c2t);

  // ===== predict_iou =====
  k_wxy<<<16, 64, 0, stream>>>(props, 1024, 7, WXT, WYT, ART);
  k_cvt_f16<<<50176, 256, 0, stream>>>(w_f1rt, WF, 12845056);
  k_pool<7, true><<<dim3(64, 16), 256, 0, stream>>>(A, WXT, WYT, ART, MODp, nullptr, Ph, 16);

  k_gemm_f16<<<dim3(8, 8), 256, 0, stream>>>(Ph, WF, b_f1rt, Y1, 12544, 1024);
  k_fc_stats<<<4, 256, 0, stream>>>(Y1, 1024, 1024, MEAN, ISTD);
  k_fc_bn_relu<<<4096, 256, 0, stream>>>(Y1, MEAN, ISTD, g_f1rt, be_f1rt, 1024 * 1024, 1024);

  k_gemm<<<dim3(16, 16), 256, 0, stream>>>(Y1, w_f2rt, b_f2rt, Y2, 1024, 1024);
  k_fc_stats<<<4, 256, 0, stream>>>(Y2, 1024, 1024, MEAN, ISTD);
  k_fc_bn_relu<<<4096, 256, 0, stream>>>(Y2, MEAN, ISTD, g_f2rt, be_f2rt, 1024 * 1024, 1024);

  k_iou<<<1024, 256, 0, stream>>>(Y2, w_iou, b_iou, (float*)d_out);
}

// Round 3
// 2148.835 us; speedup vs baseline: 3.5051x; 1.4045x over previous
//
#include <hip/hip_runtime.h>
#include <cstddef>

// ---------------------------------------------------------------------------
// FPNIoUNetHR forward — round 3: packed split-K f16 MFMA GEMMs + sparse pool.
// S=64, C=256, H=W=36, N=16.
// ---------------------------------------------------------------------------

typedef _Float16 f16;
typedef __attribute__((ext_vector_type(8))) _Float16 f16x8;
typedef __attribute__((ext_vector_type(4))) float f32x4;

__device__ __forceinline__ void gload16(const void* g, void* l) {
  __builtin_amdgcn_global_load_lds((const __attribute__((address_space(1))) void*)g,
                                   (__attribute__((address_space(3))) void*)l, 16, 0, 0);
}

static __device__ __forceinline__ float hat_int(float x) {
  float u = fminf(1.f, fmaxf(-1.f, x));
  float a = 0.5f * (1.f + u) * (1.f + u);
  float b = 0.5f + u - 0.5f * u * u;
  return (u <= 0.f) ? a : b;
}

// Packed GEMM operand layout: element (row,k) of a row-major [M][K] matrix ->
// [row/128][k/32][(k/8)%4][row%128][k%8]. One k-step chunk (128 rows x 32 k)
// is 8 KB contiguous, exactly the LDS image the MFMA frag reads want.
static __device__ __forceinline__ size_t pk_off(int row, int k, int K) {
  return (size_t)(row >> 7) * ((size_t)K * 128) + (size_t)(k >> 5) * 4096
       + (size_t)((((k >> 3) & 3) * 128 + (row & 127)) * 8 + (k & 7));
}

// ---- zero helper (float4 granularity, exact grid) -------------------------
__global__ void k_zero(float4* __restrict__ p, int n4) {
  int i = blockIdx.x * 256 + threadIdx.x;
  if (i < n4) p[i] = float4{0.f, 0.f, 0.f, 0.f};
}

// ---- zero the 148 border positions of FT per image ------------------------
__global__ void k_border(f16* __restrict__ FT) {
  const int img = blockIdx.x;
  f16* base = FT + (size_t)img * 1444 * 256;
  for (int i = threadIdx.x; i < 148 * 256; i += 256) {
    int b = i >> 8, c = i & 255;
    int r, cc;
    if (b < 38)       { r = 0;          cc = b; }
    else if (b < 76)  { r = 37;         cc = b - 38; }
    else if (b < 112) { r = b - 76 + 1; cc = 0; }
    else              { r = b - 112 + 1; cc = 37; }
    base[(r * 38 + cc) * 256 + c] = (f16)0.f;
  }
}

// ---- pad + (optional BN+ReLU) + CHW->HWC f16 convert ----------------------
template <bool BN>
__global__ void k_pad(const float* __restrict__ src, f16* __restrict__ FT,
                      const float* __restrict__ mean, const float* __restrict__ istd,
                      const float* __restrict__ g, const float* __restrict__ be) {
  const int img = blockIdx.x, h = blockIdx.y, c = threadIdx.x;
  float sc = 1.f, sh = 0.f;
  if (BN) { sc = istd[c] * g[c]; sh = be[c] - mean[c] * sc; }
  const float* sp = src + ((size_t)img * 256 + c) * 1296 + h * 36;
  f16* op = FT + ((size_t)img * 1444 + (h + 1) * 38 + 1) * 256 + c;
#pragma unroll 4
  for (int w = 0; w < 36; ++w) {
    float v = sp[w];
    if (BN) v = fmaxf(fmaf(v, sc, sh), 0.f);
    op[w * 256] = (f16)v;
  }
}

// ---- conv weights [256][256][3][3] fp32 -> [oc][t*256+c] f16 --------------
__global__ void k_repack_w(const float* __restrict__ w, f16* __restrict__ o) {
  int i = blockIdx.x * 256 + threadIdx.x;
  int oc = i / 2304;
  int k = i - oc * 2304;
  int t = k >> 8, c = k & 255;
  o[i] = (f16)w[(oc * 256 + c) * 9 + t];
}

// ---- pack fp32 [N][K] weights into packed f16 (write-coalesced) -----------
__global__ void k_pack_w(const float* __restrict__ src, f16* __restrict__ dst,
                         int K, int total) {
  int i = blockIdx.x * 256 + threadIdx.x;
  if (i >= total) return;
  const int blkSz = K * 128;
  int nt = i / blkSz;
  int wi = i - nt * blkSz;
  int ks = wi >> 12;
  int r2 = wi & 4095;
  int koct = r2 >> 10;
  int r3 = r2 & 1023;
  int col = r3 >> 3, kj = r3 & 7;
  int k = ks * 32 + koct * 8 + kj;
  int row = nt * 128 + col;
  dst[i] = (f16)src[(size_t)row * K + k];
}

// ---- 3x3 conv via MFMA implicit GEMM (unchanged from round 2) -------------
__global__ __launch_bounds__(256) void k_conv_mfma(
    const f16* __restrict__ FT, const f16* __restrict__ W,
    const float* __restrict__ bias, float* __restrict__ y) {
  __shared__ f16x8 sA[512];
  __shared__ f16x8 sB[512];
  const int bid = blockIdx.x;
  const int orig = (bid & 7) * 176 + (bid >> 3);   // bijective: 1408 % 8 == 0
  const int img = orig / 22;
  const int rem = orig - img * 22;
  const int oct = rem / 11;
  const int pt  = rem - oct * 11;
  const int m0 = oct * 128;
  const int p0 = pt * 128;
  const int tid = threadIdx.x;
  const int lane = tid & 63;
  const int wv = tid >> 6;
  const int wr = wv >> 1, wc = wv & 1;

  const f16* aBase = W + (size_t)(m0 + lane) * 2304 + wv * 8;
  const f16* ftImg = FT + (size_t)img * 1444 * 256;
  int pos0 = p0 + lane;
  int pc0 = min(pos0, 1295);
  int pc1 = min(pos0 + 64, 1295);
  int pb0 = ((pc0 / 36) * 38 + (pc0 % 36)) * 256;
  int pb1 = ((pc1 / 36) * 38 + (pc1 % 36)) * 256;

  char* lA = (char*)sA + wv * 2048 + lane * 16;
  char* lB = (char*)sB + wv * 2048 + lane * 16;

  f32x4 acc[4][4] = {};

  for (int ks = 0; ks < 72; ++ks) {
    const int k0 = ks * 32;
    const int t = k0 >> 8;
    const int dy = t / 3, dx = t - dy * 3;
    const int c0 = k0 & 255;
    const int tap = (dy * 38 + dx) * 256 + c0 + wv * 8;
    gload16(aBase + k0, lA);
    gload16(aBase + 64 * 2304 + k0, lA + 1024);
    gload16(ftImg + pb0 + tap, lB);
    gload16(ftImg + pb1 + tap, lB + 1024);
    __syncthreads();
    f16x8 af[4], bf[4];
#pragma unroll
    for (int i = 0; i < 4; ++i) {
      af[i] = sA[((lane >> 4) << 7) + wr * 64 + i * 16 + (lane & 15)];
      bf[i] = sB[((lane >> 4) << 7) + wc * 64 + i * 16 + (lane & 15)];
    }
#pragma unroll
    for (int i = 0; i < 4; ++i)
#pragma unroll
      for (int j = 0; j < 4; ++j)
        acc[i][j] = __builtin_amdgcn_mfma_f32_16x16x32_f16(af[i], bf[j], acc[i][j], 0, 0, 0);
    __syncthreads();
  }

  const int colb = p0 + wc * 64 + (lane & 15);
  const int rowb = m0 + wr * 64 + ((lane >> 4) << 2);
#pragma unroll
  for (int i = 0; i < 4; ++i) {
#pragma unroll
    for (int j = 0; j < 4; ++j) {
      const int col = colb + j * 16;
      if (col < 1296) {
#pragma unroll
        for (int r = 0; r < 4; ++r) {
          const int oc = rowb + i * 16 + r;
          y[((size_t)img * 256 + oc) * 1296 + col] = acc[i][j][r] + bias[oc];
        }
      }
    }
  }
}

// ---- packed split-K f16 MFMA GEMM -----------------------------------------
// Apk/Bpk in pk_off layout. Writes fp32 partial [z][mrows][Nout] (no bias).
__global__ __launch_bounds__(256) void k_gemm_f16pk(
    const f16* __restrict__ Apk, const f16* __restrict__ Bpk,
    float* __restrict__ part, int K, int Nout, int stepsPerZ, int mrows) {
  __shared__ f16x8 sA[512];
  __shared__ f16x8 sB[512];
  const int nt = blockIdx.x, mt = blockIdx.y, z = blockIdx.z;
  const int tid = threadIdx.x;
  const int lane = tid & 63;
  const int wv = tid >> 6;
  const int wr = wv >> 1, wc = wv & 1;

  const f16* aC = Apk + (size_t)mt * K * 128;
  const f16* bC = Bpk + (size_t)nt * K * 128;
  char* lA = (char*)sA + wv * 2048 + lane * 16;
  char* lB = (char*)sB + wv * 2048 + lane * 16;

  f32x4 acc[4][4] = {};

  const int ks0 = z * stepsPerZ, ks1 = ks0 + stepsPerZ;
  for (int ks = ks0; ks < ks1; ++ks) {
    const f16* ap = aC + (size_t)ks * 4096 + wv * 1024 + lane * 8;
    const f16* bp = bC + (size_t)ks * 4096 + wv * 1024 + lane * 8;
    gload16(ap, lA);
    gload16(ap + 512, lA + 1024);
    gload16(bp, lB);
    gload16(bp + 512, lB + 1024);
    __syncthreads();
    f16x8 af[4], bf[4];
#pragma unroll
    for (int i = 0; i < 4; ++i) {
      af[i] = sA[((lane >> 4) << 7) + wr * 64 + i * 16 + (lane & 15)];
      bf[i] = sB[((lane >> 4) << 7) + wc * 64 + i * 16 + (lane & 15)];
    }
#pragma unroll
    for (int i = 0; i < 4; ++i)
#pragma unroll
      for (int j = 0; j < 4; ++j)
        acc[i][j] = __builtin_amdgcn_mfma_f32_16x16x32_f16(af[i], bf[j], acc[i][j], 0, 0, 0);
    __syncthreads();
  }

  const size_t zoff = (size_t)z * mrows * Nout;
  const int colb = nt * 128 + wc * 64 + (lane & 15);
  const int rowb = mt * 128 + wr * 64 + ((lane >> 4) << 2);
#pragma unroll
  for (int i = 0; i < 4; ++i)
#pragma unroll
    for (int j = 0; j < 4; ++j)
#pragma unroll
      for (int r = 0; r < 4; ++r)
        part[zoff + (size_t)(rowb + i * 16 + r) * Nout + colb + j * 16] = acc[i][j][r];
}

// ---- reduce split-K partials + bias ---------------------------------------
__global__ void k_reduce(const float* __restrict__ part, const float* __restrict__ bias,
                         float* __restrict__ out, int mrows, int Mout, int Nout, int sk) {
  int i = blockIdx.x * 256 + threadIdx.x;
  if (i >= Mout * Nout) return;
  int row = i / Nout, col = i - row * Nout;
  float s = bias[col];
  for (int z = 0; z < sk; ++z)
    s += part[(size_t)z * mrows * Nout + (size_t)row * Nout + col];
  out[i] = s;
}

// ---- per-channel BN stats over (s, hw) ------------------------------------
__global__ void k_chan_stats(const float* __restrict__ y,
                             float* __restrict__ mean, float* __restrict__ istd) {
  const int c = blockIdx.x, tid = threadIdx.x;
  float s = 0.f, ss = 0.f;
  for (int img = 0; img < 64; ++img) {
    const float* p = y + ((size_t)img * 256 + c) * 1296;
    for (int i = tid; i < 1296; i += 256) { float v = p[i]; s += v; ss += v * v; }
  }
  __shared__ float rs[256], rss[256];
  rs[tid] = s; rss[tid] = ss;
  __syncthreads();
  for (int o = 128; o > 0; o >>= 1) {
    if (tid < o) { rs[tid] += rs[tid + o]; rss[tid] += rss[tid + o]; }
    __syncthreads();
  }
  if (tid == 0) {
    float m = rs[0] * (1.f / 82944.f);
    float var = rss[0] * (1.f / 82944.f) - m * m;
    mean[c] = m;
    istd[c] = rsqrtf(var + 1e-5f);
  }
}

// ---- BN+ReLU elementwise on conv tensor (float4, in place) ----------------
__global__ void k_bn_relu_conv(float* __restrict__ y, const float* __restrict__ mean,
                               const float* __restrict__ istd, const float* __restrict__ g,
                               const float* __restrict__ be) {
  int i = blockIdx.x * 256 + threadIdx.x;
  int c = (i / 324) & 255;
  float sc = istd[c] * g[c];
  float sh = be[c] - mean[c] * sc;
  float4 v = reinterpret_cast<float4*>(y)[i];
  v.x = fmaxf(fmaf(v.x, sc, sh), 0.f);
  v.y = fmaxf(fmaf(v.y, sc, sh), 0.f);
  v.z = fmaxf(fmaf(v.z, sc, sh), 0.f);
  v.w = fmaxf(fmaf(v.w, sc, sh), 0.f);
  reinterpret_cast<float4*>(y)[i] = v;
}

// ---- PrRoI separable weights + sparse-range metadata ----------------------
__global__ void k_wxy(const float* __restrict__ rois, int ntot, int P,
                      float* __restrict__ Wx, float* __restrict__ Wy,
                      float* __restrict__ area,
                      int* __restrict__ HLO, int* __restrict__ HCNT,
                      int* __restrict__ WLO) {
  int idx = blockIdx.x * blockDim.x + threadIdx.x;
  if (idx >= ntot) return;
  float rx = rois[idx * 4 + 0], ry = rois[idx * 4 + 1];
  float rw = rois[idx * 4 + 2], rh = rois[idx * 4 + 3];
  float x1 = rx * 0.125f, y1 = ry * 0.125f;
  float x2 = (rx + rw) * 0.125f, y2 = (ry + rh) * 0.125f;
  float bw = (x2 - x1) / P, bh = (y2 - y1) / P;
  area[idx] = bw * bh;
  int hlo = max(0, (int)ceilf(y1 - 1.f));
  int hhi = min(35, (int)floorf(y2 + 1.f));
  HLO[idx] = hlo;
  HCNT[idx] = max(0, hhi - hlo + 1);
  for (int q = 0; q < P; ++q) {
    float xlo = x1 + q * bw, ylo = y1 + q * bh;
    WLO[idx * P + q] = min(31, max(0, (int)ceilf(xlo - 1.f)));
    for (int g = 0; g < 36; ++g) {
      float fg = (float)g;
      Wx[(idx * P + q) * 36 + g] = hat_int(xlo + bw - fg) - hat_int(xlo - fg);
      Wy[(idx * P + q) * 36 + g] = hat_int(ylo + bh - fg) - hat_int(ylo - fg);
    }
  }
}

// ---- PrRoI pool: block=(s,n), thread=channel; writes packed f16 -----------
// SPARSE: restrict h to the active row range, 5-wide x windows per bin
// (wave-uniform bounds; bw<=1.79 for P=7 so support <=4 taps -> 5 covers).
template <int P, bool MOD, bool SPARSE>
__global__ __launch_bounds__(256) void k_pool(
    const float* __restrict__ feat, const float* __restrict__ Wx,
    const float* __restrict__ Wy, const float* __restrict__ area,
    const int* __restrict__ HLO, const int* __restrict__ HCNT,
    const int* __restrict__ WLO,
    const float* __restrict__ mod, f16* __restrict__ outPk, int N) {
  const int s = blockIdx.x, n = blockIdx.y;
  const int idx = s * N + n;
  const int c = threadIdx.x;
  constexpr int KD = P * P * 256;
  __shared__ float sWx[P * 36], sWy[P * 36];
  __shared__ int sWLO[P];
  __shared__ int sH[2];
  for (int i = threadIdx.x; i < P * 36; i += 256) {
    sWx[i] = Wx[(size_t)idx * P * 36 + i];
    sWy[i] = Wy[(size_t)idx * P * 36 + i];
  }
  if (threadIdx.x < P) sWLO[threadIdx.x] = WLO[idx * P + threadIdx.x];
  if (threadIdx.x == 0) { sH[0] = HLO[idx]; sH[1] = HCNT[idx]; }
  __syncthreads();
  const float* f = feat + ((size_t)s * 256 + c) * 1296;
  float o[P][P] = {};
  const int hlo = SPARSE ? sH[0] : 0;
  const int hcnt = SPARSE ? sH[1] : 36;
  for (int hh = 0; hh < hcnt; ++hh) {
    const int h = hlo + hh;
    const float* rp = f + h * 36;
    float colsum[P];
    if (SPARSE) {
#pragma unroll
      for (int q = 0; q < P; ++q) {
        const int w0 = sWLO[q];
        float v = 0.f;
#pragma unroll
        for (int j = 0; j < 5; ++j) v = fmaf(sWx[q * 36 + w0 + j], rp[w0 + j], v);
        colsum[q] = v;
      }
    } else {
      float row[36];
#pragma unroll
      for (int w = 0; w < 36; ++w) row[w] = rp[w];
#pragma unroll
      for (int q = 0; q < P; ++q) {
        float v = 0.f;
#pragma unroll
        for (int w = 0; w < 36; ++w) v = fmaf(sWx[q * 36 + w], row[w], v);
        colsum[q] = v;
      }
    }
#pragma unroll
    for (int p = 0; p < P; ++p) {
      const float wy = sWy[p * 36 + h];
      if (wy != 0.f) {
#pragma unroll
        for (int q = 0; q < P; ++q) o[p][q] = fmaf(wy, colsum[q], o[p][q]);
      }
    }
  }
  float a = area[idx];
  float inv = (a > 0.f) ? 1.f / fmaxf(a, 1e-12f) : 0.f;
  float msc = MOD ? (mod[s * 256 + c] * inv) : inv;
  const int kbase = c * (P * P);
#pragma unroll
  for (int p = 0; p < P; ++p)
#pragma unroll
    for (int q = 0; q < P; ++q)
      outPk[pk_off(idx, kbase + p * P + q, KD)] = (f16)(o[p][q] * msc);
}

// ---- FC BN stats over batch dim -------------------------------------------
__global__ void k_fc_stats(const float* __restrict__ y, int M, int Nf,
                           float* __restrict__ mean, float* __restrict__ istd) {
  int col = blockIdx.x * 256 + threadIdx.x;
  if (col >= Nf) return;
  float s = 0.f, ss = 0.f;
  for (int m = 0; m < M; ++m) {
    float v = y[(size_t)m * Nf + col];
    s += v; ss += v * v;
  }
  float mu = s / (float)M;
  float var = ss / (float)M - mu * mu;
  mean[col] = mu;
  istd[col] = rsqrtf(var + 1e-5f);
}

// ---- FC BN+ReLU elementwise (fp32 in place) -------------------------------
__global__ void k_fc_bn_relu(float* __restrict__ y, const float* __restrict__ mean,
                             const float* __restrict__ istd, const float* __restrict__ g,
                             const float* __restrict__ be, int total, int Nf) {
  int i = blockIdx.x * 256 + threadIdx.x;
  if (i >= total) return;
  int col = i % Nf;
  float sc = istd[col] * g[col];
  float sh = be[col] - mean[col] * sc;
  y[i] = fmaxf(fmaf(y[i], sc, sh), 0.f);
}

// ---- FC BN+ReLU -> packed f16 (next GEMM's A operand) ---------------------
__global__ void k_fc_bn_relu_pk(const float* __restrict__ y, const float* __restrict__ mean,
                                const float* __restrict__ istd, const float* __restrict__ g,
                                const float* __restrict__ be, f16* __restrict__ xpk,
                                int total, int Nf) {
  int i = blockIdx.x * 256 + threadIdx.x;
  if (i >= total) return;
  int row = i / Nf, col = i - row * Nf;
  float sc = istd[col] * g[col];
  float sh = be[col] - mean[col] * sc;
  float v = fmaxf(fmaf(y[i], sc, sh), 0.f);
  xpk[pk_off(row, col, Nf)] = (f16)v;
}

// ---- IoU head -------------------------------------------------------------
__global__ void k_iou(const float* __restrict__ x, const float* __restrict__ w,
                      const float* __restrict__ b, float* __restrict__ out) {
  const int r = blockIdx.x, tid = threadIdx.x;
  float s = 0.f;
  for (int k = tid; k < 1024; k += 256) s = fmaf(x[(size_t)r * 1024 + k], w[k], s);
  __shared__ float red[256];
  red[tid] = s;
  __syncthreads();
  for (int o = 128; o > 0; o >>= 1) {
    if (tid < o) red[tid] += red[tid + o];
    __syncthreads();
  }
  if (tid == 0) out[r] = red[0] + b[0];
}

// ---------------------------------------------------------------------------
// Workspace layout (float offsets). Total ~46.2M floats = 184.8 MB.
// PART overlays A (A dead when partials live); WPK2R/WPK2RT in A's tail.
// PHPK/X2PK overlay FT (dead after last conv).
// ---------------------------------------------------------------------------
static const size_t O_A      = 0;            // 21,233,664 conv out fp32
static const size_t O_WPK2RT = 16000000;     // in A region (used post-pool_t)
static const size_t O_WPK2R  = 20000000;     // in A region (used post-pool_r)
static const size_t O_FT     = 21233664;     // 11,829,248 f16 HWC padded
static const size_t O_X2PK   = 21233664 + 6422528;  // in FT region
static const size_t O_WC     = 33062912;     //    294,912 conv w f16
static const size_t O_WPK1RT = 33357824;     //  6,422,528
static const size_t O_WPK1R  = 39780352;     //  3,276,800
static const size_t O_PRPK   = 43057152;     //    409,600
static const size_t O_Y1     = 43466752;     //  1,048,576
static const size_t O_Y2     = 44515328;     //  1,048,576
static const size_t O_MOD    = 45563904;     //     16,384
static const size_t O_WXR    = 45580288;     //     11,520
static const size_t O_WYR    = 45591808;     //     11,520
static const size_t O_ARR    = 45603328;     //         64
static const size_t O_WXT    = 45603392;     //    258,048
static const size_t O_WYT    = 45861440;     //    258,048
static const size_t O_ART    = 46119488;     //      1,024
static const size_t O_MEAN   = 46120512;     //      1,024
static const size_t O_ISTD   = 46121536;     //      1,024
static const size_t O_X1PK   = 46122560;     //     65,536
static const size_t O_META   = 46188096;     //      9,664 (ints)

extern "C" void kernel_launch(void* const* d_in, const int* in_sizes, int n_in,
                              void* d_out, int out_size, void* d_ws, size_t ws_size,
                              hipStream_t stream) {
  (void)in_sizes; (void)n_in; (void)out_size; (void)ws_size;
  const float* feat1  = (const float*)d_in[0];
  const float* feat2  = (const float*)d_in[1];
  const float* bb1    = (const float*)d_in[2];
  const float* props  = (const float*)d_in[3];
  const float* w_c1r  = (const float*)d_in[4];
  const float* b_c1r  = (const float*)d_in[5];
  const float* g_c1r  = (const float*)d_in[6];
  const float* be_c1r = (const float*)d_in[7];
  const float* w_c1t  = (const float*)d_in[8];
  const float* b_c1t  = (const float*)d_in[9];
  const float* g_c1t  = (const float*)d_in[10];
  const float* be_c1t = (const float*)d_in[11];
  const float* w_c2t  = (const float*)d_in[12];
  const float* b_c2t  = (const float*)d_in[13];
  const float* g_c2t  = (const float*)d_in[14];
  const float* be_c2t = (const float*)d_in[15];
  const float* w_f1r  = (const float*)d_in[16];
  const float* b_f1r  = (const float*)d_in[17];
  const float* g_f1r  = (const float*)d_in[18];
  const float* be_f1r = (const float*)d_in[19];
  const float* w_f2r  = (const float*)d_in[20];
  const float* b_f2r  = (const float*)d_in[21];
  const float* g_f2r  = (const float*)d_in[22];
  const float* be_f2r = (const float*)d_in[23];
  const float* w_f1rt = (const float*)d_in[24];
  const float* b_f1rt = (const float*)d_in[25];
  const float* g_f1rt = (const float*)d_in[26];
  const float* be_f1rt= (const float*)d_in[27];
  const float* w_f2rt = (const float*)d_in[28];
  const float* b_f2rt = (const float*)d_in[29];
  const float* g_f2rt = (const float*)d_in[30];
  const float* be_f2rt= (const float*)d_in[31];
  const float* w_iou  = (const float*)d_in[32];
  const float* b_iou  = (const float*)d_in[33];

  float* ws    = (float*)d_ws;
  float* A     = ws + O_A;
  float* PART  = ws + O_A;                  // overlays A
  f16*   WPK2RT= (f16*)(ws + O_WPK2RT);
  f16*   WPK2R = (f16*)(ws + O_WPK2R);
  f16*   FT    = (f16*)(ws + O_FT);
  f16*   PHPK  = FT;                        // overlays FT
  f16*   X2PK  = (f16*)(ws + O_X2PK);
  f16*   WC    = (f16*)(ws + O_WC);
  f16*   WPK1RT= (f16*)(ws + O_WPK1RT);
  f16*   WPK1R = (f16*)(ws + O_WPK1R);
  f16*   PRPK  = (f16*)(ws + O_PRPK);
  float* Y1    = ws + O_Y1;
  float* Y2    = ws + O_Y2;
  float* MODp  = ws + O_MOD;
  float* WXR   = ws + O_WXR;
  float* WYR   = ws + O_WYR;
  float* ARR   = ws + O_ARR;
  float* WXT   = ws + O_WXT;
  float* WYT   = ws + O_WYT;
  float* ART   = ws + O_ART;
  float* MEAN  = ws + O_MEAN;
  float* ISTD  = ws + O_ISTD;
  f16*   X1PK  = (f16*)(ws + O_X1PK);
  int*   META  = (int*)(ws + O_META);
  int* HLOR = META;          // 64
  int* HCNTR= META + 64;     // 64
  int* WLOR = META + 128;    // 320
  int* HLOT = META + 448;    // 1024
  int* HCNTT= META + 1472;   // 1024
  int* WLOT = META + 2496;   // 7168

  // ===== get_modulation branch =====
  k_border<<<64, 256, 0, stream>>>(FT);
  k_repack_w<<<2304, 256, 0, stream>>>(w_c1r, WC);
  k_pad<false><<<dim3(64, 36), 256, 0, stream>>>(feat1, FT, nullptr, nullptr, nullptr, nullptr);
  k_conv_mfma<<<1408, 256, 0, stream>>>(FT, WC, b_c1r, A);
  k_chan_stats<<<256, 256, 0, stream>>>(A, MEAN, ISTD);
  k_bn_relu_conv<<<20736, 256, 0, stream>>>(A, MEAN, ISTD, g_c1r, be_c1r);

  k_wxy<<<1, 64, 0, stream>>>(bb1, 64, 5, WXR, WYR, ARR, HLOR, HCNTR, WLOR);
  k_zero<<<400, 256, 0, stream>>>((float4*)PRPK, 102400);
  k_pool<5, false, false><<<dim3(64, 1), 256, 0, stream>>>(
      A, WXR, WYR, ARR, HLOR, HCNTR, WLOR, nullptr, PRPK, 1);

  k_pack_w<<<25600, 256, 0, stream>>>(w_f1r, WPK1R, 6400, 6553600);
  k_gemm_f16pk<<<dim3(8, 1, 8), 256, 0, stream>>>(PRPK, WPK1R, PART, 6400, 1024, 25, 128);
  k_reduce<<<256, 256, 0, stream>>>(PART, b_f1r, Y1, 128, 64, 1024, 8);
  k_fc_stats<<<4, 256, 0, stream>>>(Y1, 64, 1024, MEAN, ISTD);
  k_zero<<<64, 256, 0, stream>>>((float4*)X1PK, 16384);
  k_fc_bn_relu_pk<<<256, 256, 0, stream>>>(Y1, MEAN, ISTD, g_f1r, be_f1r, X1PK, 64 * 1024, 1024);

  k_pack_w<<<1024, 256, 0, stream>>>(w_f2r, WPK2R, 1024, 262144);
  k_gemm_f16pk<<<dim3(2, 1, 4), 256, 0, stream>>>(X1PK, WPK2R, PART, 1024, 256, 8, 128);
  k_reduce<<<64, 256, 0, stream>>>(PART, b_f2r, MODp, 128, 64, 256, 4);
  k_fc_stats<<<1, 256, 0, stream>>>(MODp, 64, 256, MEAN, ISTD);
  k_fc_bn_relu<<<64, 256, 0, stream>>>(MODp, MEAN, ISTD, g_f2r, be_f2r, 64 * 256, 256);

  // ===== get_iou_feat branch =====
  k_repack_w<<<2304, 256, 0, stream>>>(w_c1t, WC);
  k_pad<false><<<dim3(64, 36), 256, 0, stream>>>(feat2, FT, nullptr, nullptr, nullptr, nullptr);
  k_conv_mfma<<<1408, 256, 0, stream>>>(FT, WC, b_c1t, A);
  k_chan_stats<<<256, 256, 0, stream>>>(A, MEAN, ISTD);
  k_pad<true><<<dim3(64, 36), 256, 0, stream>>>(A, FT, MEAN, ISTD, g_c1t, be_c1t);

  k_repack_w<<<2304, 256, 0, stream>>>(w_c2t, WC);
  k_conv_mfma<<<1408, 256, 0, stream>>>(FT, WC, b_c2t, A);
  k_chan_stats<<<256, 256, 0, stream>>>(A, MEAN, ISTD);
  k_bn_relu_conv<<<20736, 256, 0, stream>>>(A, MEAN, ISTD, g_c2t, be_c2t);

  // ===== predict_iou =====
  k_wxy<<<16, 64, 0, stream>>>(props, 1024, 7, WXT, WYT, ART, HLOT, HCNTT, WLOT);
  k_pool<7, true, true><<<dim3(64, 16), 256, 0, stream>>>(
      A, WXT, WYT, ART, HLOT, HCNTT, WLOT, MODp, PHPK, 16);

  k_pack_w<<<50176, 256, 0, stream>>>(w_f1rt, WPK1RT, 12544, 12845056);
  k_gemm_f16pk<<<dim3(8, 8, 8), 256, 0, stream>>>(PHPK, WPK1RT, PART, 12544, 1024, 49, 1024);
  k_reduce<<<4096, 256, 0, stream>>>(PART, b_f1rt, Y1, 1024, 1024, 1024, 8);
  k_fc_stats<<<4, 256, 0, stream>>>(Y1, 1024, 1024, MEAN, ISTD);
  k_fc_bn_relu_pk<<<4096, 256, 0, stream>>>(Y1, MEAN, ISTD, g_f1rt, be_f1rt, X2PK, 1024 * 1024, 1024);

  k_pack_w<<<4096, 256, 0, stream>>>(w_f2rt, WPK2RT, 1024, 1048576);
  k_gemm_f16pk<<<dim3(8, 8, 4), 256, 0, stream>>>(X2PK, WPK2RT, PART, 1024, 1024, 8, 1024);
  k_reduce<<<4096, 256, 0, stream>>>(PART, b_f2rt, Y2, 1024, 1024, 1024, 4);
  k_fc_stats<<<4, 256, 0, stream>>>(Y2, 1024, 1024, MEAN, ISTD);
  k_fc_bn_relu<<<4096, 256, 0, stream>>>(Y2, MEAN, ISTD, g_f2rt, be_f2rt, 1024 * 1024, 1024);

  k_iou<<<1024, 256, 0, stream>>>(Y2, w_iou, b_iou, (float*)d_out);
}

// Round 4
// 1680.416 us; speedup vs baseline: 4.4821x; 1.2788x over previous
//
#include <hip/hip_runtime.h>
#include <cstddef>

// ---------------------------------------------------------------------------
// FPNIoUNetHR forward — round 4: deterministic two-pass FC BN stats
// (round-3 k_fc_stats was latency-bound at 253 us; 1024 threads total).
// S=64, C=256, H=W=36, N=16.
// ---------------------------------------------------------------------------

typedef _Float16 f16;
typedef __attribute__((ext_vector_type(8))) _Float16 f16x8;
typedef __attribute__((ext_vector_type(4))) float f32x4;

__device__ __forceinline__ void gload16(const void* g, void* l) {
  __builtin_amdgcn_global_load_lds((const __attribute__((address_space(1))) void*)g,
                                   (__attribute__((address_space(3))) void*)l, 16, 0, 0);
}

static __device__ __forceinline__ float hat_int(float x) {
  float u = fminf(1.f, fmaxf(-1.f, x));
  float a = 0.5f * (1.f + u) * (1.f + u);
  float b = 0.5f + u - 0.5f * u * u;
  return (u <= 0.f) ? a : b;
}

// Packed GEMM operand layout: element (row,k) of a row-major [M][K] matrix ->
// [row/128][k/32][(k/8)%4][row%128][k%8]. One k-step chunk (128 rows x 32 k)
// is 8 KB contiguous, exactly the LDS image the MFMA frag reads want.
static __device__ __forceinline__ size_t pk_off(int row, int k, int K) {
  return (size_t)(row >> 7) * ((size_t)K * 128) + (size_t)(k >> 5) * 4096
       + (size_t)((((k >> 3) & 3) * 128 + (row & 127)) * 8 + (k & 7));
}

// ---- zero helper (float4 granularity) -------------------------------------
__global__ void k_zero(float4* __restrict__ p, int n4) {
  int i = blockIdx.x * 256 + threadIdx.x;
  if (i < n4) p[i] = float4{0.f, 0.f, 0.f, 0.f};
}

// ---- zero the 148 border positions of FT per image ------------------------
__global__ void k_border(f16* __restrict__ FT) {
  const int img = blockIdx.x;
  f16* base = FT + (size_t)img * 1444 * 256;
  for (int i = threadIdx.x; i < 148 * 256; i += 256) {
    int b = i >> 8, c = i & 255;
    int r, cc;
    if (b < 38)       { r = 0;          cc = b; }
    else if (b < 76)  { r = 37;         cc = b - 38; }
    else if (b < 112) { r = b - 76 + 1; cc = 0; }
    else              { r = b - 112 + 1; cc = 37; }
    base[(r * 38 + cc) * 256 + c] = (f16)0.f;
  }
}

// ---- pad + (optional BN+ReLU) + CHW->HWC f16 convert ----------------------
template <bool BN>
__global__ void k_pad(const float* __restrict__ src, f16* __restrict__ FT,
                      const float* __restrict__ mean, const float* __restrict__ istd,
                      const float* __restrict__ g, const float* __restrict__ be) {
  const int img = blockIdx.x, h = blockIdx.y, c = threadIdx.x;
  float sc = 1.f, sh = 0.f;
  if (BN) { sc = istd[c] * g[c]; sh = be[c] - mean[c] * sc; }
  const float* sp = src + ((size_t)img * 256 + c) * 1296 + h * 36;
  f16* op = FT + ((size_t)img * 1444 + (h + 1) * 38 + 1) * 256 + c;
#pragma unroll 4
  for (int w = 0; w < 36; ++w) {
    float v = sp[w];
    if (BN) v = fmaxf(fmaf(v, sc, sh), 0.f);
    op[w * 256] = (f16)v;
  }
}

// ---- conv weights [256][256][3][3] fp32 -> [oc][t*256+c] f16 --------------
__global__ void k_repack_w(const float* __restrict__ w, f16* __restrict__ o) {
  int i = blockIdx.x * 256 + threadIdx.x;
  int oc = i / 2304;
  int k = i - oc * 2304;
  int t = k >> 8, c = k & 255;
  o[i] = (f16)w[(oc * 256 + c) * 9 + t];
}

// ---- pack fp32 [N][K] weights into packed f16 (write-coalesced) -----------
__global__ void k_pack_w(const float* __restrict__ src, f16* __restrict__ dst,
                         int K, int total) {
  int i = blockIdx.x * 256 + threadIdx.x;
  if (i >= total) return;
  const int blkSz = K * 128;
  int nt = i / blkSz;
  int wi = i - nt * blkSz;
  int ks = wi >> 12;
  int r2 = wi & 4095;
  int koct = r2 >> 10;
  int r3 = r2 & 1023;
  int col = r3 >> 3, kj = r3 & 7;
  int k = ks * 32 + koct * 8 + kj;
  int row = nt * 128 + col;
  dst[i] = (f16)src[(size_t)row * K + k];
}

// ---- 3x3 conv via MFMA implicit GEMM --------------------------------------
__global__ __launch_bounds__(256) void k_conv_mfma(
    const f16* __restrict__ FT, const f16* __restrict__ W,
    const float* __restrict__ bias, float* __restrict__ y) {
  __shared__ f16x8 sA[512];
  __shared__ f16x8 sB[512];
  const int bid = blockIdx.x;
  const int orig = (bid & 7) * 176 + (bid >> 3);   // bijective: 1408 % 8 == 0
  const int img = orig / 22;
  const int rem = orig - img * 22;
  const int oct = rem / 11;
  const int pt  = rem - oct * 11;
  const int m0 = oct * 128;
  const int p0 = pt * 128;
  const int tid = threadIdx.x;
  const int lane = tid & 63;
  const int wv = tid >> 6;
  const int wr = wv >> 1, wc = wv & 1;

  const f16* aBase = W + (size_t)(m0 + lane) * 2304 + wv * 8;
  const f16* ftImg = FT + (size_t)img * 1444 * 256;
  int pos0 = p0 + lane;
  int pc0 = min(pos0, 1295);
  int pc1 = min(pos0 + 64, 1295);
  int pb0 = ((pc0 / 36) * 38 + (pc0 % 36)) * 256;
  int pb1 = ((pc1 / 36) * 38 + (pc1 % 36)) * 256;

  char* lA = (char*)sA + wv * 2048 + lane * 16;
  char* lB = (char*)sB + wv * 2048 + lane * 16;

  f32x4 acc[4][4] = {};

  for (int ks = 0; ks < 72; ++ks) {
    const int k0 = ks * 32;
    const int t = k0 >> 8;
    const int dy = t / 3, dx = t - dy * 3;
    const int c0 = k0 & 255;
    const int tap = (dy * 38 + dx) * 256 + c0 + wv * 8;
    gload16(aBase + k0, lA);
    gload16(aBase + 64 * 2304 + k0, lA + 1024);
    gload16(ftImg + pb0 + tap, lB);
    gload16(ftImg + pb1 + tap, lB + 1024);
    __syncthreads();
    f16x8 af[4], bf[4];
#pragma unroll
    for (int i = 0; i < 4; ++i) {
      af[i] = sA[((lane >> 4) << 7) + wr * 64 + i * 16 + (lane & 15)];
      bf[i] = sB[((lane >> 4) << 7) + wc * 64 + i * 16 + (lane & 15)];
    }
#pragma unroll
    for (int i = 0; i < 4; ++i)
#pragma unroll
      for (int j = 0; j < 4; ++j)
        acc[i][j] = __builtin_amdgcn_mfma_f32_16x16x32_f16(af[i], bf[j], acc[i][j], 0, 0, 0);
    __syncthreads();
  }

  const int colb = p0 + wc * 64 + (lane & 15);
  const int rowb = m0 + wr * 64 + ((lane >> 4) << 2);
#pragma unroll
  for (int i = 0; i < 4; ++i) {
#pragma unroll
    for (int j = 0; j < 4; ++j) {
      const int col = colb + j * 16;
      if (col < 1296) {
#pragma unroll
        for (int r = 0; r < 4; ++r) {
          const int oc = rowb + i * 16 + r;
          y[((size_t)img * 256 + oc) * 1296 + col] = acc[i][j][r] + bias[oc];
        }
      }
    }
  }
}

// ---- packed split-K f16 MFMA GEMM -----------------------------------------
__global__ __launch_bounds__(256) void k_gemm_f16pk(
    const f16* __restrict__ Apk, const f16* __restrict__ Bpk,
    float* __restrict__ part, int K, int Nout, int stepsPerZ, int mrows) {
  __shared__ f16x8 sA[512];
  __shared__ f16x8 sB[512];
  const int nt = blockIdx.x, mt = blockIdx.y, z = blockIdx.z;
  const int tid = threadIdx.x;
  const int lane = tid & 63;
  const int wv = tid >> 6;
  const int wr = wv >> 1, wc = wv & 1;

  const f16* aC = Apk + (size_t)mt * K * 128;
  const f16* bC = Bpk + (size_t)nt * K * 128;
  char* lA = (char*)sA + wv * 2048 + lane * 16;
  char* lB = (char*)sB + wv * 2048 + lane * 16;

  f32x4 acc[4][4] = {};

  const int ks0 = z * stepsPerZ, ks1 = ks0 + stepsPerZ;
  for (int ks = ks0; ks < ks1; ++ks) {
    const f16* ap = aC + (size_t)ks * 4096 + wv * 1024 + lane * 8;
    const f16* bp = bC + (size_t)ks * 4096 + wv * 1024 + lane * 8;
    gload16(ap, lA);
    gload16(ap + 512, lA + 1024);
    gload16(bp, lB);
    gload16(bp + 512, lB + 1024);
    __syncthreads();
    f16x8 af[4], bf[4];
#pragma unroll
    for (int i = 0; i < 4; ++i) {
      af[i] = sA[((lane >> 4) << 7) + wr * 64 + i * 16 + (lane & 15)];
      bf[i] = sB[((lane >> 4) << 7) + wc * 64 + i * 16 + (lane & 15)];
    }
#pragma unroll
    for (int i = 0; i < 4; ++i)
#pragma unroll
      for (int j = 0; j < 4; ++j)
        acc[i][j] = __builtin_amdgcn_mfma_f32_16x16x32_f16(af[i], bf[j], acc[i][j], 0, 0, 0);
    __syncthreads();
  }

  const size_t zoff = (size_t)z * mrows * Nout;
  const int colb = nt * 128 + wc * 64 + (lane & 15);
  const int rowb = mt * 128 + wr * 64 + ((lane >> 4) << 2);
#pragma unroll
  for (int i = 0; i < 4; ++i)
#pragma unroll
    for (int j = 0; j < 4; ++j)
#pragma unroll
      for (int r = 0; r < 4; ++r)
        part[zoff + (size_t)(rowb + i * 16 + r) * Nout + colb + j * 16] = acc[i][j][r];
}

// ---- reduce split-K partials + bias ---------------------------------------
__global__ void k_reduce(const float* __restrict__ part, const float* __restrict__ bias,
                         float* __restrict__ out, int mrows, int Mout, int Nout, int sk) {
  int i = blockIdx.x * 256 + threadIdx.x;
  if (i >= Mout * Nout) return;
  int row = i / Nout, col = i - row * Nout;
  float s = bias[col];
  for (int z = 0; z < sk; ++z)
    s += part[(size_t)z * mrows * Nout + (size_t)row * Nout + col];
  out[i] = s;
}

// ---- per-channel BN stats over (s, hw) ------------------------------------
__global__ void k_chan_stats(const float* __restrict__ y,
                             float* __restrict__ mean, float* __restrict__ istd) {
  const int c = blockIdx.x, tid = threadIdx.x;
  float s = 0.f, ss = 0.f;
  for (int img = 0; img < 64; ++img) {
    const float* p = y + ((size_t)img * 256 + c) * 1296;
    for (int i = tid; i < 1296; i += 256) { float v = p[i]; s += v; ss += v * v; }
  }
  __shared__ float rs[256], rss[256];
  rs[tid] = s; rss[tid] = ss;
  __syncthreads();
  for (int o = 128; o > 0; o >>= 1) {
    if (tid < o) { rs[tid] += rs[tid + o]; rss[tid] += rss[tid + o]; }
    __syncthreads();
  }
  if (tid == 0) {
    float m = rs[0] * (1.f / 82944.f);
    float var = rss[0] * (1.f / 82944.f) - m * m;
    mean[c] = m;
    istd[c] = rsqrtf(var + 1e-5f);
  }
}

// ---- BN+ReLU elementwise on conv tensor (float4, in place) ----------------
__global__ void k_bn_relu_conv(float* __restrict__ y, const float* __restrict__ mean,
                               const float* __restrict__ istd, const float* __restrict__ g,
                               const float* __restrict__ be) {
  int i = blockIdx.x * 256 + threadIdx.x;
  int c = (i / 324) & 255;
  float sc = istd[c] * g[c];
  float sh = be[c] - mean[c] * sc;
  float4 v = reinterpret_cast<float4*>(y)[i];
  v.x = fmaxf(fmaf(v.x, sc, sh), 0.f);
  v.y = fmaxf(fmaf(v.y, sc, sh), 0.f);
  v.z = fmaxf(fmaf(v.z, sc, sh), 0.f);
  v.w = fmaxf(fmaf(v.w, sc, sh), 0.f);
  reinterpret_cast<float4*>(y)[i] = v;
}

// ---- PrRoI separable weights + sparse-range metadata ----------------------
__global__ void k_wxy(const float* __restrict__ rois, int ntot, int P,
                      float* __restrict__ Wx, float* __restrict__ Wy,
                      float* __restrict__ area,
                      int* __restrict__ HLO, int* __restrict__ HCNT,
                      int* __restrict__ WLO) {
  int idx = blockIdx.x * blockDim.x + threadIdx.x;
  if (idx >= ntot) return;
  float rx = rois[idx * 4 + 0], ry = rois[idx * 4 + 1];
  float rw = rois[idx * 4 + 2], rh = rois[idx * 4 + 3];
  float x1 = rx * 0.125f, y1 = ry * 0.125f;
  float x2 = (rx + rw) * 0.125f, y2 = (ry + rh) * 0.125f;
  float bw = (x2 - x1) / P, bh = (y2 - y1) / P;
  area[idx] = bw * bh;
  int hlo = max(0, (int)ceilf(y1 - 1.f));
  int hhi = min(35, (int)floorf(y2 + 1.f));
  HLO[idx] = hlo;
  HCNT[idx] = max(0, hhi - hlo + 1);
  for (int q = 0; q < P; ++q) {
    float xlo = x1 + q * bw, ylo = y1 + q * bh;
    WLO[idx * P + q] = min(31, max(0, (int)ceilf(xlo - 1.f)));
    for (int g = 0; g < 36; ++g) {
      float fg = (float)g;
      Wx[(idx * P + q) * 36 + g] = hat_int(xlo + bw - fg) - hat_int(xlo - fg);
      Wy[(idx * P + q) * 36 + g] = hat_int(ylo + bh - fg) - hat_int(ylo - fg);
    }
  }
}

// ---- PrRoI pool: block=(s,n), thread=channel; writes packed f16 -----------
template <int P, bool MOD, bool SPARSE>
__global__ __launch_bounds__(256) void k_pool(
    const float* __restrict__ feat, const float* __restrict__ Wx,
    const float* __restrict__ Wy, const float* __restrict__ area,
    const int* __restrict__ HLO, const int* __restrict__ HCNT,
    const int* __restrict__ WLO,
    const float* __restrict__ mod, f16* __restrict__ outPk, int N) {
  const int s = blockIdx.x, n = blockIdx.y;
  const int idx = s * N + n;
  const int c = threadIdx.x;
  constexpr int KD = P * P * 256;
  __shared__ float sWx[P * 36], sWy[P * 36];
  __shared__ int sWLO[P];
  __shared__ int sH[2];
  for (int i = threadIdx.x; i < P * 36; i += 256) {
    sWx[i] = Wx[(size_t)idx * P * 36 + i];
    sWy[i] = Wy[(size_t)idx * P * 36 + i];
  }
  if (threadIdx.x < P) sWLO[threadIdx.x] = WLO[idx * P + threadIdx.x];
  if (threadIdx.x == 0) { sH[0] = HLO[idx]; sH[1] = HCNT[idx]; }
  __syncthreads();
  const float* f = feat + ((size_t)s * 256 + c) * 1296;
  float o[P][P] = {};
  const int hlo = SPARSE ? sH[0] : 0;
  const int hcnt = SPARSE ? sH[1] : 36;
  for (int hh = 0; hh < hcnt; ++hh) {
    const int h = hlo + hh;
    const float* rp = f + h * 36;
    float colsum[P];
    if (SPARSE) {
#pragma unroll
      for (int q = 0; q < P; ++q) {
        const int w0 = sWLO[q];
        float v = 0.f;
#pragma unroll
        for (int j = 0; j < 5; ++j) v = fmaf(sWx[q * 36 + w0 + j], rp[w0 + j], v);
        colsum[q] = v;
      }
    } else {
      float row[36];
#pragma unroll
      for (int w = 0; w < 36; ++w) row[w] = rp[w];
#pragma unroll
      for (int q = 0; q < P; ++q) {
        float v = 0.f;
#pragma unroll
        for (int w = 0; w < 36; ++w) v = fmaf(sWx[q * 36 + w], row[w], v);
        colsum[q] = v;
      }
    }
#pragma unroll
    for (int p = 0; p < P; ++p) {
      const float wy = sWy[p * 36 + h];
      if (wy != 0.f) {
#pragma unroll
        for (int q = 0; q < P; ++q) o[p][q] = fmaf(wy, colsum[q], o[p][q]);
      }
    }
  }
  float a = area[idx];
  float inv = (a > 0.f) ? 1.f / fmaxf(a, 1e-12f) : 0.f;
  float msc = MOD ? (mod[s * 256 + c] * inv) : inv;
  const int kbase = c * (P * P);
#pragma unroll
  for (int p = 0; p < P; ++p)
#pragma unroll
    for (int q = 0; q < P; ++q)
      outPk[pk_off(idx, kbase + p * P + q, KD)] = (f16)(o[p][q] * msc);
}

// ---- FC BN stats, two-pass deterministic ----------------------------------
// pass 1: grid (Nf/256, nz); block z sums rows [z*rpz, z*rpz+rpz)
__global__ void k_fc_stats_part(const float* __restrict__ y, int M, int Nf, int rpz,
                                float* __restrict__ psum, float* __restrict__ psq) {
  int col = blockIdx.x * 256 + threadIdx.x;
  int z = blockIdx.y;
  if (col >= Nf) return;
  int r0 = z * rpz;
  int r1 = min(M, r0 + rpz);
  float s = 0.f, ss = 0.f;
  for (int m = r0; m < r1; ++m) {
    float v = y[(size_t)m * Nf + col];
    s += v; ss += v * v;
  }
  psum[(size_t)z * Nf + col] = s;
  psq[(size_t)z * Nf + col] = ss;
}

// pass 2: fold nz partials, emit mean/istd
__global__ void k_fc_stats_final(const float* __restrict__ psum, const float* __restrict__ psq,
                                 int nz, int Nf, int M,
                                 float* __restrict__ mean, float* __restrict__ istd) {
  int col = blockIdx.x * 256 + threadIdx.x;
  if (col >= Nf) return;
  float s = 0.f, ss = 0.f;
  for (int z = 0; z < nz; ++z) {
    s += psum[(size_t)z * Nf + col];
    ss += psq[(size_t)z * Nf + col];
  }
  float mu = s / (float)M;
  float var = ss / (float)M - mu * mu;
  mean[col] = mu;
  istd[col] = rsqrtf(var + 1e-5f);
}

// ---- FC BN+ReLU elementwise (fp32 in place) -------------------------------
__global__ void k_fc_bn_relu(float* __restrict__ y, const float* __restrict__ mean,
                             const float* __restrict__ istd, const float* __restrict__ g,
                             const float* __restrict__ be, int total, int Nf) {
  int i = blockIdx.x * 256 + threadIdx.x;
  if (i >= total) return;
  int col = i % Nf;
  float sc = istd[col] * g[col];
  float sh = be[col] - mean[col] * sc;
  y[i] = fmaxf(fmaf(y[i], sc, sh), 0.f);
}

// ---- FC BN+ReLU -> packed f16 (next GEMM's A operand) ---------------------
__global__ void k_fc_bn_relu_pk(const float* __restrict__ y, const float* __restrict__ mean,
                                const float* __restrict__ istd, const float* __restrict__ g,
                                const float* __restrict__ be, f16* __restrict__ xpk,
                                int total, int Nf) {
  int i = blockIdx.x * 256 + threadIdx.x;
  if (i >= total) return;
  int row = i / Nf, col = i - row * Nf;
  float sc = istd[col] * g[col];
  float sh = be[col] - mean[col] * sc;
  float v = fmaxf(fmaf(y[i], sc, sh), 0.f);
  xpk[pk_off(row, col, Nf)] = (f16)v;
}

// ---- IoU head -------------------------------------------------------------
__global__ void k_iou(const float* __restrict__ x, const float* __restrict__ w,
                      const float* __restrict__ b, float* __restrict__ out) {
  const int r = blockIdx.x, tid = threadIdx.x;
  float s = 0.f;
  for (int k = tid; k < 1024; k += 256) s = fmaf(x[(size_t)r * 1024 + k], w[k], s);
  __shared__ float red[256];
  red[tid] = s;
  __syncthreads();
  for (int o = 128; o > 0; o >>= 1) {
    if (tid < o) red[tid] += red[tid + o];
    __syncthreads();
  }
  if (tid == 0) out[r] = red[0] + b[0];
}

// ---------------------------------------------------------------------------
// Workspace layout (float offsets). Total ~46.2M floats = 184.8 MB.
// PART overlays A; PSUM/PSQ live at A+13M (dead zone when stats run);
// WPK2R/WPK2RT in A's tail; PHPK/X2PK overlay FT.
// ---------------------------------------------------------------------------
static const size_t O_A      = 0;            // 21,233,664 conv out fp32
static const size_t O_PSUM   = 13000000;     // 65,536 (in A region)
static const size_t O_PSQ    = 13065536;     // 65,536 (in A region)
static const size_t O_WPK2RT = 16000000;     // in A region
static const size_t O_WPK2R  = 20000000;     // in A region
static const size_t O_FT     = 21233664;     // 11,829,248 f16 HWC padded
static const size_t O_X2PK   = 21233664 + 6422528;  // in FT region
static const size_t O_WC     = 33062912;     //    294,912 conv w f16
static const size_t O_WPK1RT = 33357824;     //  6,422,528
static const size_t O_WPK1R  = 39780352;     //  3,276,800
static const size_t O_PRPK   = 43057152;     //    409,600
static const size_t O_Y1     = 43466752;     //  1,048,576
static const size_t O_Y2     = 44515328;     //  1,048,576
static const size_t O_MOD    = 45563904;     //     16,384
static const size_t O_WXR    = 45580288;     //     11,520
static const size_t O_WYR    = 45591808;     //     11,520
static const size_t O_ARR    = 45603328;     //         64
static const size_t O_WXT    = 45603392;     //    258,048
static const size_t O_WYT    = 45861440;     //    258,048
static const size_t O_ART    = 46119488;     //      1,024
static const size_t O_MEAN   = 46120512;     //      1,024
static const size_t O_ISTD   = 46121536;     //      1,024
static const size_t O_X1PK   = 46122560;     //     65,536
static const size_t O_META   = 46188096;     //      9,664 (ints)

extern "C" void kernel_launch(void* const* d_in, const int* in_sizes, int n_in,
                              void* d_out, int out_size, void* d_ws, size_t ws_size,
                              hipStream_t stream) {
  (void)in_sizes; (void)n_in; (void)out_size; (void)ws_size;
  const float* feat1  = (const float*)d_in[0];
  const float* feat2  = (const float*)d_in[1];
  const float* bb1    = (const float*)d_in[2];
  const float* props  = (const float*)d_in[3];
  const float* w_c1r  = (const float*)d_in[4];
  const float* b_c1r  = (const float*)d_in[5];
  const float* g_c1r  = (const float*)d_in[6];
  const float* be_c1r = (const float*)d_in[7];
  const float* w_c1t  = (const float*)d_in[8];
  const float* b_c1t  = (const float*)d_in[9];
  const float* g_c1t  = (const float*)d_in[10];
  const float* be_c1t = (const float*)d_in[11];
  const float* w_c2t  = (const float*)d_in[12];
  const float* b_c2t  = (const float*)d_in[13];
  const float* g_c2t  = (const float*)d_in[14];
  const float* be_c2t = (const float*)d_in[15];
  const float* w_f1r  = (const float*)d_in[16];
  const float* b_f1r  = (const float*)d_in[17];
  const float* g_f1r  = (const float*)d_in[18];
  const float* be_f1r = (const float*)d_in[19];
  const float* w_f2r  = (const float*)d_in[20];
  const float* b_f2r  = (const float*)d_in[21];
  const float* g_f2r  = (const float*)d_in[22];
  const float* be_f2r = (const float*)d_in[23];
  const float* w_f1rt = (const float*)d_in[24];
  const float* b_f1rt = (const float*)d_in[25];
  const float* g_f1rt = (const float*)d_in[26];
  const float* be_f1rt= (const float*)d_in[27];
  const float* w_f2rt = (const float*)d_in[28];
  const float* b_f2rt = (const float*)d_in[29];
  const float* g_f2rt = (const float*)d_in[30];
  const float* be_f2rt= (const float*)d_in[31];
  const float* w_iou  = (const float*)d_in[32];
  const float* b_iou  = (const float*)d_in[33];

  float* ws    = (float*)d_ws;
  float* A     = ws + O_A;
  float* PART  = ws + O_A;                  // overlays A
  float* PSUM  = ws + O_PSUM;
  float* PSQ   = ws + O_PSQ;
  f16*   WPK2RT= (f16*)(ws + O_WPK2RT);
  f16*   WPK2R = (f16*)(ws + O_WPK2R);
  f16*   FT    = (f16*)(ws + O_FT);
  f16*   PHPK  = FT;                        // overlays FT
  f16*   X2PK  = (f16*)(ws + O_X2PK);
  f16*   WC    = (f16*)(ws + O_WC);
  f16*   WPK1RT= (f16*)(ws + O_WPK1RT);
  f16*   WPK1R = (f16*)(ws + O_WPK1R);
  f16*   PRPK  = (f16*)(ws + O_PRPK);
  float* Y1    = ws + O_Y1;
  float* Y2    = ws + O_Y2;
  float* MODp  = ws + O_MOD;
  float* WXR   = ws + O_WXR;
  float* WYR   = ws + O_WYR;
  float* ARR   = ws + O_ARR;
  float* WXT   = ws + O_WXT;
  float* WYT   = ws + O_WYT;
  float* ART   = ws + O_ART;
  float* MEAN  = ws + O_MEAN;
  float* ISTD  = ws + O_ISTD;
  f16*   X1PK  = (f16*)(ws + O_X1PK);
  int*   META  = (int*)(ws + O_META);
  int* HLOR = META;          // 64
  int* HCNTR= META + 64;     // 64
  int* WLOR = META + 128;    // 320
  int* HLOT = META + 448;    // 1024
  int* HCNTT= META + 1472;   // 1024
  int* WLOT = META + 2496;   // 7168

  // ===== get_modulation branch =====
  k_border<<<64, 256, 0, stream>>>(FT);
  k_repack_w<<<2304, 256, 0, stream>>>(w_c1r, WC);
  k_pad<false><<<dim3(64, 36), 256, 0, stream>>>(feat1, FT, nullptr, nullptr, nullptr, nullptr);
  k_conv_mfma<<<1408, 256, 0, stream>>>(FT, WC, b_c1r, A);
  k_chan_stats<<<256, 256, 0, stream>>>(A, MEAN, ISTD);
  k_bn_relu_conv<<<20736, 256, 0, stream>>>(A, MEAN, ISTD, g_c1r, be_c1r);

  k_wxy<<<1, 64, 0, stream>>>(bb1, 64, 5, WXR, WYR, ARR, HLOR, HCNTR, WLOR);
  k_zero<<<400, 256, 0, stream>>>((float4*)PRPK, 102400);
  k_pool<5, false, false><<<dim3(64, 1), 256, 0, stream>>>(
      A, WXR, WYR, ARR, HLOR, HCNTR, WLOR, nullptr, PRPK, 1);

  k_pack_w<<<25600, 256, 0, stream>>>(w_f1r, WPK1R, 6400, 6553600);
  k_gemm_f16pk<<<dim3(8, 1, 8), 256, 0, stream>>>(PRPK, WPK1R, PART, 6400, 1024, 25, 128);
  k_reduce<<<256, 256, 0, stream>>>(PART, b_f1r, Y1, 128, 64, 1024, 8);
  k_fc_stats_part<<<dim3(4, 8), 256, 0, stream>>>(Y1, 64, 1024, 8, PSUM, PSQ);
  k_fc_stats_final<<<4, 256, 0, stream>>>(PSUM, PSQ, 8, 1024, 64, MEAN, ISTD);
  k_zero<<<64, 256, 0, stream>>>((float4*)X1PK, 16384);
  k_fc_bn_relu_pk<<<256, 256, 0, stream>>>(Y1, MEAN, ISTD, g_f1r, be_f1r, X1PK, 64 * 1024, 1024);

  k_pack_w<<<1024, 256, 0, stream>>>(w_f2r, WPK2R, 1024, 262144);
  k_gemm_f16pk<<<dim3(2, 1, 4), 256, 0, stream>>>(X1PK, WPK2R, PART, 1024, 256, 8, 128);
  k_reduce<<<64, 256, 0, stream>>>(PART, b_f2r, MODp, 128, 64, 256, 4);
  k_fc_stats_part<<<dim3(1, 8), 256, 0, stream>>>(MODp, 64, 256, 8, PSUM, PSQ);
  k_fc_stats_final<<<1, 256, 0, stream>>>(PSUM, PSQ, 8, 256, 64, MEAN, ISTD);
  k_fc_bn_relu<<<64, 256, 0, stream>>>(MODp, MEAN, ISTD, g_f2r, be_f2r, 64 * 256, 256);

  // ===== get_iou_feat branch =====
  k_repack_w<<<2304, 256, 0, stream>>>(w_c1t, WC);
  k_pad<false><<<dim3(64, 36), 256, 0, stream>>>(feat2, FT, nullptr, nullptr, nullptr, nullptr);
  k_conv_mfma<<<1408, 256, 0, stream>>>(FT, WC, b_c1t, A);
  k_chan_stats<<<256, 256, 0, stream>>>(A, MEAN, ISTD);
  k_pad<true><<<dim3(64, 36), 256, 0, stream>>>(A, FT, MEAN, ISTD, g_c1t, be_c1t);

  k_repack_w<<<2304, 256, 0, stream>>>(w_c2t, WC);
  k_conv_mfma<<<1408, 256, 0, stream>>>(FT, WC, b_c2t, A);
  k_chan_stats<<<256, 256, 0, stream>>>(A, MEAN, ISTD);
  k_bn_relu_conv<<<20736, 256, 0, stream>>>(A, MEAN, ISTD, g_c2t, be_c2t);

  // ===== predict_iou =====
  k_wxy<<<16, 64, 0, stream>>>(props, 1024, 7, WXT, WYT, ART, HLOT, HCNTT, WLOT);
  k_pool<7, true, true><<<dim3(64, 16), 256, 0, stream>>>(
      A, WXT, WYT, ART, HLOT, HCNTT, WLOT, MODp, PHPK, 16);

  k_pack_w<<<50176, 256, 0, stream>>>(w_f1rt, WPK1RT, 12544, 12845056);
  k_gemm_f16pk<<<dim3(8, 8, 8), 256, 0, stream>>>(PHPK, WPK1RT, PART, 12544, 1024, 49, 1024);
  k_reduce<<<4096, 256, 0, stream>>>(PART, b_f1rt, Y1, 1024, 1024, 1024, 8);
  k_fc_stats_part<<<dim3(4, 64), 256, 0, stream>>>(Y1, 1024, 1024, 16, PSUM, PSQ);
  k_fc_stats_final<<<4, 256, 0, stream>>>(PSUM, PSQ, 64, 1024, 1024, MEAN, ISTD);
  k_fc_bn_relu_pk<<<4096, 256, 0, stream>>>(Y1, MEAN, ISTD, g_f1rt, be_f1rt, X2PK, 1024 * 1024, 1024);

  k_pack_w<<<4096, 256, 0, stream>>>(w_f2rt, WPK2RT, 1024, 1048576);
  k_gemm_f16pk<<<dim3(8, 8, 4), 256, 0, stream>>>(X2PK, WPK2RT, PART, 1024, 1024, 8, 1024);
  k_reduce<<<4096, 256, 0, stream>>>(PART, b_f2rt, Y2, 1024, 1024, 1024, 4);
  k_fc_stats_part<<<dim3(4, 64), 256, 0, stream>>>(Y2, 1024, 1024, 16, PSUM, PSQ);
  k_fc_stats_final<<<4, 256, 0, stream>>>(PSUM, PSQ, 64, 1024, 1024, MEAN, ISTD);
  k_fc_bn_relu<<<4096, 256, 0, stream>>>(Y2, MEAN, ISTD, g_f2rt, be_f2rt, 1024 * 1024, 1024);

  k_iou<<<1024, 256, 0, stream>>>(Y2, w_iou, b_iou, (float*)d_out);
}

// Round 5
// 1368.761 us; speedup vs baseline: 5.5026x; 1.2277x over previous
//
#include <hip/hip_runtime.h>
#include <cstddef>

// ---------------------------------------------------------------------------
// FPNIoUNetHR forward — round 5: 2-phase double-buffered MFMA staging,
// two-pass conv BN stats, sparse pool_r.
// S=64, C=256, H=W=36, N=16.
// ---------------------------------------------------------------------------

typedef _Float16 f16;
typedef __attribute__((ext_vector_type(8))) _Float16 f16x8;
typedef __attribute__((ext_vector_type(4))) float f32x4;

__device__ __forceinline__ void gload16(const void* g, void* l) {
  __builtin_amdgcn_global_load_lds((const __attribute__((address_space(1))) void*)g,
                                   (__attribute__((address_space(3))) void*)l, 16, 0, 0);
}

static __device__ __forceinline__ float hat_int(float x) {
  float u = fminf(1.f, fmaxf(-1.f, x));
  float a = 0.5f * (1.f + u) * (1.f + u);
  float b = 0.5f + u - 0.5f * u * u;
  return (u <= 0.f) ? a : b;
}

// Packed GEMM operand layout: element (row,k) of a row-major [M][K] matrix ->
// [row/128][k/32][(k/8)%4][row%128][k%8]. One k-step chunk (128 rows x 32 k)
// is 8 KB contiguous, exactly the LDS image the MFMA frag reads want.
static __device__ __forceinline__ size_t pk_off(int row, int k, int K) {
  return (size_t)(row >> 7) * ((size_t)K * 128) + (size_t)(k >> 5) * 4096
       + (size_t)((((k >> 3) & 3) * 128 + (row & 127)) * 8 + (k & 7));
}

// ---- zero helper (float4 granularity) -------------------------------------
__global__ void k_zero(float4* __restrict__ p, int n4) {
  int i = blockIdx.x * 256 + threadIdx.x;
  if (i < n4) p[i] = float4{0.f, 0.f, 0.f, 0.f};
}

// ---- zero the 148 border positions of FT per image ------------------------
__global__ void k_border(f16* __restrict__ FT) {
  const int img = blockIdx.x;
  f16* base = FT + (size_t)img * 1444 * 256;
  for (int i = threadIdx.x; i < 148 * 256; i += 256) {
    int b = i >> 8, c = i & 255;
    int r, cc;
    if (b < 38)       { r = 0;          cc = b; }
    else if (b < 76)  { r = 37;         cc = b - 38; }
    else if (b < 112) { r = b - 76 + 1; cc = 0; }
    else              { r = b - 112 + 1; cc = 37; }
    base[(r * 38 + cc) * 256 + c] = (f16)0.f;
  }
}

// ---- pad + (optional BN+ReLU) + CHW->HWC f16 convert ----------------------
template <bool BN>
__global__ void k_pad(const float* __restrict__ src, f16* __restrict__ FT,
                      const float* __restrict__ mean, const float* __restrict__ istd,
                      const float* __restrict__ g, const float* __restrict__ be) {
  const int img = blockIdx.x, h = blockIdx.y, c = threadIdx.x;
  float sc = 1.f, sh = 0.f;
  if (BN) { sc = istd[c] * g[c]; sh = be[c] - mean[c] * sc; }
  const float* sp = src + ((size_t)img * 256 + c) * 1296 + h * 36;
  f16* op = FT + ((size_t)img * 1444 + (h + 1) * 38 + 1) * 256 + c;
#pragma unroll 4
  for (int w = 0; w < 36; ++w) {
    float v = sp[w];
    if (BN) v = fmaxf(fmaf(v, sc, sh), 0.f);
    op[w * 256] = (f16)v;
  }
}

// ---- conv weights [256][256][3][3] fp32 -> [oc][t*256+c] f16 --------------
__global__ void k_repack_w(const float* __restrict__ w, f16* __restrict__ o) {
  int i = blockIdx.x * 256 + threadIdx.x;
  int oc = i / 2304;
  int k = i - oc * 2304;
  int t = k >> 8, c = k & 255;
  o[i] = (f16)w[(oc * 256 + c) * 9 + t];
}

// ---- pack fp32 [N][K] weights into packed f16 (write-coalesced) -----------
__global__ void k_pack_w(const float* __restrict__ src, f16* __restrict__ dst,
                         int K, int total) {
  int i = blockIdx.x * 256 + threadIdx.x;
  if (i >= total) return;
  const int blkSz = K * 128;
  int nt = i / blkSz;
  int wi = i - nt * blkSz;
  int ks = wi >> 12;
  int r2 = wi & 4095;
  int koct = r2 >> 10;
  int r3 = r2 & 1023;
  int col = r3 >> 3, kj = r3 & 7;
  int k = ks * 32 + koct * 8 + kj;
  int row = nt * 128 + col;
  dst[i] = (f16)src[(size_t)row * K + k];
}

// ---- 3x3 conv via MFMA implicit GEMM, 2-phase double-buffered -------------
__global__ __launch_bounds__(256) void k_conv_mfma(
    const f16* __restrict__ FT, const f16* __restrict__ W,
    const float* __restrict__ bias, float* __restrict__ y) {
  __shared__ f16x8 sA[1024];   // 2 buffers x 512
  __shared__ f16x8 sB[1024];
  const int bid = blockIdx.x;
  const int orig = (bid & 7) * 176 + (bid >> 3);   // bijective: 1408 % 8 == 0
  const int img = orig / 22;
  const int rem = orig - img * 22;
  const int oct = rem / 11;
  const int pt  = rem - oct * 11;
  const int m0 = oct * 128;
  const int p0 = pt * 128;
  const int tid = threadIdx.x;
  const int lane = tid & 63;
  const int wv = tid >> 6;
  const int wr = wv >> 1, wc = wv & 1;

  const f16* aBase = W + (size_t)(m0 + lane) * 2304 + wv * 8;
  const f16* ftImg = FT + (size_t)img * 1444 * 256;
  int pos0 = p0 + lane;
  int pc0 = min(pos0, 1295);
  int pc1 = min(pos0 + 64, 1295);
  int pb0 = ((pc0 / 36) * 38 + (pc0 % 36)) * 256;
  int pb1 = ((pc1 / 36) * 38 + (pc1 % 36)) * 256;

  const int loff = wv * 2048 + lane * 16;

  auto stage = [&](int buf, int ks) {
    const int k0 = ks * 32;
    const int t = k0 >> 8;
    const int dy = t / 3, dx = t - dy * 3;
    const int c0 = k0 & 255;
    const int tap = (dy * 38 + dx) * 256 + c0 + wv * 8;
    char* lA = (char*)sA + buf * 8192 + loff;
    char* lB = (char*)sB + buf * 8192 + loff;
    gload16(aBase + k0, lA);
    gload16(aBase + 64 * 2304 + k0, lA + 1024);
    gload16(ftImg + pb0 + tap, lB);
    gload16(ftImg + pb1 + tap, lB + 1024);
  };

  f32x4 acc[4][4] = {};
  const int fidxA = ((lane >> 4) << 7) + wr * 64 + (lane & 15);
  const int fidxB = ((lane >> 4) << 7) + wc * 64 + (lane & 15);

  stage(0, 0);
  __syncthreads();
  int cur = 0;
  for (int ks = 0; ks < 72; ++ks) {
    if (ks < 71) stage(cur ^ 1, ks + 1);
    f16x8 af[4], bf[4];
#pragma unroll
    for (int i = 0; i < 4; ++i) {
      af[i] = sA[cur * 512 + fidxA + i * 16];
      bf[i] = sB[cur * 512 + fidxB + i * 16];
    }
#pragma unroll
    for (int i = 0; i < 4; ++i)
#pragma unroll
      for (int j = 0; j < 4; ++j)
        acc[i][j] = __builtin_amdgcn_mfma_f32_16x16x32_f16(af[i], bf[j], acc[i][j], 0, 0, 0);
    __syncthreads();
    cur ^= 1;
  }

  const int colb = p0 + wc * 64 + (lane & 15);
  const int rowb = m0 + wr * 64 + ((lane >> 4) << 2);
#pragma unroll
  for (int i = 0; i < 4; ++i) {
#pragma unroll
    for (int j = 0; j < 4; ++j) {
      const int col = colb + j * 16;
      if (col < 1296) {
#pragma unroll
        for (int r = 0; r < 4; ++r) {
          const int oc = rowb + i * 16 + r;
          y[((size_t)img * 256 + oc) * 1296 + col] = acc[i][j][r] + bias[oc];
        }
      }
    }
  }
}

// ---- packed split-K f16 MFMA GEMM, 2-phase double-buffered ----------------
__global__ __launch_bounds__(256) void k_gemm_f16pk(
    const f16* __restrict__ Apk, const f16* __restrict__ Bpk,
    float* __restrict__ part, int K, int Nout, int stepsPerZ, int mrows) {
  __shared__ f16x8 sA[1024];
  __shared__ f16x8 sB[1024];
  const int nt = blockIdx.x, mt = blockIdx.y, z = blockIdx.z;
  const int tid = threadIdx.x;
  const int lane = tid & 63;
  const int wv = tid >> 6;
  const int wr = wv >> 1, wc = wv & 1;

  const f16* aC = Apk + (size_t)mt * K * 128 + wv * 1024 + lane * 8;
  const f16* bC = Bpk + (size_t)nt * K * 128 + wv * 1024 + lane * 8;
  const int loff = wv * 2048 + lane * 16;

  auto stage = [&](int buf, int ks) {
    char* lA = (char*)sA + buf * 8192 + loff;
    char* lB = (char*)sB + buf * 8192 + loff;
    const f16* ap = aC + (size_t)ks * 4096;
    const f16* bp = bC + (size_t)ks * 4096;
    gload16(ap, lA);
    gload16(ap + 512, lA + 1024);
    gload16(bp, lB);
    gload16(bp + 512, lB + 1024);
  };

  f32x4 acc[4][4] = {};
  const int fidxA = ((lane >> 4) << 7) + wr * 64 + (lane & 15);
  const int fidxB = ((lane >> 4) << 7) + wc * 64 + (lane & 15);

  const int ks0 = z * stepsPerZ;
  stage(0, ks0);
  __syncthreads();
  int cur = 0;
  for (int i = 0; i < stepsPerZ; ++i) {
    if (i + 1 < stepsPerZ) stage(cur ^ 1, ks0 + i + 1);
    f16x8 af[4], bf[4];
#pragma unroll
    for (int j = 0; j < 4; ++j) {
      af[j] = sA[cur * 512 + fidxA + j * 16];
      bf[j] = sB[cur * 512 + fidxB + j * 16];
    }
#pragma unroll
    for (int ii = 0; ii < 4; ++ii)
#pragma unroll
      for (int jj = 0; jj < 4; ++jj)
        acc[ii][jj] = __builtin_amdgcn_mfma_f32_16x16x32_f16(af[ii], bf[jj], acc[ii][jj], 0, 0, 0);
    __syncthreads();
    cur ^= 1;
  }

  const size_t zoff = (size_t)z * mrows * Nout;
  const int colb = nt * 128 + wc * 64 + (lane & 15);
  const int rowb = mt * 128 + wr * 64 + ((lane >> 4) << 2);
#pragma unroll
  for (int i = 0; i < 4; ++i)
#pragma unroll
    for (int j = 0; j < 4; ++j)
#pragma unroll
      for (int r = 0; r < 4; ++r)
        part[zoff + (size_t)(rowb + i * 16 + r) * Nout + colb + j * 16] = acc[i][j][r];
}

// ---- reduce split-K partials + bias ---------------------------------------
__global__ void k_reduce(const float* __restrict__ part, const float* __restrict__ bias,
                         float* __restrict__ out, int mrows, int Mout, int Nout, int sk) {
  int i = blockIdx.x * 256 + threadIdx.x;
  if (i >= Mout * Nout) return;
  int row = i / Nout, col = i - row * Nout;
  float s = bias[col];
  for (int z = 0; z < sk; ++z)
    s += part[(size_t)z * mrows * Nout + (size_t)row * Nout + col];
  out[i] = s;
}

// ---- conv BN stats, two-pass: pass 1 over 4-image groups ------------------
__global__ void k_chan_stats_part(const float* __restrict__ y,
                                  float* __restrict__ psum, float* __restrict__ psq) {
  const int c = blockIdx.x, z = blockIdx.y, tid = threadIdx.x;
  float s = 0.f, ss = 0.f;
  for (int img = z * 4; img < z * 4 + 4; ++img) {
    const float* p = y + ((size_t)img * 256 + c) * 1296;
    for (int i = tid; i < 1296; i += 256) { float v = p[i]; s += v; ss += v * v; }
  }
  __shared__ float rs[256], rss[256];
  rs[tid] = s; rss[tid] = ss;
  __syncthreads();
  for (int o = 128; o > 0; o >>= 1) {
    if (tid < o) { rs[tid] += rs[tid + o]; rss[tid] += rss[tid + o]; }
    __syncthreads();
  }
  if (tid == 0) {
    psum[z * 256 + c] = rs[0];
    psq[z * 256 + c] = rss[0];
  }
}

// pass 2: fold 16 partials per channel
__global__ void k_chan_stats_final(const float* __restrict__ psum, const float* __restrict__ psq,
                                   float* __restrict__ mean, float* __restrict__ istd) {
  const int c = threadIdx.x;
  float s = 0.f, ss = 0.f;
  for (int z = 0; z < 16; ++z) { s += psum[z * 256 + c]; ss += psq[z * 256 + c]; }
  float m = s * (1.f / 82944.f);
  float var = ss * (1.f / 82944.f) - m * m;
  mean[c] = m;
  istd[c] = rsqrtf(var + 1e-5f);
}

// ---- BN+ReLU elementwise on conv tensor (float4, in place) ----------------
__global__ void k_bn_relu_conv(float* __restrict__ y, const float* __restrict__ mean,
                               const float* __restrict__ istd, const float* __restrict__ g,
                               const float* __restrict__ be) {
  int i = blockIdx.x * 256 + threadIdx.x;
  int c = (i / 324) & 255;
  float sc = istd[c] * g[c];
  float sh = be[c] - mean[c] * sc;
  float4 v = reinterpret_cast<float4*>(y)[i];
  v.x = fmaxf(fmaf(v.x, sc, sh), 0.f);
  v.y = fmaxf(fmaf(v.y, sc, sh), 0.f);
  v.z = fmaxf(fmaf(v.z, sc, sh), 0.f);
  v.w = fmaxf(fmaf(v.w, sc, sh), 0.f);
  reinterpret_cast<float4*>(y)[i] = v;
}

// ---- PrRoI separable weights + sparse-range metadata ----------------------
__global__ void k_wxy(const float* __restrict__ rois, int ntot, int P,
                      float* __restrict__ Wx, float* __restrict__ Wy,
                      float* __restrict__ area,
                      int* __restrict__ HLO, int* __restrict__ HCNT,
                      int* __restrict__ WLO) {
  int idx = blockIdx.x * blockDim.x + threadIdx.x;
  if (idx >= ntot) return;
  float rx = rois[idx * 4 + 0], ry = rois[idx * 4 + 1];
  float rw = rois[idx * 4 + 2], rh = rois[idx * 4 + 3];
  float x1 = rx * 0.125f, y1 = ry * 0.125f;
  float x2 = (rx + rw) * 0.125f, y2 = (ry + rh) * 0.125f;
  float bw = (x2 - x1) / P, bh = (y2 - y1) / P;
  area[idx] = bw * bh;
  int hlo = max(0, (int)ceilf(y1 - 1.f));
  int hhi = min(35, (int)floorf(y2 + 1.f));
  HLO[idx] = hlo;
  HCNT[idx] = max(0, hhi - hlo + 1);
  for (int q = 0; q < P; ++q) {
    float xlo = x1 + q * bw, ylo = y1 + q * bh;
    WLO[idx * P + q] = min(31, max(0, (int)ceilf(xlo - 1.f)));
    for (int g = 0; g < 36; ++g) {
      float fg = (float)g;
      Wx[(idx * P + q) * 36 + g] = hat_int(xlo + bw - fg) - hat_int(xlo - fg);
      Wy[(idx * P + q) * 36 + g] = hat_int(ylo + bh - fg) - hat_int(ylo - fg);
    }
  }
}

// ---- PrRoI pool: block=(s,n), thread=channel; writes packed f16 -----------
// SPARSE: h restricted to active rows; 5-wide x windows (support <= 5 taps
// for both P=5 (bw<=2.5) and P=7 (bw<=1.79); wave-uniform bounds).
template <int P, bool MOD, bool SPARSE>
__global__ __launch_bounds__(256) void k_pool(
    const float* __restrict__ feat, const float* __restrict__ Wx,
    const float* __restrict__ Wy, const float* __restrict__ area,
    const int* __restrict__ HLO, const int* __restrict__ HCNT,
    const int* __restrict__ WLO,
    const float* __restrict__ mod, f16* __restrict__ outPk, int N) {
  const int s = blockIdx.x, n = blockIdx.y;
  const int idx = s * N + n;
  const int c = threadIdx.x;
  constexpr int KD = P * P * 256;
  __shared__ float sWx[P * 36], sWy[P * 36];
  __shared__ int sWLO[P];
  __shared__ int sH[2];
  for (int i = threadIdx.x; i < P * 36; i += 256) {
    sWx[i] = Wx[(size_t)idx * P * 36 + i];
    sWy[i] = Wy[(size_t)idx * P * 36 + i];
  }
  if (threadIdx.x < P) sWLO[threadIdx.x] = WLO[idx * P + threadIdx.x];
  if (threadIdx.x == 0) { sH[0] = HLO[idx]; sH[1] = HCNT[idx]; }
  __syncthreads();
  const float* f = feat + ((size_t)s * 256 + c) * 1296;
  float o[P][P] = {};
  const int hlo = SPARSE ? sH[0] : 0;
  const int hcnt = SPARSE ? sH[1] : 36;
  for (int hh = 0; hh < hcnt; ++hh) {
    const int h = hlo + hh;
    const float* rp = f + h * 36;
    float colsum[P];
    if (SPARSE) {
#pragma unroll
      for (int q = 0; q < P; ++q) {
        const int w0 = sWLO[q];
        float v = 0.f;
#pragma unroll
        for (int j = 0; j < 5; ++j) v = fmaf(sWx[q * 36 + w0 + j], rp[w0 + j], v);
        colsum[q] = v;
      }
    } else {
      float row[36];
#pragma unroll
      for (int w = 0; w < 36; ++w) row[w] = rp[w];
#pragma unroll
      for (int q = 0; q < P; ++q) {
        float v = 0.f;
#pragma unroll
        for (int w = 0; w < 36; ++w) v = fmaf(sWx[q * 36 + w], row[w], v);
        colsum[q] = v;
      }
    }
#pragma unroll
    for (int p = 0; p < P; ++p) {
      const float wy = sWy[p * 36 + h];
      if (wy != 0.f) {
#pragma unroll
        for (int q = 0; q < P; ++q) o[p][q] = fmaf(wy, colsum[q], o[p][q]);
      }
    }
  }
  float a = area[idx];
  float inv = (a > 0.f) ? 1.f / fmaxf(a, 1e-12f) : 0.f;
  float msc = MOD ? (mod[s * 256 + c] * inv) : inv;
  const int kbase = c * (P * P);
#pragma unroll
  for (int p = 0; p < P; ++p)
#pragma unroll
    for (int q = 0; q < P; ++q)
      outPk[pk_off(idx, kbase + p * P + q, KD)] = (f16)(o[p][q] * msc);
}

// ---- FC BN stats, two-pass deterministic ----------------------------------
__global__ void k_fc_stats_part(const float* __restrict__ y, int M, int Nf, int rpz,
                                float* __restrict__ psum, float* __restrict__ psq) {
  int col = blockIdx.x * 256 + threadIdx.x;
  int z = blockIdx.y;
  if (col >= Nf) return;
  int r0 = z * rpz;
  int r1 = min(M, r0 + rpz);
  float s = 0.f, ss = 0.f;
  for (int m = r0; m < r1; ++m) {
    float v = y[(size_t)m * Nf + col];
    s += v; ss += v * v;
  }
  psum[(size_t)z * Nf + col] = s;
  psq[(size_t)z * Nf + col] = ss;
}

__global__ void k_fc_stats_final(const float* __restrict__ psum, const float* __restrict__ psq,
                                 int nz, int Nf, int M,
                                 float* __restrict__ mean, float* __restrict__ istd) {
  int col = blockIdx.x * 256 + threadIdx.x;
  if (col >= Nf) return;
  float s = 0.f, ss = 0.f;
  for (int z = 0; z < nz; ++z) {
    s += psum[(size_t)z * Nf + col];
    ss += psq[(size_t)z * Nf + col];
  }
  float mu = s / (float)M;
  float var = ss / (float)M - mu * mu;
  mean[col] = mu;
  istd[col] = rsqrtf(var + 1e-5f);
}

// ---- FC BN+ReLU elementwise (fp32 in place) -------------------------------
__global__ void k_fc_bn_relu(float* __restrict__ y, const float* __restrict__ mean,
                             const float* __restrict__ istd, const float* __restrict__ g,
                             const float* __restrict__ be, int total, int Nf) {
  int i = blockIdx.x * 256 + threadIdx.x;
  if (i >= total) return;
  int col = i % Nf;
  float sc = istd[col] * g[col];
  float sh = be[col] - mean[col] * sc;
  y[i] = fmaxf(fmaf(y[i], sc, sh), 0.f);
}

// ---- FC BN+ReLU -> packed f16 (next GEMM's A operand) ---------------------
__global__ void k_fc_bn_relu_pk(const float* __restrict__ y, const float* __restrict__ mean,
                                const float* __restrict__ istd, const float* __restrict__ g,
                                const float* __restrict__ be, f16* __restrict__ xpk,
                                int total, int Nf) {
  int i = blockIdx.x * 256 + threadIdx.x;
  if (i >= total) return;
  int row = i / Nf, col = i - row * Nf;
  float sc = istd[col] * g[col];
  float sh = be[col] - mean[col] * sc;
  float v = fmaxf(fmaf(y[i], sc, sh), 0.f);
  xpk[pk_off(row, col, Nf)] = (f16)v;
}

// ---- IoU head -------------------------------------------------------------
__global__ void k_iou(const float* __restrict__ x, const float* __restrict__ w,
                      const float* __restrict__ b, float* __restrict__ out) {
  const int r = blockIdx.x, tid = threadIdx.x;
  float s = 0.f;
  for (int k = tid; k < 1024; k += 256) s = fmaf(x[(size_t)r * 1024 + k], w[k], s);
  __shared__ float red[256];
  red[tid] = s;
  __syncthreads();
  for (int o = 128; o > 0; o >>= 1) {
    if (tid < o) red[tid] += red[tid + o];
    __syncthreads();
  }
  if (tid == 0) out[r] = red[0] + b[0];
}

// ---------------------------------------------------------------------------
// Workspace layout (float offsets). Total ~46.21M floats = 184.9 MB.
// PART overlays A; fc-stats PSUM/PSQ at A+13M (A dead there when used);
// chan-stats partials in dedicated PSC region (A is live).
// ---------------------------------------------------------------------------
static const size_t O_A      = 0;            // 21,233,664 conv out fp32
static const size_t O_PSUM   = 13000000;     // 65,536 (in A region, fc only)
static const size_t O_PSQ    = 13065536;     // 65,536 (in A region, fc only)
static const size_t O_WPK2RT = 16000000;     // in A region
static const size_t O_WPK2R  = 20000000;     // in A region
static const size_t O_FT     = 21233664;     // 11,829,248 f16 HWC padded
static const size_t O_X2PK   = 21233664 + 6422528;  // in FT region
static const size_t O_WC     = 33062912;     //    294,912 conv w f16
static const size_t O_WPK1RT = 33357824;     //  6,422,528
static const size_t O_WPK1R  = 39780352;     //  3,276,800
static const size_t O_PRPK   = 43057152;     //    409,600
static const size_t O_Y1     = 43466752;     //  1,048,576
static const size_t O_Y2     = 44515328;     //  1,048,576
static const size_t O_MOD    = 45563904;     //     16,384
static const size_t O_WXR    = 45580288;     //     11,520
static const size_t O_WYR    = 45591808;     //     11,520
static const size_t O_ARR    = 45603328;     //         64
static const size_t O_WXT    = 45603392;     //    258,048
static const size_t O_WYT    = 45861440;     //    258,048
static const size_t O_ART    = 46119488;     //      1,024
static const size_t O_MEAN   = 46120512;     //      1,024
static const size_t O_ISTD   = 46121536;     //      1,024
static const size_t O_X1PK   = 46122560;     //     65,536
static const size_t O_META   = 46188096;     //      9,664 (ints)
static const size_t O_PSC    = 46197760;     //      8,192 (chan-stats partials)

extern "C" void kernel_launch(void* const* d_in, const int* in_sizes, int n_in,
                              void* d_out, int out_size, void* d_ws, size_t ws_size,
                              hipStream_t stream) {
  (void)in_sizes; (void)n_in; (void)out_size; (void)ws_size;
  const float* feat1  = (const float*)d_in[0];
  const float* feat2  = (const float*)d_in[1];
  const float* bb1    = (const float*)d_in[2];
  const float* props  = (const float*)d_in[3];
  const float* w_c1r  = (const float*)d_in[4];
  const float* b_c1r  = (const float*)d_in[5];
  const float* g_c1r  = (const float*)d_in[6];
  const float* be_c1r = (const float*)d_in[7];
  const float* w_c1t  = (const float*)d_in[8];
  const float* b_c1t  = (const float*)d_in[9];
  const float* g_c1t  = (const float*)d_in[10];
  const float* be_c1t = (const float*)d_in[11];
  const float* w_c2t  = (const float*)d_in[12];
  const float* b_c2t  = (const float*)d_in[13];
  const float* g_c2t  = (const float*)d_in[14];
  const float* be_c2t = (const float*)d_in[15];
  const float* w_f1r  = (const float*)d_in[16];
  const float* b_f1r  = (const float*)d_in[17];
  const float* g_f1r  = (const float*)d_in[18];
  const float* be_f1r = (const float*)d_in[19];
  const float* w_f2r  = (const float*)d_in[20];
  const float* b_f2r  = (const float*)d_in[21];
  const float* g_f2r  = (const float*)d_in[22];
  const float* be_f2r = (const float*)d_in[23];
  const float* w_f1rt = (const float*)d_in[24];
  const float* b_f1rt = (const float*)d_in[25];
  const float* g_f1rt = (const float*)d_in[26];
  const float* be_f1rt= (const float*)d_in[27];
  const float* w_f2rt = (const float*)d_in[28];
  const float* b_f2rt = (const float*)d_in[29];
  const float* g_f2rt = (const float*)d_in[30];
  const float* be_f2rt= (const float*)d_in[31];
  const float* w_iou  = (const float*)d_in[32];
  const float* b_iou  = (const float*)d_in[33];

  float* ws    = (float*)d_ws;
  float* A     = ws + O_A;
  float* PART  = ws + O_A;                  // overlays A
  float* PSUM  = ws + O_PSUM;
  float* PSQ   = ws + O_PSQ;
  f16*   WPK2RT= (f16*)(ws + O_WPK2RT);
  f16*   WPK2R = (f16*)(ws + O_WPK2R);
  f16*   FT    = (f16*)(ws + O_FT);
  f16*   PHPK  = FT;                        // overlays FT
  f16*   X2PK  = (f16*)(ws + O_X2PK);
  f16*   WC    = (f16*)(ws + O_WC);
  f16*   WPK1RT= (f16*)(ws + O_WPK1RT);
  f16*   WPK1R = (f16*)(ws + O_WPK1R);
  f16*   PRPK  = (f16*)(ws + O_PRPK);
  float* Y1    = ws + O_Y1;
  float* Y2    = ws + O_Y2;
  float* MODp  = ws + O_MOD;
  float* WXR   = ws + O_WXR;
  float* WYR   = ws + O_WYR;
  float* ARR   = ws + O_ARR;
  float* WXT   = ws + O_WXT;
  float* WYT   = ws + O_WYT;
  float* ART   = ws + O_ART;
  float* MEAN  = ws + O_MEAN;
  float* ISTD  = ws + O_ISTD;
  f16*   X1PK  = (f16*)(ws + O_X1PK);
  int*   META  = (int*)(ws + O_META);
  float* PSUMC = ws + O_PSC;        // 4096
  float* PSQC  = ws + O_PSC + 4096; // 4096
  int* HLOR = META;          // 64
  int* HCNTR= META + 64;     // 64
  int* WLOR = META + 128;    // 320
  int* HLOT = META + 448;    // 1024
  int* HCNTT= META + 1472;   // 1024
  int* WLOT = META + 2496;   // 7168

  // ===== get_modulation branch =====
  k_border<<<64, 256, 0, stream>>>(FT);
  k_repack_w<<<2304, 256, 0, stream>>>(w_c1r, WC);
  k_pad<false><<<dim3(64, 36), 256, 0, stream>>>(feat1, FT, nullptr, nullptr, nullptr, nullptr);
  k_conv_mfma<<<1408, 256, 0, stream>>>(FT, WC, b_c1r, A);
  k_chan_stats_part<<<dim3(256, 16), 256, 0, stream>>>(A, PSUMC, PSQC);
  k_chan_stats_final<<<1, 256, 0, stream>>>(PSUMC, PSQC, MEAN, ISTD);
  k_bn_relu_conv<<<20736, 256, 0, stream>>>(A, MEAN, ISTD, g_c1r, be_c1r);

  k_wxy<<<1, 64, 0, stream>>>(bb1, 64, 5, WXR, WYR, ARR, HLOR, HCNTR, WLOR);
  k_zero<<<400, 256, 0, stream>>>((float4*)PRPK, 102400);
  k_pool<5, false, true><<<dim3(64, 1), 256, 0, stream>>>(
      A, WXR, WYR, ARR, HLOR, HCNTR, WLOR, nullptr, PRPK, 1);

  k_pack_w<<<25600, 256, 0, stream>>>(w_f1r, WPK1R, 6400, 6553600);
  k_gemm_f16pk<<<dim3(8, 1, 8), 256, 0, stream>>>(PRPK, WPK1R, PART, 6400, 1024, 25, 128);
  k_reduce<<<256, 256, 0, stream>>>(PART, b_f1r, Y1, 128, 64, 1024, 8);
  k_fc_stats_part<<<dim3(4, 8), 256, 0, stream>>>(Y1, 64, 1024, 8, PSUM, PSQ);
  k_fc_stats_final<<<4, 256, 0, stream>>>(PSUM, PSQ, 8, 1024, 64, MEAN, ISTD);
  k_zero<<<64, 256, 0, stream>>>((float4*)X1PK, 16384);
  k_fc_bn_relu_pk<<<256, 256, 0, stream>>>(Y1, MEAN, ISTD, g_f1r, be_f1r, X1PK, 64 * 1024, 1024);

  k_pack_w<<<1024, 256, 0, stream>>>(w_f2r, WPK2R, 1024, 262144);
  k_gemm_f16pk<<<dim3(2, 1, 4), 256, 0, stream>>>(X1PK, WPK2R, PART, 1024, 256, 8, 128);
  k_reduce<<<64, 256, 0, stream>>>(PART, b_f2r, MODp, 128, 64, 256, 4);
  k_fc_stats_part<<<dim3(1, 8), 256, 0, stream>>>(MODp, 64, 256, 8, PSUM, PSQ);
  k_fc_stats_final<<<1, 256, 0, stream>>>(PSUM, PSQ, 8, 256, 64, MEAN, ISTD);
  k_fc_bn_relu<<<64, 256, 0, stream>>>(MODp, MEAN, ISTD, g_f2r, be_f2r, 64 * 256, 256);

  // ===== get_iou_feat branch =====
  k_repack_w<<<2304, 256, 0, stream>>>(w_c1t, WC);
  k_pad<false><<<dim3(64, 36), 256, 0, stream>>>(feat2, FT, nullptr, nullptr, nullptr, nullptr);
  k_conv_mfma<<<1408, 256, 0, stream>>>(FT, WC, b_c1t, A);
  k_chan_stats_part<<<dim3(256, 16), 256, 0, stream>>>(A, PSUMC, PSQC);
  k_chan_stats_final<<<1, 256, 0, stream>>>(PSUMC, PSQC, MEAN, ISTD);
  k_pad<true><<<dim3(64, 36), 256, 0, stream>>>(A, FT, MEAN, ISTD, g_c1t, be_c1t);

  k_repack_w<<<2304, 256, 0, stream>>>(w_c2t, WC);
  k_conv_mfma<<<1408, 256, 0, stream>>>(FT, WC, b_c2t, A);
  k_chan_stats_part<<<dim3(256, 16), 256, 0, stream>>>(A, PSUMC, PSQC);
  k_chan_stats_final<<<1, 256, 0, stream>>>(PSUMC, PSQC, MEAN, ISTD);
  k_bn_relu_conv<<<20736, 256, 0, stream>>>(A, MEAN, ISTD, g_c2t, be_c2t);

  // ===== predict_iou =====
  k_wxy<<<16, 64, 0, stream>>>(props, 1024, 7, WXT, WYT, ART, HLOT, HCNTT, WLOT);
  k_pool<7, true, true><<<dim3(64, 16), 256, 0, stream>>>(
      A, WXT, WYT, ART, HLOT, HCNTT, WLOT, MODp, PHPK, 16);

  k_pack_w<<<50176, 256, 0, stream>>>(w_f1rt, WPK1RT, 12544, 12845056);
  k_gemm_f16pk<<<dim3(8, 8, 8), 256, 0, stream>>>(PHPK, WPK1RT, PART, 12544, 1024, 49, 1024);
  k_reduce<<<4096, 256, 0, stream>>>(PART, b_f1rt, Y1, 1024, 1024, 1024, 8);
  k_fc_stats_part<<<dim3(4, 64), 256, 0, stream>>>(Y1, 1024, 1024, 16, PSUM, PSQ);
  k_fc_stats_final<<<4, 256, 0, stream>>>(PSUM, PSQ, 64, 1024, 1024, MEAN, ISTD);
  k_fc_bn_relu_pk<<<4096, 256, 0, stream>>>(Y1, MEAN, ISTD, g_f1rt, be_f1rt, X2PK, 1024 * 1024, 1024);

  k_pack_w<<<4096, 256, 0, stream>>>(w_f2rt, WPK2RT, 1024, 1048576);
  k_gemm_f16pk<<<dim3(8, 8, 4), 256, 0, stream>>>(X2PK, WPK2RT, PART, 1024, 1024, 8, 1024);
  k_reduce<<<4096, 256, 0, stream>>>(PART, b_f2rt, Y2, 1024, 1024, 1024, 4);
  k_fc_stats_part<<<dim3(4, 64), 256, 0, stream>>>(Y2, 1024, 1024, 16, PSUM, PSQ);
  k_fc_stats_final<<<4, 256, 0, stream>>>(PSUM, PSQ, 64, 1024, 1024, MEAN, ISTD);
  k_fc_bn_relu<<<4096, 256, 0, stream>>>(Y2, MEAN, ISTD, g_f2rt, be_f2rt, 1024 * 1024, 1024);

  k_iou<<<1024, 256, 0, stream>>>(Y2, w_iou, b_iou, (float*)d_out);
}

// Round 6
// 1215.314 us; speedup vs baseline: 6.1974x; 1.1263x over previous
//
#include <hip/hip_runtime.h>
#include <cstddef>

// ---------------------------------------------------------------------------
// FPNIoUNetHR forward — round 6: lane-contiguous conv staging
// (packed conv weights + channel-octet-major feature layout FT2).
// S=64, C=256, H=W=36, N=16.
// ---------------------------------------------------------------------------

typedef _Float16 f16;
typedef __attribute__((ext_vector_type(8))) _Float16 f16x8;
typedef __attribute__((ext_vector_type(4))) float f32x4;

__device__ __forceinline__ void gload16(const void* g, void* l) {
  __builtin_amdgcn_global_load_lds((const __attribute__((address_space(1))) void*)g,
                                   (__attribute__((address_space(3))) void*)l, 16, 0, 0);
}

static __device__ __forceinline__ float hat_int(float x) {
  float u = fminf(1.f, fmaxf(-1.f, x));
  float a = 0.5f * (1.f + u) * (1.f + u);
  float b = 0.5f + u - 0.5f * u * u;
  return (u <= 0.f) ? a : b;
}

// Packed GEMM operand layout: element (row,k) of a row-major [M][K] matrix ->
// [row/128][k/32][(k/8)%4][row%128][k%8]. One k-step chunk (128 rows x 32 k)
// is 8 KB contiguous, exactly the LDS image the MFMA frag reads want.
static __device__ __forceinline__ size_t pk_off(int row, int k, int K) {
  return (size_t)(row >> 7) * ((size_t)K * 128) + (size_t)(k >> 5) * 4096
       + (size_t)((((k >> 3) & 3) * 128 + (row & 127)) * 8 + (k & 7));
}

// ---- zero helper (float4 granularity) -------------------------------------
__global__ void k_zero(float4* __restrict__ p, int n4) {
  int i = blockIdx.x * 256 + threadIdx.x;
  if (i < n4) p[i] = float4{0.f, 0.f, 0.f, 0.f};
}

// ---- zero the 148 border positions of FT2 per image -----------------------
// FT2 layout: [img][koct(c/8)][1444(38x38)][c%8] f16
__global__ void k_border(f16* __restrict__ FT) {
  const int img = blockIdx.x;
  f16* base = FT + (size_t)img * 32 * 1444 * 8;
  for (int i = threadIdx.x; i < 148 * 256; i += 256) {
    int b = i >> 8, c = i & 255;
    int r, cc;
    if (b < 38)       { r = 0;          cc = b; }
    else if (b < 76)  { r = 37;         cc = b - 38; }
    else if (b < 112) { r = b - 76 + 1; cc = 0; }
    else              { r = b - 112 + 1; cc = 37; }
    base[((size_t)(c >> 3) * 1444 + r * 38 + cc) * 8 + (c & 7)] = (f16)0.f;
  }
}

// ---- pad + (optional BN+ReLU) + CHW fp32 -> FT2 f16 -----------------------
template <bool BN>
__global__ void k_pad(const float* __restrict__ src, f16* __restrict__ FT,
                      const float* __restrict__ mean, const float* __restrict__ istd,
                      const float* __restrict__ g, const float* __restrict__ be) {
  const int img = blockIdx.x, h = blockIdx.y, c = threadIdx.x;
  float sc = 1.f, sh = 0.f;
  if (BN) { sc = istd[c] * g[c]; sh = be[c] - mean[c] * sc; }
  const float* sp = src + ((size_t)img * 256 + c) * 1296 + h * 36;
  f16* op = FT + (((size_t)img * 32 + (c >> 3)) * 1444 + (h + 1) * 38 + 1) * 8 + (c & 7);
#pragma unroll 4
  for (int w = 0; w < 36; ++w) {
    float v = sp[w];
    if (BN) v = fmaxf(fmaf(v, sc, sh), 0.f);
    op[w * 8] = (f16)v;
  }
}

// ---- conv weights [256][256][3][3] fp32 -> packed f16 ---------------------
// dst: [oct(oc/128)][ks(0..71)][koct(0..3)][row128][kj8], k = t*256 + c
__global__ void k_pack_wc(const float* __restrict__ w, f16* __restrict__ dst) {
  int i = blockIdx.x * 256 + threadIdx.x;   // < 589,824
  int oct = i / 294912;
  int r = i - oct * 294912;
  int ks = r >> 12;
  int r2 = r & 4095;
  int koct = r2 >> 10;
  int r3 = r2 & 1023;
  int row = r3 >> 3, kj = r3 & 7;
  int k = ks * 32 + koct * 8 + kj;
  int t = k >> 8, c = k & 255;
  int oc = oct * 128 + row;
  dst[i] = (f16)w[(oc * 256 + c) * 9 + t];
}

// ---- pack fp32 [N][K] weights into packed f16 (write-coalesced) -----------
__global__ void k_pack_w(const float* __restrict__ src, f16* __restrict__ dst,
                         int K, int total) {
  int i = blockIdx.x * 256 + threadIdx.x;
  if (i >= total) return;
  const int blkSz = K * 128;
  int nt = i / blkSz;
  int wi = i - nt * blkSz;
  int ks = wi >> 12;
  int r2 = wi & 4095;
  int koct = r2 >> 10;
  int r3 = r2 & 1023;
  int col = r3 >> 3, kj = r3 & 7;
  int k = ks * 32 + koct * 8 + kj;
  int row = nt * 128 + col;
  dst[i] = (f16)src[(size_t)row * K + k];
}

// ---- 3x3 conv via MFMA implicit GEMM, 2-phase dbuf, contiguous staging ----
// FT2 [img][32 koct][1444][8] f16, Wpk packed (k_pack_wc), y [64][256][1296].
__global__ __launch_bounds__(256) void k_conv_mfma(
    const f16* __restrict__ Wpk, const f16* __restrict__ FT2,
    const float* __restrict__ bias, float* __restrict__ y) {
  __shared__ f16x8 sA[1024];   // 2 buffers x 512
  __shared__ f16x8 sB[1024];
  const int bid = blockIdx.x;
  const int orig = (bid & 7) * 176 + (bid >> 3);   // bijective: 1408 % 8 == 0
  const int img = orig / 22;
  const int rem = orig - img * 22;
  const int oct = rem / 11;
  const int pt  = rem - oct * 11;
  const int m0 = oct * 128;
  const int p0 = pt * 128;
  const int tid = threadIdx.x;
  const int lane = tid & 63;
  const int wv = tid >> 6;
  const int wr = wv >> 1, wc = wv & 1;

  const f16* aBase = Wpk + (size_t)oct * 294912 + wv * 1024 + lane * 8;
  const f16* ftImg = FT2 + (size_t)img * 32 * 1444 * 8;
  int pos0 = p0 + lane;
  int pc0 = min(pos0, 1295);
  int pc1 = min(pos0 + 64, 1295);
  int pb0 = (pc0 / 36) * 38 + (pc0 % 36);   // padded-grid position index
  int pb1 = (pc1 / 36) * 38 + (pc1 % 36);

  const int loff = wv * 2048 + lane * 16;

  auto stage = [&](int buf, int ks) {
    const int t = ks >> 3;
    const int dy = t / 3, dx = t - dy * 3;
    const int cs = ks & 7;
    const int dyx = dy * 38 + dx;
    char* lA = (char*)sA + buf * 8192 + loff;
    char* lB = (char*)sB + buf * 8192 + loff;
    const f16* ap = aBase + (size_t)ks * 4096;
    const f16* bp = ftImg + ((size_t)(cs * 4 + wv) * 1444 + dyx) * 8;
    gload16(ap, lA);
    gload16(ap + 512, lA + 1024);
    gload16(bp + pb0 * 8, lB);
    gload16(bp + pb1 * 8, lB + 1024);
  };

  f32x4 acc[4][4] = {};
  const int fidxA = ((lane >> 4) << 7) + wr * 64 + (lane & 15);
  const int fidxB = ((lane >> 4) << 7) + wc * 64 + (lane & 15);

  stage(0, 0);
  __syncthreads();
  int cur = 0;
  for (int ks = 0; ks < 72; ++ks) {
    if (ks < 71) stage(cur ^ 1, ks + 1);
    f16x8 af[4], bf[4];
#pragma unroll
    for (int i = 0; i < 4; ++i) {
      af[i] = sA[cur * 512 + fidxA + i * 16];
      bf[i] = sB[cur * 512 + fidxB + i * 16];
    }
#pragma unroll
    for (int i = 0; i < 4; ++i)
#pragma unroll
      for (int j = 0; j < 4; ++j)
        acc[i][j] = __builtin_amdgcn_mfma_f32_16x16x32_f16(af[i], bf[j], acc[i][j], 0, 0, 0);
    __syncthreads();
    cur ^= 1;
  }

  const int colb = p0 + wc * 64 + (lane & 15);
  const int rowb = m0 + wr * 64 + ((lane >> 4) << 2);
#pragma unroll
  for (int i = 0; i < 4; ++i) {
#pragma unroll
    for (int j = 0; j < 4; ++j) {
      const int col = colb + j * 16;
      if (col < 1296) {
#pragma unroll
        for (int r = 0; r < 4; ++r) {
          const int oc = rowb + i * 16 + r;
          y[((size_t)img * 256 + oc) * 1296 + col] = acc[i][j][r] + bias[oc];
        }
      }
    }
  }
}

// ---- packed split-K f16 MFMA GEMM, 2-phase double-buffered ----------------
__global__ __launch_bounds__(256) void k_gemm_f16pk(
    const f16* __restrict__ Apk, const f16* __restrict__ Bpk,
    float* __restrict__ part, int K, int Nout, int stepsPerZ, int mrows) {
  __shared__ f16x8 sA[1024];
  __shared__ f16x8 sB[1024];
  const int nt = blockIdx.x, mt = blockIdx.y, z = blockIdx.z;
  const int tid = threadIdx.x;
  const int lane = tid & 63;
  const int wv = tid >> 6;
  const int wr = wv >> 1, wc = wv & 1;

  const f16* aC = Apk + (size_t)mt * K * 128 + wv * 1024 + lane * 8;
  const f16* bC = Bpk + (size_t)nt * K * 128 + wv * 1024 + lane * 8;
  const int loff = wv * 2048 + lane * 16;

  auto stage = [&](int buf, int ks) {
    char* lA = (char*)sA + buf * 8192 + loff;
    char* lB = (char*)sB + buf * 8192 + loff;
    const f16* ap = aC + (size_t)ks * 4096;
    const f16* bp = bC + (size_t)ks * 4096;
    gload16(ap, lA);
    gload16(ap + 512, lA + 1024);
    gload16(bp, lB);
    gload16(bp + 512, lB + 1024);
  };

  f32x4 acc[4][4] = {};
  const int fidxA = ((lane >> 4) << 7) + wr * 64 + (lane & 15);
  const int fidxB = ((lane >> 4) << 7) + wc * 64 + (lane & 15);

  const int ks0 = z * stepsPerZ;
  stage(0, ks0);
  __syncthreads();
  int cur = 0;
  for (int i = 0; i < stepsPerZ; ++i) {
    if (i + 1 < stepsPerZ) stage(cur ^ 1, ks0 + i + 1);
    f16x8 af[4], bf[4];
#pragma unroll
    for (int j = 0; j < 4; ++j) {
      af[j] = sA[cur * 512 + fidxA + j * 16];
      bf[j] = sB[cur * 512 + fidxB + j * 16];
    }
#pragma unroll
    for (int ii = 0; ii < 4; ++ii)
#pragma unroll
      for (int jj = 0; jj < 4; ++jj)
        acc[ii][jj] = __builtin_amdgcn_mfma_f32_16x16x32_f16(af[ii], bf[jj], acc[ii][jj], 0, 0, 0);
    __syncthreads();
    cur ^= 1;
  }

  const size_t zoff = (size_t)z * mrows * Nout;
  const int colb = nt * 128 + wc * 64 + (lane & 15);
  const int rowb = mt * 128 + wr * 64 + ((lane >> 4) << 2);
#pragma unroll
  for (int i = 0; i < 4; ++i)
#pragma unroll
    for (int j = 0; j < 4; ++j)
#pragma unroll
      for (int r = 0; r < 4; ++r)
        part[zoff + (size_t)(rowb + i * 16 + r) * Nout + colb + j * 16] = acc[i][j][r];
}

// ---- reduce split-K partials + bias ---------------------------------------
__global__ void k_reduce(const float* __restrict__ part, const float* __restrict__ bias,
                         float* __restrict__ out, int mrows, int Mout, int Nout, int sk) {
  int i = blockIdx.x * 256 + threadIdx.x;
  if (i >= Mout * Nout) return;
  int row = i / Nout, col = i - row * Nout;
  float s = bias[col];
  for (int z = 0; z < sk; ++z)
    s += part[(size_t)z * mrows * Nout + (size_t)row * Nout + col];
  out[i] = s;
}

// ---- conv BN stats, two-pass: pass 1 over 4-image groups ------------------
__global__ void k_chan_stats_part(const float* __restrict__ y,
                                  float* __restrict__ psum, float* __restrict__ psq) {
  const int c = blockIdx.x, z = blockIdx.y, tid = threadIdx.x;
  float s = 0.f, ss = 0.f;
  for (int img = z * 4; img < z * 4 + 4; ++img) {
    const float* p = y + ((size_t)img * 256 + c) * 1296;
    for (int i = tid; i < 1296; i += 256) { float v = p[i]; s += v; ss += v * v; }
  }
  __shared__ float rs[256], rss[256];
  rs[tid] = s; rss[tid] = ss;
  __syncthreads();
  for (int o = 128; o > 0; o >>= 1) {
    if (tid < o) { rs[tid] += rs[tid + o]; rss[tid] += rss[tid + o]; }
    __syncthreads();
  }
  if (tid == 0) {
    psum[z * 256 + c] = rs[0];
    psq[z * 256 + c] = rss[0];
  }
}

// pass 2: fold 16 partials per channel
__global__ void k_chan_stats_final(const float* __restrict__ psum, const float* __restrict__ psq,
                                   float* __restrict__ mean, float* __restrict__ istd) {
  const int c = threadIdx.x;
  float s = 0.f, ss = 0.f;
  for (int z = 0; z < 16; ++z) { s += psum[z * 256 + c]; ss += psq[z * 256 + c]; }
  float m = s * (1.f / 82944.f);
  float var = ss * (1.f / 82944.f) - m * m;
  mean[c] = m;
  istd[c] = rsqrtf(var + 1e-5f);
}

// ---- BN+ReLU elementwise on conv tensor (float4, in place) ----------------
__global__ void k_bn_relu_conv(float* __restrict__ y, const float* __restrict__ mean,
                               const float* __restrict__ istd, const float* __restrict__ g,
                               const float* __restrict__ be) {
  int i = blockIdx.x * 256 + threadIdx.x;
  int c = (i / 324) & 255;
  float sc = istd[c] * g[c];
  float sh = be[c] - mean[c] * sc;
  float4 v = reinterpret_cast<float4*>(y)[i];
  v.x = fmaxf(fmaf(v.x, sc, sh), 0.f);
  v.y = fmaxf(fmaf(v.y, sc, sh), 0.f);
  v.z = fmaxf(fmaf(v.z, sc, sh), 0.f);
  v.w = fmaxf(fmaf(v.w, sc, sh), 0.f);
  reinterpret_cast<float4*>(y)[i] = v;
}

// ---- PrRoI separable weights + sparse-range metadata ----------------------
__global__ void k_wxy(const float* __restrict__ rois, int ntot, int P,
                      float* __restrict__ Wx, float* __restrict__ Wy,
                      float* __restrict__ area,
                      int* __restrict__ HLO, int* __restrict__ HCNT,
                      int* __restrict__ WLO) {
  int idx = blockIdx.x * blockDim.x + threadIdx.x;
  if (idx >= ntot) return;
  float rx = rois[idx * 4 + 0], ry = rois[idx * 4 + 1];
  float rw = rois[idx * 4 + 2], rh = rois[idx * 4 + 3];
  float x1 = rx * 0.125f, y1 = ry * 0.125f;
  float x2 = (rx + rw) * 0.125f, y2 = (ry + rh) * 0.125f;
  float bw = (x2 - x1) / P, bh = (y2 - y1) / P;
  area[idx] = bw * bh;
  int hlo = max(0, (int)ceilf(y1 - 1.f));
  int hhi = min(35, (int)floorf(y2 + 1.f));
  HLO[idx] = hlo;
  HCNT[idx] = max(0, hhi - hlo + 1);
  for (int q = 0; q < P; ++q) {
    float xlo = x1 + q * bw, ylo = y1 + q * bh;
    WLO[idx * P + q] = min(31, max(0, (int)ceilf(xlo - 1.f)));
    for (int g = 0; g < 36; ++g) {
      float fg = (float)g;
      Wx[(idx * P + q) * 36 + g] = hat_int(xlo + bw - fg) - hat_int(xlo - fg);
      Wy[(idx * P + q) * 36 + g] = hat_int(ylo + bh - fg) - hat_int(ylo - fg);
    }
  }
}

// ---- PrRoI pool: block=(s,n), thread=channel; writes packed f16 -----------
// SPARSE: h restricted to active rows; 5-wide x windows (support <= 5 taps
// for both P=5 (bw<=2.5) and P=7 (bw<=1.79); wave-uniform bounds).
template <int P, bool MOD, bool SPARSE>
__global__ __launch_bounds__(256) void k_pool(
    const float* __restrict__ feat, const float* __restrict__ Wx,
    const float* __restrict__ Wy, const float* __restrict__ area,
    const int* __restrict__ HLO, const int* __restrict__ HCNT,
    const int* __restrict__ WLO,
    const float* __restrict__ mod, f16* __restrict__ outPk, int N) {
  const int s = blockIdx.x, n = blockIdx.y;
  const int idx = s * N + n;
  const int c = threadIdx.x;
  constexpr int KD = P * P * 256;
  __shared__ float sWx[P * 36], sWy[P * 36];
  __shared__ int sWLO[P];
  __shared__ int sH[2];
  for (int i = threadIdx.x; i < P * 36; i += 256) {
    sWx[i] = Wx[(size_t)idx * P * 36 + i];
    sWy[i] = Wy[(size_t)idx * P * 36 + i];
  }
  if (threadIdx.x < P) sWLO[threadIdx.x] = WLO[idx * P + threadIdx.x];
  if (threadIdx.x == 0) { sH[0] = HLO[idx]; sH[1] = HCNT[idx]; }
  __syncthreads();
  const float* f = feat + ((size_t)s * 256 + c) * 1296;
  float o[P][P] = {};
  const int hlo = SPARSE ? sH[0] : 0;
  const int hcnt = SPARSE ? sH[1] : 36;
  for (int hh = 0; hh < hcnt; ++hh) {
    const int h = hlo + hh;
    const float* rp = f + h * 36;
    float colsum[P];
    if (SPARSE) {
#pragma unroll
      for (int q = 0; q < P; ++q) {
        const int w0 = sWLO[q];
        float v = 0.f;
#pragma unroll
        for (int j = 0; j < 5; ++j) v = fmaf(sWx[q * 36 + w0 + j], rp[w0 + j], v);
        colsum[q] = v;
      }
    } else {
      float row[36];
#pragma unroll
      for (int w = 0; w < 36; ++w) row[w] = rp[w];
#pragma unroll
      for (int q = 0; q < P; ++q) {
        float v = 0.f;
#pragma unroll
        for (int w = 0; w < 36; ++w) v = fmaf(sWx[q * 36 + w], row[w], v);
        colsum[q] = v;
      }
    }
#pragma unroll
    for (int p = 0; p < P; ++p) {
      const float wy = sWy[p * 36 + h];
      if (wy != 0.f) {
#pragma unroll
        for (int q = 0; q < P; ++q) o[p][q] = fmaf(wy, colsum[q], o[p][q]);
      }
    }
  }
  float a = area[idx];
  float inv = (a > 0.f) ? 1.f / fmaxf(a, 1e-12f) : 0.f;
  float msc = MOD ? (mod[s * 256 + c] * inv) : inv;
  const int kbase = c * (P * P);
#pragma unroll
  for (int p = 0; p < P; ++p)
#pragma unroll
    for (int q = 0; q < P; ++q)
      outPk[pk_off(idx, kbase + p * P + q, KD)] = (f16)(o[p][q] * msc);
}

// ---- FC BN stats, two-pass deterministic ----------------------------------
__global__ void k_fc_stats_part(const float* __restrict__ y, int M, int Nf, int rpz,
                                float* __restrict__ psum, float* __restrict__ psq) {
  int col = blockIdx.x * 256 + threadIdx.x;
  int z = blockIdx.y;
  if (col >= Nf) return;
  int r0 = z * rpz;
  int r1 = min(M, r0 + rpz);
  float s = 0.f, ss = 0.f;
  for (int m = r0; m < r1; ++m) {
    float v = y[(size_t)m * Nf + col];
    s += v; ss += v * v;
  }
  psum[(size_t)z * Nf + col] = s;
  psq[(size_t)z * Nf + col] = ss;
}

__global__ void k_fc_stats_final(const float* __restrict__ psum, const float* __restrict__ psq,
                                 int nz, int Nf, int M,
                                 float* __restrict__ mean, float* __restrict__ istd) {
  int col = blockIdx.x * 256 + threadIdx.x;
  if (col >= Nf) return;
  float s = 0.f, ss = 0.f;
  for (int z = 0; z < nz; ++z) {
    s += psum[(size_t)z * Nf + col];
    ss += psq[(size_t)z * Nf + col];
  }
  float mu = s / (float)M;
  float var = ss / (float)M - mu * mu;
  mean[col] = mu;
  istd[col] = rsqrtf(var + 1e-5f);
}

// ---- FC BN+ReLU elementwise (fp32 in place) -------------------------------
__global__ void k_fc_bn_relu(float* __restrict__ y, const float* __restrict__ mean,
                             const float* __restrict__ istd, const float* __restrict__ g,
                             const float* __restrict__ be, int total, int Nf) {
  int i = blockIdx.x * 256 + threadIdx.x;
  if (i >= total) return;
  int col = i % Nf;
  float sc = istd[col] * g[col];
  float sh = be[col] - mean[col] * sc;
  y[i] = fmaxf(fmaf(y[i], sc, sh), 0.f);
}

// ---- FC BN+ReLU -> packed f16 (next GEMM's A operand) ---------------------
__global__ void k_fc_bn_relu_pk(const float* __restrict__ y, const float* __restrict__ mean,
                                const float* __restrict__ istd, const float* __restrict__ g,
                                const float* __restrict__ be, f16* __restrict__ xpk,
                                int total, int Nf) {
  int i = blockIdx.x * 256 + threadIdx.x;
  if (i >= total) return;
  int row = i / Nf, col = i - row * Nf;
  float sc = istd[col] * g[col];
  float sh = be[col] - mean[col] * sc;
  float v = fmaxf(fmaf(y[i], sc, sh), 0.f);
  xpk[pk_off(row, col, Nf)] = (f16)v;
}

// ---- IoU head -------------------------------------------------------------
__global__ void k_iou(const float* __restrict__ x, const float* __restrict__ w,
                      const float* __restrict__ b, float* __restrict__ out) {
  const int r = blockIdx.x, tid = threadIdx.x;
  float s = 0.f;
  for (int k = tid; k < 1024; k += 256) s = fmaf(x[(size_t)r * 1024 + k], w[k], s);
  __shared__ float red[256];
  red[tid] = s;
  __syncthreads();
  for (int o = 128; o > 0; o >>= 1) {
    if (tid < o) red[tid] += red[tid + o];
    __syncthreads();
  }
  if (tid == 0) out[r] = red[0] + b[0];
}

// ---------------------------------------------------------------------------
// Workspace layout (float offsets). Total ~46.21M floats = 184.9 MB.
// ---------------------------------------------------------------------------
static const size_t O_A      = 0;            // 21,233,664 conv out fp32
static const size_t O_PSUM   = 13000000;     // 65,536 (in A region, fc only)
static const size_t O_PSQ    = 13065536;     // 65,536 (in A region, fc only)
static const size_t O_WPK2RT = 16000000;     // in A region
static const size_t O_WPK2R  = 20000000;     // in A region
static const size_t O_FT     = 21233664;     // 11,829,248 f16 FT2 / PHPK
static const size_t O_X2PK   = 21233664 + 6422528;  // in FT region
static const size_t O_WC     = 33062912;     //    294,912 conv w packed f16
static const size_t O_WPK1RT = 33357824;     //  6,422,528
static const size_t O_WPK1R  = 39780352;     //  3,276,800
static const size_t O_PRPK   = 43057152;     //    409,600
static const size_t O_Y1     = 43466752;     //  1,048,576
static const size_t O_Y2     = 44515328;     //  1,048,576
static const size_t O_MOD    = 45563904;     //     16,384
static const size_t O_WXR    = 45580288;     //     11,520
static const size_t O_WYR    = 45591808;     //     11,520
static const size_t O_ARR    = 45603328;     //         64
static const size_t O_WXT    = 45603392;     //    258,048
static const size_t O_WYT    = 45861440;     //    258,048
static const size_t O_ART    = 46119488;     //      1,024
static const size_t O_MEAN   = 46120512;     //      1,024
static const size_t O_ISTD   = 46121536;     //      1,024
static const size_t O_X1PK   = 46122560;     //     65,536
static const size_t O_META   = 46188096;     //      9,664 (ints)
static const size_t O_PSC    = 46197760;     //      8,192 (chan-stats partials)

extern "C" void kernel_launch(void* const* d_in, const int* in_sizes, int n_in,
                              void* d_out, int out_size, void* d_ws, size_t ws_size,
                              hipStream_t stream) {
  (void)in_sizes; (void)n_in; (void)out_size; (void)ws_size;
  const float* feat1  = (const float*)d_in[0];
  const float* feat2  = (const float*)d_in[1];
  const float* bb1    = (const float*)d_in[2];
  const float* props  = (const float*)d_in[3];
  const float* w_c1r  = (const float*)d_in[4];
  const float* b_c1r  = (const float*)d_in[5];
  const float* g_c1r  = (const float*)d_in[6];
  const float* be_c1r = (const float*)d_in[7];
  const float* w_c1t  = (const float*)d_in[8];
  const float* b_c1t  = (const float*)d_in[9];
  const float* g_c1t  = (const float*)d_in[10];
  const float* be_c1t = (const float*)d_in[11];
  const float* w_c2t  = (const float*)d_in[12];
  const float* b_c2t  = (const float*)d_in[13];
  const float* g_c2t  = (const float*)d_in[14];
  const float* be_c2t = (const float*)d_in[15];
  const float* w_f1r  = (const float*)d_in[16];
  const float* b_f1r  = (const float*)d_in[17];
  const float* g_f1r  = (const float*)d_in[18];
  const float* be_f1r = (const float*)d_in[19];
  const float* w_f2r  = (const float*)d_in[20];
  const float* b_f2r  = (const float*)d_in[21];
  const float* g_f2r  = (const float*)d_in[22];
  const float* be_f2r = (const float*)d_in[23];
  const float* w_f1rt = (const float*)d_in[24];
  const float* b_f1rt = (const float*)d_in[25];
  const float* g_f1rt = (const float*)d_in[26];
  const float* be_f1rt= (const float*)d_in[27];
  const float* w_f2rt = (const float*)d_in[28];
  const float* b_f2rt = (const float*)d_in[29];
  const float* g_f2rt = (const float*)d_in[30];
  const float* be_f2rt= (const float*)d_in[31];
  const float* w_iou  = (const float*)d_in[32];
  const float* b_iou  = (const float*)d_in[33];

  float* ws    = (float*)d_ws;
  float* A     = ws + O_A;
  float* PART  = ws + O_A;                  // overlays A
  float* PSUM  = ws + O_PSUM;
  float* PSQ   = ws + O_PSQ;
  f16*   WPK2RT= (f16*)(ws + O_WPK2RT);
  f16*   WPK2R = (f16*)(ws + O_WPK2R);
  f16*   FT2   = (f16*)(ws + O_FT);
  f16*   PHPK  = FT2;                       // overlays FT2
  f16*   X2PK  = (f16*)(ws + O_X2PK);
  f16*   WC    = (f16*)(ws + O_WC);
  f16*   WPK1RT= (f16*)(ws + O_WPK1RT);
  f16*   WPK1R = (f16*)(ws + O_WPK1R);
  f16*   PRPK  = (f16*)(ws + O_PRPK);
  float* Y1    = ws + O_Y1;
  float* Y2    = ws + O_Y2;
  float* MODp  = ws + O_MOD;
  float* WXR   = ws + O_WXR;
  float* WYR   = ws + O_WYR;
  float* ARR   = ws + O_ARR;
  float* WXT   = ws + O_WXT;
  float* WYT   = ws + O_WYT;
  float* ART   = ws + O_ART;
  float* MEAN  = ws + O_MEAN;
  float* ISTD  = ws + O_ISTD;
  f16*   X1PK  = (f16*)(ws + O_X1PK);
  int*   META  = (int*)(ws + O_META);
  float* PSUMC = ws + O_PSC;        // 4096
  float* PSQC  = ws + O_PSC + 4096; // 4096
  int* HLOR = META;          // 64
  int* HCNTR= META + 64;     // 64
  int* WLOR = META + 128;    // 320
  int* HLOT = META + 448;    // 1024
  int* HCNTT= META + 1472;   // 1024
  int* WLOT = META + 2496;   // 7168

  // ===== get_modulation branch =====
  k_border<<<64, 256, 0, stream>>>(FT2);
  k_pack_wc<<<2304, 256, 0, stream>>>(w_c1r, WC);
  k_pad<false><<<dim3(64, 36), 256, 0, stream>>>(feat1, FT2, nullptr, nullptr, nullptr, nullptr);
  k_conv_mfma<<<1408, 256, 0, stream>>>(WC, FT2, b_c1r, A);
  k_chan_stats_part<<<dim3(256, 16), 256, 0, stream>>>(A, PSUMC, PSQC);
  k_chan_stats_final<<<1, 256, 0, stream>>>(PSUMC, PSQC, MEAN, ISTD);
  k_bn_relu_conv<<<20736, 256, 0, stream>>>(A, MEAN, ISTD, g_c1r, be_c1r);

  k_wxy<<<1, 64, 0, stream>>>(bb1, 64, 5, WXR, WYR, ARR, HLOR, HCNTR, WLOR);
  k_zero<<<400, 256, 0, stream>>>((float4*)PRPK, 102400);
  k_pool<5, false, true><<<dim3(64, 1), 256, 0, stream>>>(
      A, WXR, WYR, ARR, HLOR, HCNTR, WLOR, nullptr, PRPK, 1);

  k_pack_w<<<25600, 256, 0, stream>>>(w_f1r, WPK1R, 6400, 6553600);
  k_gemm_f16pk<<<dim3(8, 1, 8), 256, 0, stream>>>(PRPK, WPK1R, PART, 6400, 1024, 25, 128);
  k_reduce<<<256, 256, 0, stream>>>(PART, b_f1r, Y1, 128, 64, 1024, 8);
  k_fc_stats_part<<<dim3(4, 8), 256, 0, stream>>>(Y1, 64, 1024, 8, PSUM, PSQ);
  k_fc_stats_final<<<4, 256, 0, stream>>>(PSUM, PSQ, 8, 1024, 64, MEAN, ISTD);
  k_zero<<<64, 256, 0, stream>>>((float4*)X1PK, 16384);
  k_fc_bn_relu_pk<<<256, 256, 0, stream>>>(Y1, MEAN, ISTD, g_f1r, be_f1r, X1PK, 64 * 1024, 1024);

  k_pack_w<<<1024, 256, 0, stream>>>(w_f2r, WPK2R, 1024, 262144);
  k_gemm_f16pk<<<dim3(2, 1, 4), 256, 0, stream>>>(X1PK, WPK2R, PART, 1024, 256, 8, 128);
  k_reduce<<<64, 256, 0, stream>>>(PART, b_f2r, MODp, 128, 64, 256, 4);
  k_fc_stats_part<<<dim3(1, 8), 256, 0, stream>>>(MODp, 64, 256, 8, PSUM, PSQ);
  k_fc_stats_final<<<1, 256, 0, stream>>>(PSUM, PSQ, 8, 256, 64, MEAN, ISTD);
  k_fc_bn_relu<<<64, 256, 0, stream>>>(MODp, MEAN, ISTD, g_f2r, be_f2r, 64 * 256, 256);

  // ===== get_iou_feat branch =====
  k_pack_wc<<<2304, 256, 0, stream>>>(w_c1t, WC);
  k_pad<false><<<dim3(64, 36), 256, 0, stream>>>(feat2, FT2, nullptr, nullptr, nullptr, nullptr);
  k_conv_mfma<<<1408, 256, 0, stream>>>(WC, FT2, b_c1t, A);
  k_chan_stats_part<<<dim3(256, 16), 256, 0, stream>>>(A, PSUMC, PSQC);
  k_chan_stats_final<<<1, 256, 0, stream>>>(PSUMC, PSQC, MEAN, ISTD);
  k_pad<true><<<dim3(64, 36), 256, 0, stream>>>(A, FT2, MEAN, ISTD, g_c1t, be_c1t);

  k_pack_wc<<<2304, 256, 0, stream>>>(w_c2t, WC);
  k_conv_mfma<<<1408, 256, 0, stream>>>(WC, FT2, b_c2t, A);
  k_chan_stats_part<<<dim3(256, 16), 256, 0, stream>>>(A, PSUMC, PSQC);
  k_chan_stats_final<<<1, 256, 0, stream>>>(PSUMC, PSQC, MEAN, ISTD);
  k_bn_relu_conv<<<20736, 256, 0, stream>>>(A, MEAN, ISTD, g_c2t, be_c2t);

  // ===== predict_iou =====
  k_wxy<<<16, 64, 0, stream>>>(props, 1024, 7, WXT, WYT, ART, HLOT, HCNTT, WLOT);
  k_pool<7, true, true><<<dim3(64, 16), 256, 0, stream>>>(
      A, WXT, WYT, ART, HLOT, HCNTT, WLOT, MODp, PHPK, 16);

  k_pack_w<<<50176, 256, 0, stream>>>(w_f1rt, WPK1RT, 12544, 12845056);
  k_gemm_f16pk<<<dim3(8, 8, 8), 256, 0, stream>>>(PHPK, WPK1RT, PART, 12544, 1024, 49, 1024);
  k_reduce<<<4096, 256, 0, stream>>>(PART, b_f1rt, Y1, 1024, 1024, 1024, 8);
  k_fc_stats_part<<<dim3(4, 64), 256, 0, stream>>>(Y1, 1024, 1024, 16, PSUM, PSQ);
  k_fc_stats_final<<<4, 256, 0, stream>>>(PSUM, PSQ, 64, 1024, 1024, MEAN, ISTD);
  k_fc_bn_relu_pk<<<4096, 256, 0, stream>>>(Y1, MEAN, ISTD, g_f1rt, be_f1rt, X2PK, 1024 * 1024, 1024);

  k_pack_w<<<4096, 256, 0, stream>>>(w_f2rt, WPK2RT, 1024, 1048576);
  k_gemm_f16pk<<<dim3(8, 8, 4), 256, 0, stream>>>(X2PK, WPK2RT, PART, 1024, 1024, 8, 1024);
  k_reduce<<<4096, 256, 0, stream>>>(PART, b_f2rt, Y2, 1024, 1024, 1024, 4);
  k_fc_stats_part<<<dim3(4, 64), 256, 0, stream>>>(Y2, 1024, 1024, 16, PSUM, PSQ);
  k_fc_stats_final<<<4, 256, 0, stream>>>(PSUM, PSQ, 64, 1024, 1024, MEAN, ISTD);
  k_fc_bn_relu<<<4096, 256, 0, stream>>>(Y2, MEAN, ISTD, g_f2rt, be_f2rt, 1024 * 1024, 1024);

  k_iou<<<1024, 256, 0, stream>>>(Y2, w_iou, b_iou, (float*)d_out);
}

// Round 7
// 1095.628 us; speedup vs baseline: 6.8744x; 1.1092x over previous
//
#include <hip/hip_runtime.h>
#include <cstddef>

// ---------------------------------------------------------------------------
// FPNIoUNetHR forward — round 7: 3-deep counted-vmcnt MFMA pipelines
// (never drain vmcnt(0) in the main loop); BN+ReLU fused into pool reads.
// S=64, C=256, H=W=36, N=16.
// ---------------------------------------------------------------------------

typedef _Float16 f16;
typedef __attribute__((ext_vector_type(8))) _Float16 f16x8;
typedef __attribute__((ext_vector_type(4))) float f32x4;

__device__ __forceinline__ void gload16(const void* g, void* l) {
  __builtin_amdgcn_global_load_lds((const __attribute__((address_space(1))) void*)g,
                                   (__attribute__((address_space(3))) void*)l, 16, 0, 0);
}

// counted-vmcnt + barrier (wait only the OLDEST staged tile; memory clobber
// fences compiler-visible LDS reads/writes across it)
#define WAITB(N) asm volatile("s_waitcnt vmcnt(" #N ")\n\ts_barrier" ::: "memory")
// all my ds_reads retired, then barrier (safe to let others overwrite LDS)
#define LGKB()   asm volatile("s_waitcnt lgkmcnt(0)\n\ts_barrier" ::: "memory")

static __device__ __forceinline__ float hat_int(float x) {
  float u = fminf(1.f, fmaxf(-1.f, x));
  float a = 0.5f * (1.f + u) * (1.f + u);
  float b = 0.5f + u - 0.5f * u * u;
  return (u <= 0.f) ? a : b;
}

// Packed GEMM operand layout: element (row,k) of a row-major [M][K] matrix ->
// [row/128][k/32][(k/8)%4][row%128][k%8]. One k-step chunk (128 rows x 32 k)
// is 8 KB contiguous, exactly the LDS image the MFMA frag reads want.
static __device__ __forceinline__ size_t pk_off(int row, int k, int K) {
  return (size_t)(row >> 7) * ((size_t)K * 128) + (size_t)(k >> 5) * 4096
       + (size_t)((((k >> 3) & 3) * 128 + (row & 127)) * 8 + (k & 7));
}

// ---- zero helper (float4 granularity) -------------------------------------
__global__ void k_zero(float4* __restrict__ p, int n4) {
  int i = blockIdx.x * 256 + threadIdx.x;
  if (i < n4) p[i] = float4{0.f, 0.f, 0.f, 0.f};
}

// ---- zero the 148 border positions of FT2 per image -----------------------
// FT2 layout: [img][koct(c/8)][1444(38x38)][c%8] f16
__global__ void k_border(f16* __restrict__ FT) {
  const int img = blockIdx.x;
  f16* base = FT + (size_t)img * 32 * 1444 * 8;
  for (int i = threadIdx.x; i < 148 * 256; i += 256) {
    int b = i >> 8, c = i & 255;
    int r, cc;
    if (b < 38)       { r = 0;          cc = b; }
    else if (b < 76)  { r = 37;         cc = b - 38; }
    else if (b < 112) { r = b - 76 + 1; cc = 0; }
    else              { r = b - 112 + 1; cc = 37; }
    base[((size_t)(c >> 3) * 1444 + r * 38 + cc) * 8 + (c & 7)] = (f16)0.f;
  }
}

// ---- pad + (optional BN+ReLU) + CHW fp32 -> FT2 f16 -----------------------
template <bool BN>
__global__ void k_pad(const float* __restrict__ src, f16* __restrict__ FT,
                      const float* __restrict__ mean, const float* __restrict__ istd,
                      const float* __restrict__ g, const float* __restrict__ be) {
  const int img = blockIdx.x, h = blockIdx.y, c = threadIdx.x;
  float sc = 1.f, sh = 0.f;
  if (BN) { sc = istd[c] * g[c]; sh = be[c] - mean[c] * sc; }
  const float* sp = src + ((size_t)img * 256 + c) * 1296 + h * 36;
  f16* op = FT + (((size_t)img * 32 + (c >> 3)) * 1444 + (h + 1) * 38 + 1) * 8 + (c & 7);
#pragma unroll 4
  for (int w = 0; w < 36; ++w) {
    float v = sp[w];
    if (BN) v = fmaxf(fmaf(v, sc, sh), 0.f);
    op[w * 8] = (f16)v;
  }
}

// ---- conv weights [256][256][3][3] fp32 -> packed f16 ---------------------
// dst: [oct(oc/128)][ks(0..71)][koct(0..3)][row128][kj8], k = t*256 + c
__global__ void k_pack_wc(const float* __restrict__ w, f16* __restrict__ dst) {
  int i = blockIdx.x * 256 + threadIdx.x;   // < 589,824
  int oct = i / 294912;
  int r = i - oct * 294912;
  int ks = r >> 12;
  int r2 = r & 4095;
  int koct = r2 >> 10;
  int r3 = r2 & 1023;
  int row = r3 >> 3, kj = r3 & 7;
  int k = ks * 32 + koct * 8 + kj;
  int t = k >> 8, c = k & 255;
  int oc = oct * 128 + row;
  dst[i] = (f16)w[(oc * 256 + c) * 9 + t];
}

// ---- pack fp32 [N][K] weights into packed f16 (write-coalesced) -----------
__global__ void k_pack_w(const float* __restrict__ src, f16* __restrict__ dst,
                         int K, int total) {
  int i = blockIdx.x * 256 + threadIdx.x;
  if (i >= total) return;
  const int blkSz = K * 128;
  int nt = i / blkSz;
  int wi = i - nt * blkSz;
  int ks = wi >> 12;
  int r2 = wi & 4095;
  int koct = r2 >> 10;
  int r3 = r2 & 1023;
  int col = r3 >> 3, kj = r3 & 7;
  int k = ks * 32 + koct * 8 + kj;
  int row = nt * 128 + col;
  dst[i] = (f16)src[(size_t)row * K + k];
}

// ---- 3x3 conv via MFMA implicit GEMM, 3-deep counted-vmcnt pipeline -------
// FT2 [img][32 koct][1444][8] f16, Wpk packed (k_pack_wc), y [64][256][1296].
__global__ __launch_bounds__(256) void k_conv_mfma(
    const f16* __restrict__ Wpk, const f16* __restrict__ FT2,
    const float* __restrict__ bias, float* __restrict__ y) {
  __shared__ f16x8 sA[1536];   // 3 buffers x 512 (8 KB each)
  __shared__ f16x8 sB[1536];
  const int bid = blockIdx.x;
  const int orig = (bid & 7) * 176 + (bid >> 3);   // bijective: 1408 % 8 == 0
  const int img = orig / 22;
  const int rem = orig - img * 22;
  const int oct = rem / 11;
  const int pt  = rem - oct * 11;
  const int m0 = oct * 128;
  const int p0 = pt * 128;
  const int tid = threadIdx.x;
  const int lane = tid & 63;
  const int wv = tid >> 6;
  const int wr = wv >> 1, wc = wv & 1;

  const f16* aBase = Wpk + (size_t)oct * 294912 + wv * 1024 + lane * 8;
  const f16* ftImg = FT2 + (size_t)img * 32 * 1444 * 8;
  int pos0 = p0 + lane;
  int pc0 = min(pos0, 1295);
  int pc1 = min(pos0 + 64, 1295);
  int pb0 = (pc0 / 36) * 38 + (pc0 % 36);   // padded-grid position index
  int pb1 = (pc1 / 36) * 38 + (pc1 % 36);

  const int loff = wv * 2048 + lane * 16;

  auto stage = [&](int buf, int ks) {
    const int t = ks >> 3;
    const int dy = t / 3, dx = t - dy * 3;
    const int cs = ks & 7;
    const int dyx = dy * 38 + dx;
    char* lA = (char*)sA + buf * 8192 + loff;
    char* lB = (char*)sB + buf * 8192 + loff;
    const f16* ap = aBase + (size_t)ks * 4096;
    const f16* bp = ftImg + ((size_t)(cs * 4 + wv) * 1444 + dyx) * 8;
    gload16(ap, lA);
    gload16(ap + 512, lA + 1024);
    gload16(bp + pb0 * 8, lB);
    gload16(bp + pb1 * 8, lB + 1024);
  };

  f32x4 acc[4][4] = {};
  const int fidxA = ((lane >> 4) << 7) + wr * 64 + (lane & 15);
  const int fidxB = ((lane >> 4) << 7) + wc * 64 + (lane & 15);

  stage(0, 0); stage(1, 1); stage(2, 2);   // 12 loads in flight per wave
  int cur = 0;
  for (int ks = 0; ks < 72; ++ks) {
    const int r = 71 - ks;
    if (r >= 2)      WAITB(8);   // oldest tile (this step) landed
    else if (r == 1) WAITB(4);
    else             WAITB(0);
    const int base = cur * 512;
    f16x8 af[4], bf[4];
#pragma unroll
    for (int i = 0; i < 4; ++i) {
      af[i] = sA[base + fidxA + i * 16];
      bf[i] = sB[base + fidxB + i * 16];
    }
#pragma unroll
    for (int i = 0; i < 4; ++i)
#pragma unroll
      for (int j = 0; j < 4; ++j)
        acc[i][j] = __builtin_amdgcn_mfma_f32_16x16x32_f16(af[i], bf[j], acc[i][j], 0, 0, 0);
    LGKB();                       // my ds_reads retired; safe to restage slot
    if (ks + 3 < 72) stage(cur, ks + 3);
    cur = (cur == 2) ? 0 : cur + 1;
  }

  const int colb = p0 + wc * 64 + (lane & 15);
  const int rowb = m0 + wr * 64 + ((lane >> 4) << 2);
#pragma unroll
  for (int i = 0; i < 4; ++i) {
#pragma unroll
    for (int j = 0; j < 4; ++j) {
      const int col = colb + j * 16;
      if (col < 1296) {
#pragma unroll
        for (int r = 0; r < 4; ++r) {
          const int oc = rowb + i * 16 + r;
          y[((size_t)img * 256 + oc) * 1296 + col] = acc[i][j][r] + bias[oc];
        }
      }
    }
  }
}

// ---- packed split-K f16 MFMA GEMM, 3-deep counted-vmcnt pipeline ----------
__global__ __launch_bounds__(256) void k_gemm_f16pk(
    const f16* __restrict__ Apk, const f16* __restrict__ Bpk,
    float* __restrict__ part, int K, int Nout, int stepsPerZ, int mrows) {
  __shared__ f16x8 sA[1536];
  __shared__ f16x8 sB[1536];
  const int nt = blockIdx.x, mt = blockIdx.y, z = blockIdx.z;
  const int tid = threadIdx.x;
  const int lane = tid & 63;
  const int wv = tid >> 6;
  const int wr = wv >> 1, wc = wv & 1;

  const f16* aC = Apk + (size_t)mt * K * 128 + wv * 1024 + lane * 8;
  const f16* bC = Bpk + (size_t)nt * K * 128 + wv * 1024 + lane * 8;
  const int loff = wv * 2048 + lane * 16;

  auto stage = [&](int buf, int ks) {
    char* lA = (char*)sA + buf * 8192 + loff;
    char* lB = (char*)sB + buf * 8192 + loff;
    const f16* ap = aC + (size_t)ks * 4096;
    const f16* bp = bC + (size_t)ks * 4096;
    gload16(ap, lA);
    gload16(ap + 512, lA + 1024);
    gload16(bp, lB);
    gload16(bp + 512, lB + 1024);
  };

  f32x4 acc[4][4] = {};
  const int fidxA = ((lane >> 4) << 7) + wr * 64 + (lane & 15);
  const int fidxB = ((lane >> 4) << 7) + wc * 64 + (lane & 15);

  const int ks0 = z * stepsPerZ;
  stage(0, ks0); stage(1, ks0 + 1); stage(2, ks0 + 2);   // stepsPerZ >= 3 always
  int cur = 0;
  for (int i = 0; i < stepsPerZ; ++i) {
    const int r = stepsPerZ - 1 - i;
    if (r >= 2)      WAITB(8);
    else if (r == 1) WAITB(4);
    else             WAITB(0);
    const int base = cur * 512;
    f16x8 af[4], bf[4];
#pragma unroll
    for (int j = 0; j < 4; ++j) {
      af[j] = sA[base + fidxA + j * 16];
      bf[j] = sB[base + fidxB + j * 16];
    }
#pragma unroll
    for (int ii = 0; ii < 4; ++ii)
#pragma unroll
      for (int jj = 0; jj < 4; ++jj)
        acc[ii][jj] = __builtin_amdgcn_mfma_f32_16x16x32_f16(af[ii], bf[jj], acc[ii][jj], 0, 0, 0);
    LGKB();
    if (i + 3 < stepsPerZ) stage(cur, ks0 + i + 3);
    cur = (cur == 2) ? 0 : cur + 1;
  }

  const size_t zoff = (size_t)z * mrows * Nout;
  const int colb = nt * 128 + wc * 64 + (lane & 15);
  const int rowb = mt * 128 + wr * 64 + ((lane >> 4) << 2);
#pragma unroll
  for (int i = 0; i < 4; ++i)
#pragma unroll
    for (int j = 0; j < 4; ++j)
#pragma unroll
      for (int r = 0; r < 4; ++r)
        part[zoff + (size_t)(rowb + i * 16 + r) * Nout + colb + j * 16] = acc[i][j][r];
}

// ---- reduce split-K partials + bias ---------------------------------------
__global__ void k_reduce(const float* __restrict__ part, const float* __restrict__ bias,
                         float* __restrict__ out, int mrows, int Mout, int Nout, int sk) {
  int i = blockIdx.x * 256 + threadIdx.x;
  if (i >= Mout * Nout) return;
  int row = i / Nout, col = i - row * Nout;
  float s = bias[col];
  for (int z = 0; z < sk; ++z)
    s += part[(size_t)z * mrows * Nout + (size_t)row * Nout + col];
  out[i] = s;
}

// ---- conv BN stats, two-pass: pass 1 over 4-image groups ------------------
__global__ void k_chan_stats_part(const float* __restrict__ y,
                                  float* __restrict__ psum, float* __restrict__ psq) {
  const int c = blockIdx.x, z = blockIdx.y, tid = threadIdx.x;
  float s = 0.f, ss = 0.f;
  for (int img = z * 4; img < z * 4 + 4; ++img) {
    const float* p = y + ((size_t)img * 256 + c) * 1296;
    for (int i = tid; i < 1296; i += 256) { float v = p[i]; s += v; ss += v * v; }
  }
  __shared__ float rs[256], rss[256];
  rs[tid] = s; rss[tid] = ss;
  __syncthreads();
  for (int o = 128; o > 0; o >>= 1) {
    if (tid < o) { rs[tid] += rs[tid + o]; rss[tid] += rss[tid + o]; }
    __syncthreads();
  }
  if (tid == 0) {
    psum[z * 256 + c] = rs[0];
    psq[z * 256 + c] = rss[0];
  }
}

// pass 2: fold 16 partials per channel
__global__ void k_chan_stats_final(const float* __restrict__ psum, const float* __restrict__ psq,
                                   float* __restrict__ mean, float* __restrict__ istd) {
  const int c = threadIdx.x;
  float s = 0.f, ss = 0.f;
  for (int z = 0; z < 16; ++z) { s += psum[z * 256 + c]; ss += psq[z * 256 + c]; }
  float m = s * (1.f / 82944.f);
  float var = ss * (1.f / 82944.f) - m * m;
  mean[c] = m;
  istd[c] = rsqrtf(var + 1e-5f);
}

// ---- PrRoI separable weights + sparse-range metadata ----------------------
__global__ void k_wxy(const float* __restrict__ rois, int ntot, int P,
                      float* __restrict__ Wx, float* __restrict__ Wy,
                      float* __restrict__ area,
                      int* __restrict__ HLO, int* __restrict__ HCNT,
                      int* __restrict__ WLO) {
  int idx = blockIdx.x * blockDim.x + threadIdx.x;
  if (idx >= ntot) return;
  float rx = rois[idx * 4 + 0], ry = rois[idx * 4 + 1];
  float rw = rois[idx * 4 + 2], rh = rois[idx * 4 + 3];
  float x1 = rx * 0.125f, y1 = ry * 0.125f;
  float x2 = (rx + rw) * 0.125f, y2 = (ry + rh) * 0.125f;
  float bw = (x2 - x1) / P, bh = (y2 - y1) / P;
  area[idx] = bw * bh;
  int hlo = max(0, (int)ceilf(y1 - 1.f));
  int hhi = min(35, (int)floorf(y2 + 1.f));
  HLO[idx] = hlo;
  HCNT[idx] = max(0, hhi - hlo + 1);
  for (int q = 0; q < P; ++q) {
    float xlo = x1 + q * bw, ylo = y1 + q * bh;
    WLO[idx * P + q] = min(31, max(0, (int)ceilf(xlo - 1.f)));
    for (int g = 0; g < 36; ++g) {
      float fg = (float)g;
      Wx[(idx * P + q) * 36 + g] = hat_int(xlo + bw - fg) - hat_int(xlo - fg);
      Wy[(idx * P + q) * 36 + g] = hat_int(ylo + bh - fg) - hat_int(ylo - fg);
    }
  }
}

// ---- PrRoI pool with fused BN+ReLU on the read path -----------------------
// feat is RAW conv output (pre-BN); thread c applies v -> max(v*sc+sh, 0).
// SPARSE: h restricted to active rows; 5-wide x windows (support <= 5 taps
// for both P=5 (bw<=2.5) and P=7 (bw<=1.79); wave-uniform bounds).
template <int P, bool MOD, bool SPARSE>
__global__ __launch_bounds__(256) void k_pool(
    const float* __restrict__ feat, const float* __restrict__ Wx,
    const float* __restrict__ Wy, const float* __restrict__ area,
    const int* __restrict__ HLO, const int* __restrict__ HCNT,
    const int* __restrict__ WLO,
    const float* __restrict__ mean, const float* __restrict__ istd,
    const float* __restrict__ g, const float* __restrict__ be,
    const float* __restrict__ mod, f16* __restrict__ outPk, int N) {
  const int s = blockIdx.x, n = blockIdx.y;
  const int idx = s * N + n;
  const int c = threadIdx.x;
  constexpr int KD = P * P * 256;
  __shared__ float sWx[P * 36], sWy[P * 36];
  __shared__ int sWLO[P];
  __shared__ int sH[2];
  for (int i = threadIdx.x; i < P * 36; i += 256) {
    sWx[i] = Wx[(size_t)idx * P * 36 + i];
    sWy[i] = Wy[(size_t)idx * P * 36 + i];
  }
  if (threadIdx.x < P) sWLO[threadIdx.x] = WLO[idx * P + threadIdx.x];
  if (threadIdx.x == 0) { sH[0] = HLO[idx]; sH[1] = HCNT[idx]; }
  __syncthreads();
  const float sc = istd[c] * g[c];
  const float sh = be[c] - mean[c] * sc;
  const float* f = feat + ((size_t)s * 256 + c) * 1296;
  float o[P][P] = {};
  const int hlo = SPARSE ? sH[0] : 0;
  const int hcnt = SPARSE ? sH[1] : 36;
  for (int hh = 0; hh < hcnt; ++hh) {
    const int h = hlo + hh;
    const float* rp = f + h * 36;
    float colsum[P];
    if (SPARSE) {
#pragma unroll
      for (int q = 0; q < P; ++q) {
        const int w0 = sWLO[q];
        float v = 0.f;
#pragma unroll
        for (int j = 0; j < 5; ++j) {
          float x = fmaxf(fmaf(rp[w0 + j], sc, sh), 0.f);
          v = fmaf(sWx[q * 36 + w0 + j], x, v);
        }
        colsum[q] = v;
      }
    } else {
      float row[36];
#pragma unroll
      for (int w = 0; w < 36; ++w) row[w] = fmaxf(fmaf(rp[w], sc, sh), 0.f);
#pragma unroll
      for (int q = 0; q < P; ++q) {
        float v = 0.f;
#pragma unroll
        for (int w = 0; w < 36; ++w) v = fmaf(sWx[q * 36 + w], row[w], v);
        colsum[q] = v;
      }
    }
#pragma unroll
    for (int p = 0; p < P; ++p) {
      const float wy = sWy[p * 36 + h];
      if (wy != 0.f) {
#pragma unroll
        for (int q = 0; q < P; ++q) o[p][q] = fmaf(wy, colsum[q], o[p][q]);
      }
    }
  }
  float a = area[idx];
  float inv = (a > 0.f) ? 1.f / fmaxf(a, 1e-12f) : 0.f;
  float msc = MOD ? (mod[s * 256 + c] * inv) : inv;
  const int kbase = c * (P * P);
#pragma unroll
  for (int p = 0; p < P; ++p)
#pragma unroll
    for (int q = 0; q < P; ++q)
      outPk[pk_off(idx, kbase + p * P + q, KD)] = (f16)(o[p][q] * msc);
}

// ---- FC BN stats, two-pass deterministic ----------------------------------
__global__ void k_fc_stats_part(const float* __restrict__ y, int M, int Nf, int rpz,
                                float* __restrict__ psum, float* __restrict__ psq) {
  int col = blockIdx.x * 256 + threadIdx.x;
  int z = blockIdx.y;
  if (col >= Nf) return;
  int r0 = z * rpz;
  int r1 = min(M, r0 + rpz);
  float s = 0.f, ss = 0.f;
  for (int m = r0; m < r1; ++m) {
    float v = y[(size_t)m * Nf + col];
    s += v; ss += v * v;
  }
  psum[(size_t)z * Nf + col] = s;
  psq[(size_t)z * Nf + col] = ss;
}

__global__ void k_fc_stats_final(const float* __restrict__ psum, const float* __restrict__ psq,
                                 int nz, int Nf, int M,
                                 float* __restrict__ mean, float* __restrict__ istd) {
  int col = blockIdx.x * 256 + threadIdx.x;
  if (col >= Nf) return;
  float s = 0.f, ss = 0.f;
  for (int z = 0; z < nz; ++z) {
    s += psum[(size_t)z * Nf + col];
    ss += psq[(size_t)z * Nf + col];
  }
  float mu = s / (float)M;
  float var = ss / (float)M - mu * mu;
  mean[col] = mu;
  istd[col] = rsqrtf(var + 1e-5f);
}

// ---- FC BN+ReLU elementwise (fp32 in place) -------------------------------
__global__ void k_fc_bn_relu(float* __restrict__ y, const float* __restrict__ mean,
                             const float* __restrict__ istd, const float* __restrict__ g,
                             const float* __restrict__ be, int total, int Nf) {
  int i = blockIdx.x * 256 + threadIdx.x;
  if (i >= total) return;
  int col = i % Nf;
  float sc = istd[col] * g[col];
  float sh = be[col] - mean[col] * sc;
  y[i] = fmaxf(fmaf(y[i], sc, sh), 0.f);
}

// ---- FC BN+ReLU -> packed f16 (next GEMM's A operand) ---------------------
__global__ void k_fc_bn_relu_pk(const float* __restrict__ y, const float* __restrict__ mean,
                                const float* __restrict__ istd, const float* __restrict__ g,
                                const float* __restrict__ be, f16* __restrict__ xpk,
                                int total, int Nf) {
  int i = blockIdx.x * 256 + threadIdx.x;
  if (i >= total) return;
  int row = i / Nf, col = i - row * Nf;
  float sc = istd[col] * g[col];
  float sh = be[col] - mean[col] * sc;
  float v = fmaxf(fmaf(y[i], sc, sh), 0.f);
  xpk[pk_off(row, col, Nf)] = (f16)v;
}

// ---- IoU head -------------------------------------------------------------
__global__ void k_iou(const float* __restrict__ x, const float* __restrict__ w,
                      const float* __restrict__ b, float* __restrict__ out) {
  const int r = blockIdx.x, tid = threadIdx.x;
  float s = 0.f;
  for (int k = tid; k < 1024; k += 256) s = fmaf(x[(size_t)r * 1024 + k], w[k], s);
  __shared__ float red[256];
  red[tid] = s;
  __syncthreads();
  for (int o = 128; o > 0; o >>= 1) {
    if (tid < o) red[tid] += red[tid + o];
    __syncthreads();
  }
  if (tid == 0) out[r] = red[0] + b[0];
}

// ---------------------------------------------------------------------------
// Workspace layout (float offsets). Total ~46.21M floats = 184.9 MB.
// ---------------------------------------------------------------------------
static const size_t O_A      = 0;            // 21,233,664 conv out fp32
static const size_t O_PSUM   = 13000000;     // 65,536 (in A region, fc only)
static const size_t O_PSQ    = 13065536;     // 65,536 (in A region, fc only)
static const size_t O_WPK2RT = 16000000;     // in A region
static const size_t O_WPK2R  = 20000000;     // in A region
static const size_t O_FT     = 21233664;     // 11,829,248 f16 FT2 / PHPK
static const size_t O_X2PK   = 21233664 + 6422528;  // in FT region
static const size_t O_WC     = 33062912;     //    294,912 conv w packed f16
static const size_t O_WPK1RT = 33357824;     //  6,422,528
static const size_t O_WPK1R  = 39780352;     //  3,276,800
static const size_t O_PRPK   = 43057152;     //    409,600
static const size_t O_Y1     = 43466752;     //  1,048,576
static const size_t O_Y2     = 44515328;     //  1,048,576
static const size_t O_MOD    = 45563904;     //     16,384
static const size_t O_WXR    = 45580288;     //     11,520
static const size_t O_WYR    = 45591808;     //     11,520
static const size_t O_ARR    = 45603328;     //         64
static const size_t O_WXT    = 45603392;     //    258,048
static const size_t O_WYT    = 45861440;     //    258,048
static const size_t O_ART    = 46119488;     //      1,024
static const size_t O_MEAN   = 46120512;     //      1,024
static const size_t O_ISTD   = 46121536;     //      1,024
static const size_t O_X1PK   = 46122560;     //     65,536
static const size_t O_META   = 46188096;     //      9,664 (ints)
static const size_t O_PSC    = 46197760;     //      8,192 (chan-stats partials)

extern "C" void kernel_launch(void* const* d_in, const int* in_sizes, int n_in,
                              void* d_out, int out_size, void* d_ws, size_t ws_size,
                              hipStream_t stream) {
  (void)in_sizes; (void)n_in; (void)out_size; (void)ws_size;
  const float* feat1  = (const float*)d_in[0];
  const float* feat2  = (const float*)d_in[1];
  const float* bb1    = (const float*)d_in[2];
  const float* props  = (const float*)d_in[3];
  const float* w_c1r  = (const float*)d_in[4];
  const float* b_c1r  = (const float*)d_in[5];
  const float* g_c1r  = (const float*)d_in[6];
  const float* be_c1r = (const float*)d_in[7];
  const float* w_c1t  = (const float*)d_in[8];
  const float* b_c1t  = (const float*)d_in[9];
  const float* g_c1t  = (const float*)d_in[10];
  const float* be_c1t = (const float*)d_in[11];
  const float* w_c2t  = (const float*)d_in[12];
  const float* b_c2t  = (const float*)d_in[13];
  const float* g_c2t  = (const float*)d_in[14];
  const float* be_c2t = (const float*)d_in[15];
  const float* w_f1r  = (const float*)d_in[16];
  const float* b_f1r  = (const float*)d_in[17];
  const float* g_f1r  = (const float*)d_in[18];
  const float* be_f1r = (const float*)d_in[19];
  const float* w_f2r  = (const float*)d_in[20];
  const float* b_f2r  = (const float*)d_in[21];
  const float* g_f2r  = (const float*)d_in[22];
  const float* be_f2r = (const float*)d_in[23];
  const float* w_f1rt = (const float*)d_in[24];
  const float* b_f1rt = (const float*)d_in[25];
  const float* g_f1rt = (const float*)d_in[26];
  const float* be_f1rt= (const float*)d_in[27];
  const float* w_f2rt = (const float*)d_in[28];
  const float* b_f2rt = (const float*)d_in[29];
  const float* g_f2rt = (const float*)d_in[30];
  const float* be_f2rt= (const float*)d_in[31];
  const float* w_iou  = (const float*)d_in[32];
  const float* b_iou  = (const float*)d_in[33];

  float* ws    = (float*)d_ws;
  float* A     = ws + O_A;
  float* PART  = ws + O_A;                  // overlays A
  float* PSUM  = ws + O_PSUM;
  float* PSQ   = ws + O_PSQ;
  f16*   WPK2RT= (f16*)(ws + O_WPK2RT);
  f16*   WPK2R = (f16*)(ws + O_WPK2R);
  f16*   FT2   = (f16*)(ws + O_FT);
  f16*   PHPK  = FT2;                       // overlays FT2
  f16*   X2PK  = (f16*)(ws + O_X2PK);
  f16*   WC    = (f16*)(ws + O_WC);
  f16*   WPK1RT= (f16*)(ws + O_WPK1RT);
  f16*   WPK1R = (f16*)(ws + O_WPK1R);
  f16*   PRPK  = (f16*)(ws + O_PRPK);
  float* Y1    = ws + O_Y1;
  float* Y2    = ws + O_Y2;
  float* MODp  = ws + O_MOD;
  float* WXR   = ws + O_WXR;
  float* WYR   = ws + O_WYR;
  float* ARR   = ws + O_ARR;
  float* WXT   = ws + O_WXT;
  float* WYT   = ws + O_WYT;
  float* ART   = ws + O_ART;
  float* MEAN  = ws + O_MEAN;
  float* ISTD  = ws + O_ISTD;
  f16*   X1PK  = (f16*)(ws + O_X1PK);
  int*   META  = (int*)(ws + O_META);
  float* PSUMC = ws + O_PSC;        // 4096
  float* PSQC  = ws + O_PSC + 4096; // 4096
  int* HLOR = META;          // 64
  int* HCNTR= META + 64;     // 64
  int* WLOR = META + 128;    // 320
  int* HLOT = META + 448;    // 1024
  int* HCNTT= META + 1472;   // 1024
  int* WLOT = META + 2496;   // 7168

  // ===== get_modulation branch =====
  k_border<<<64, 256, 0, stream>>>(FT2);
  k_pack_wc<<<2304, 256, 0, stream>>>(w_c1r, WC);
  k_pad<false><<<dim3(64, 36), 256, 0, stream>>>(feat1, FT2, nullptr, nullptr, nullptr, nullptr);
  k_conv_mfma<<<1408, 256, 0, stream>>>(WC, FT2, b_c1r, A);
  k_chan_stats_part<<<dim3(256, 16), 256, 0, stream>>>(A, PSUMC, PSQC);
  k_chan_stats_final<<<1, 256, 0, stream>>>(PSUMC, PSQC, MEAN, ISTD);

  k_wxy<<<1, 64, 0, stream>>>(bb1, 64, 5, WXR, WYR, ARR, HLOR, HCNTR, WLOR);
  k_zero<<<400, 256, 0, stream>>>((float4*)PRPK, 102400);
  k_pool<5, false, true><<<dim3(64, 1), 256, 0, stream>>>(
      A, WXR, WYR, ARR, HLOR, HCNTR, WLOR, MEAN, ISTD, g_c1r, be_c1r, nullptr, PRPK, 1);

  k_pack_w<<<25600, 256, 0, stream>>>(w_f1r, WPK1R, 6400, 6553600);
  k_gemm_f16pk<<<dim3(8, 1, 8), 256, 0, stream>>>(PRPK, WPK1R, PART, 6400, 1024, 25, 128);
  k_reduce<<<256, 256, 0, stream>>>(PART, b_f1r, Y1, 128, 64, 1024, 8);
  k_fc_stats_part<<<dim3(4, 8), 256, 0, stream>>>(Y1, 64, 1024, 8, PSUM, PSQ);
  k_fc_stats_final<<<4, 256, 0, stream>>>(PSUM, PSQ, 8, 1024, 64, MEAN, ISTD);
  k_zero<<<64, 256, 0, stream>>>((float4*)X1PK, 16384);
  k_fc_bn_relu_pk<<<256, 256, 0, stream>>>(Y1, MEAN, ISTD, g_f1r, be_f1r, X1PK, 64 * 1024, 1024);

  k_pack_w<<<1024, 256, 0, stream>>>(w_f2r, WPK2R, 1024, 262144);
  k_gemm_f16pk<<<dim3(2, 1, 4), 256, 0, stream>>>(X1PK, WPK2R, PART, 1024, 256, 8, 128);
  k_reduce<<<64, 256, 0, stream>>>(PART, b_f2r, MODp, 128, 64, 256, 4);
  k_fc_stats_part<<<dim3(1, 8), 256, 0, stream>>>(MODp, 64, 256, 8, PSUM, PSQ);
  k_fc_stats_final<<<1, 256, 0, stream>>>(PSUM, PSQ, 8, 256, 64, MEAN, ISTD);
  k_fc_bn_relu<<<64, 256, 0, stream>>>(MODp, MEAN, ISTD, g_f2r, be_f2r, 64 * 256, 256);

  // ===== get_iou_feat branch =====
  k_pack_wc<<<2304, 256, 0, stream>>>(w_c1t, WC);
  k_pad<false><<<dim3(64, 36), 256, 0, stream>>>(feat2, FT2, nullptr, nullptr, nullptr, nullptr);
  k_conv_mfma<<<1408, 256, 0, stream>>>(WC, FT2, b_c1t, A);
  k_chan_stats_part<<<dim3(256, 16), 256, 0, stream>>>(A, PSUMC, PSQC);
  k_chan_stats_final<<<1, 256, 0, stream>>>(PSUMC, PSQC, MEAN, ISTD);
  k_pad<true><<<dim3(64, 36), 256, 0, stream>>>(A, FT2, MEAN, ISTD, g_c1t, be_c1t);

  k_pack_wc<<<2304, 256, 0, stream>>>(w_c2t, WC);
  k_conv_mfma<<<1408, 256, 0, stream>>>(WC, FT2, b_c2t, A);
  k_chan_stats_part<<<dim3(256, 16), 256, 0, stream>>>(A, PSUMC, PSQC);
  k_chan_stats_final<<<1, 256, 0, stream>>>(PSUMC, PSQC, MEAN, ISTD);

  // ===== predict_iou =====
  k_wxy<<<16, 64, 0, stream>>>(props, 1024, 7, WXT, WYT, ART, HLOT, HCNTT, WLOT);
  k_pool<7, true, true><<<dim3(64, 16), 256, 0, stream>>>(
      A, WXT, WYT, ART, HLOT, HCNTT, WLOT, MEAN, ISTD, g_c2t, be_c2t, MODp, PHPK, 16);

  k_pack_w<<<50176, 256, 0, stream>>>(w_f1rt, WPK1RT, 12544, 12845056);
  k_gemm_f16pk<<<dim3(8, 8, 8), 256, 0, stream>>>(PHPK, WPK1RT, PART, 12544, 1024, 49, 1024);
  k_reduce<<<4096, 256, 0, stream>>>(PART, b_f1rt, Y1, 1024, 1024, 1024, 8);
  k_fc_stats_part<<<dim3(4, 64), 256, 0, stream>>>(Y1, 1024, 1024, 16, PSUM, PSQ);
  k_fc_stats_final<<<4, 256, 0, stream>>>(PSUM, PSQ, 64, 1024, 1024, MEAN, ISTD);
  k_fc_bn_relu_pk<<<4096, 256, 0, stream>>>(Y1, MEAN, ISTD, g_f1rt, be_f1rt, X2PK, 1024 * 1024, 1024);

  k_pack_w<<<4096, 256, 0, stream>>>(w_f2rt, WPK2RT, 1024, 1048576);
  k_gemm_f16pk<<<dim3(8, 8, 4), 256, 0, stream>>>(X2PK, WPK2RT, PART, 1024, 1024, 8, 1024);
  k_reduce<<<4096, 256, 0, stream>>>(PART, b_f2rt, Y2, 1024, 1024, 1024, 4);
  k_fc_stats_part<<<dim3(4, 64), 256, 0, stream>>>(Y2, 1024, 1024, 16, PSUM, PSQ);
  k_fc_stats_final<<<4, 256, 0, stream>>>(PSUM, PSQ, 64, 1024, 1024, MEAN, ISTD);
  k_fc_bn_relu<<<4096, 256, 0, stream>>>(Y2, MEAN, ISTD, g_f2rt, be_f2rt, 1024 * 1024, 1024);

  k_iou<<<1024, 256, 0, stream>>>(Y2, w_iou, b_iou, (float*)d_out);
}

// Round 8
// 1068.772 us; speedup vs baseline: 7.0471x; 1.0251x over previous
//
#include <hip/hip_runtime.h>
#include <cstddef>

// ---------------------------------------------------------------------------
// FPNIoUNetHR forward — round 8: HWC f16 conv outputs (coalesced pool/stats/
// pad reads, half the conv write traffic). Convs keep 3-deep counted-vmcnt.
// S=64, C=256, H=W=36, N=16.
// ---------------------------------------------------------------------------

typedef _Float16 f16;
typedef __attribute__((ext_vector_type(4))) _Float16 f16x4;
typedef __attribute__((ext_vector_type(8))) _Float16 f16x8;
typedef __attribute__((ext_vector_type(4))) float f32x4;

__device__ __forceinline__ void gload16(const void* g, void* l) {
  __builtin_amdgcn_global_load_lds((const __attribute__((address_space(1))) void*)g,
                                   (__attribute__((address_space(3))) void*)l, 16, 0, 0);
}

#define WAITB(N) asm volatile("s_waitcnt vmcnt(" #N ")\n\ts_barrier" ::: "memory")
#define LGKB()   asm volatile("s_waitcnt lgkmcnt(0)\n\ts_barrier" ::: "memory")

static __device__ __forceinline__ float hat_int(float x) {
  float u = fminf(1.f, fmaxf(-1.f, x));
  float a = 0.5f * (1.f + u) * (1.f + u);
  float b = 0.5f + u - 0.5f * u * u;
  return (u <= 0.f) ? a : b;
}

// Packed GEMM operand layout: element (row,k) of a row-major [M][K] matrix ->
// [row/128][k/32][(k/8)%4][row%128][k%8]. One k-step chunk (128 rows x 32 k)
// is 8 KB contiguous, exactly the LDS image the MFMA frag reads want.
static __device__ __forceinline__ size_t pk_off(int row, int k, int K) {
  return (size_t)(row >> 7) * ((size_t)K * 128) + (size_t)(k >> 5) * 4096
       + (size_t)((((k >> 3) & 3) * 128 + (row & 127)) * 8 + (k & 7));
}

// ---- zero helper (float4 granularity) -------------------------------------
__global__ void k_zero(float4* __restrict__ p, int n4) {
  int i = blockIdx.x * 256 + threadIdx.x;
  if (i < n4) p[i] = float4{0.f, 0.f, 0.f, 0.f};
}

// ---- zero the 148 border positions of FT2 per image -----------------------
// FT2 layout: [img][koct(c/8)][1444(38x38)][c%8] f16
__global__ void k_border(f16* __restrict__ FT) {
  const int img = blockIdx.x;
  f16* base = FT + (size_t)img * 32 * 1444 * 8;
  for (int i = threadIdx.x; i < 148 * 256; i += 256) {
    int b = i >> 8, c = i & 255;
    int r, cc;
    if (b < 38)       { r = 0;          cc = b; }
    else if (b < 76)  { r = 37;         cc = b - 38; }
    else if (b < 112) { r = b - 76 + 1; cc = 0; }
    else              { r = b - 112 + 1; cc = 37; }
    base[((size_t)(c >> 3) * 1444 + r * 38 + cc) * 8 + (c & 7)] = (f16)0.f;
  }
}

// ---- pad fp32 CHW input -> FT2 f16 (model inputs feat1/feat2) -------------
__global__ void k_pad(const float* __restrict__ src, f16* __restrict__ FT) {
  const int img = blockIdx.x, h = blockIdx.y, c = threadIdx.x;
  const float* sp = src + ((size_t)img * 256 + c) * 1296 + h * 36;
  f16* op = FT + (((size_t)img * 32 + (c >> 3)) * 1444 + (h + 1) * 38 + 1) * 8 + (c & 7);
#pragma unroll 4
  for (int w = 0; w < 36; ++w) op[w * 8] = (f16)sp[w];
}

// ---- pad HWC f16 conv output + BN+ReLU -> FT2 f16 -------------------------
__global__ void k_pad2(const f16* __restrict__ yH, f16* __restrict__ FT,
                       const float* __restrict__ mean, const float* __restrict__ istd,
                       const float* __restrict__ g, const float* __restrict__ be) {
  const int img = blockIdx.x, h = blockIdx.y, c = threadIdx.x;
  const float sc = istd[c] * g[c];
  const float sh = be[c] - mean[c] * sc;
  const f16* sp = yH + ((size_t)img * 1296 + h * 36) * 256 + c;
  f16* op = FT + (((size_t)img * 32 + (c >> 3)) * 1444 + (h + 1) * 38 + 1) * 8 + (c & 7);
#pragma unroll 4
  for (int w = 0; w < 36; ++w) {
    float v = fmaxf(fmaf((float)sp[w * 256], sc, sh), 0.f);
    op[w * 8] = (f16)v;
  }
}

// ---- conv weights [256][256][3][3] fp32 -> packed f16 ---------------------
// dst: [oct(oc/128)][ks(0..71)][koct(0..3)][row128][kj8], k = t*256 + c
__global__ void k_pack_wc(const float* __restrict__ w, f16* __restrict__ dst) {
  int i = blockIdx.x * 256 + threadIdx.x;   // < 589,824
  int oct = i / 294912;
  int r = i - oct * 294912;
  int ks = r >> 12;
  int r2 = r & 4095;
  int koct = r2 >> 10;
  int r3 = r2 & 1023;
  int row = r3 >> 3, kj = r3 & 7;
  int k = ks * 32 + koct * 8 + kj;
  int t = k >> 8, c = k & 255;
  int oc = oct * 128 + row;
  dst[i] = (f16)w[(oc * 256 + c) * 9 + t];
}

// ---- pack fp32 [N][K] weights into packed f16 (write-coalesced) -----------
__global__ void k_pack_w(const float* __restrict__ src, f16* __restrict__ dst,
                         int K, int total) {
  int i = blockIdx.x * 256 + threadIdx.x;
  if (i >= total) return;
  const int blkSz = K * 128;
  int nt = i / blkSz;
  int wi = i - nt * blkSz;
  int ks = wi >> 12;
  int r2 = wi & 4095;
  int koct = r2 >> 10;
  int r3 = r2 & 1023;
  int col = r3 >> 3, kj = r3 & 7;
  int k = ks * 32 + koct * 8 + kj;
  int row = nt * 128 + col;
  dst[i] = (f16)src[(size_t)row * K + k];
}

// ---- 3x3 conv via MFMA implicit GEMM, 3-deep counted-vmcnt pipeline -------
// FT2 [img][32 koct][1444][8] f16, Wpk packed, out yH [img][1296][256] f16.
__global__ __launch_bounds__(256) void k_conv_mfma(
    const f16* __restrict__ Wpk, const f16* __restrict__ FT2,
    const float* __restrict__ bias, f16* __restrict__ yH) {
  __shared__ f16x8 sA[1536];   // 3 buffers x 512 (8 KB each)
  __shared__ f16x8 sB[1536];
  const int bid = blockIdx.x;
  const int orig = (bid & 7) * 176 + (bid >> 3);   // bijective: 1408 % 8 == 0
  const int img = orig / 22;
  const int rem = orig - img * 22;
  const int oct = rem / 11;
  const int pt  = rem - oct * 11;
  const int m0 = oct * 128;
  const int p0 = pt * 128;
  const int tid = threadIdx.x;
  const int lane = tid & 63;
  const int wv = tid >> 6;
  const int wr = wv >> 1, wc = wv & 1;

  const f16* aBase = Wpk + (size_t)oct * 294912 + wv * 1024 + lane * 8;
  const f16* ftImg = FT2 + (size_t)img * 32 * 1444 * 8;
  int pos0 = p0 + lane;
  int pc0 = min(pos0, 1295);
  int pc1 = min(pos0 + 64, 1295);
  int pb0 = (pc0 / 36) * 38 + (pc0 % 36);
  int pb1 = (pc1 / 36) * 38 + (pc1 % 36);

  const int loff = wv * 2048 + lane * 16;

  auto stage = [&](int buf, int ks) {
    const int t = ks >> 3;
    const int dy = t / 3, dx = t - dy * 3;
    const int cs = ks & 7;
    const int dyx = dy * 38 + dx;
    char* lA = (char*)sA + buf * 8192 + loff;
    char* lB = (char*)sB + buf * 8192 + loff;
    const f16* ap = aBase + (size_t)ks * 4096;
    const f16* bp = ftImg + ((size_t)(cs * 4 + wv) * 1444 + dyx) * 8;
    gload16(ap, lA);
    gload16(ap + 512, lA + 1024);
    gload16(bp + pb0 * 8, lB);
    gload16(bp + pb1 * 8, lB + 1024);
  };

  f32x4 acc[4][4] = {};
  const int fidxA = ((lane >> 4) << 7) + wr * 64 + (lane & 15);
  const int fidxB = ((lane >> 4) << 7) + wc * 64 + (lane & 15);

  stage(0, 0); stage(1, 1); stage(2, 2);   // 12 loads in flight per wave
  int cur = 0;
  for (int ks = 0; ks < 72; ++ks) {
    const int r = 71 - ks;
    if (r >= 2)      WAITB(8);
    else if (r == 1) WAITB(4);
    else             WAITB(0);
    const int base = cur * 512;
    f16x8 af[4], bf[4];
#pragma unroll
    for (int i = 0; i < 4; ++i) {
      af[i] = sA[base + fidxA + i * 16];
      bf[i] = sB[base + fidxB + i * 16];
    }
#pragma unroll
    for (int i = 0; i < 4; ++i)
#pragma unroll
      for (int j = 0; j < 4; ++j)
        acc[i][j] = __builtin_amdgcn_mfma_f32_16x16x32_f16(af[i], bf[j], acc[i][j], 0, 0, 0);
    LGKB();
    if (ks + 3 < 72) stage(cur, ks + 3);
    cur = (cur == 2) ? 0 : cur + 1;
  }

  const int colb = p0 + wc * 64 + (lane & 15);
  const int rowb = m0 + wr * 64 + ((lane >> 4) << 2);
  f16* yb = yH + (size_t)img * 1296 * 256;
#pragma unroll
  for (int i = 0; i < 4; ++i) {
    const int oc0 = rowb + i * 16;
    float b0 = bias[oc0], b1 = bias[oc0 + 1], b2 = bias[oc0 + 2], b3 = bias[oc0 + 3];
#pragma unroll
    for (int j = 0; j < 4; ++j) {
      const int col = colb + j * 16;
      if (col < 1296) {
        f16x4 v;
        v[0] = (f16)(acc[i][j][0] + b0);
        v[1] = (f16)(acc[i][j][1] + b1);
        v[2] = (f16)(acc[i][j][2] + b2);
        v[3] = (f16)(acc[i][j][3] + b3);
        *reinterpret_cast<f16x4*>(yb + (size_t)col * 256 + oc0) = v;
      }
    }
  }
}

// ---- packed split-K f16 MFMA GEMM, 3-deep counted-vmcnt pipeline ----------
__global__ __launch_bounds__(256) void k_gemm_f16pk(
    const f16* __restrict__ Apk, const f16* __restrict__ Bpk,
    float* __restrict__ part, int K, int Nout, int stepsPerZ, int mrows) {
  __shared__ f16x8 sA[1536];
  __shared__ f16x8 sB[1536];
  const int nt = blockIdx.x, mt = blockIdx.y, z = blockIdx.z;
  const int tid = threadIdx.x;
  const int lane = tid & 63;
  const int wv = tid >> 6;
  const int wr = wv >> 1, wc = wv & 1;

  const f16* aC = Apk + (size_t)mt * K * 128 + wv * 1024 + lane * 8;
  const f16* bC = Bpk + (size_t)nt * K * 128 + wv * 1024 + lane * 8;
  const int loff = wv * 2048 + lane * 16;

  auto stage = [&](int buf, int ks) {
    char* lA = (char*)sA + buf * 8192 + loff;
    char* lB = (char*)sB + buf * 8192 + loff;
    const f16* ap = aC + (size_t)ks * 4096;
    const f16* bp = bC + (size_t)ks * 4096;
    gload16(ap, lA);
    gload16(ap + 512, lA + 1024);
    gload16(bp, lB);
    gload16(bp + 512, lB + 1024);
  };

  f32x4 acc[4][4] = {};
  const int fidxA = ((lane >> 4) << 7) + wr * 64 + (lane & 15);
  const int fidxB = ((lane >> 4) << 7) + wc * 64 + (lane & 15);

  const int ks0 = z * stepsPerZ;
  stage(0, ks0); stage(1, ks0 + 1); stage(2, ks0 + 2);
  int cur = 0;
  for (int i = 0; i < stepsPerZ; ++i) {
    const int r = stepsPerZ - 1 - i;
    if (r >= 2)      WAITB(8);
    else if (r == 1) WAITB(4);
    else             WAITB(0);
    const int base = cur * 512;
    f16x8 af[4], bf[4];
#pragma unroll
    for (int j = 0; j < 4; ++j) {
      af[j] = sA[base + fidxA + j * 16];
      bf[j] = sB[base + fidxB + j * 16];
    }
#pragma unroll
    for (int ii = 0; ii < 4; ++ii)
#pragma unroll
      for (int jj = 0; jj < 4; ++jj)
        acc[ii][jj] = __builtin_amdgcn_mfma_f32_16x16x32_f16(af[ii], bf[jj], acc[ii][jj], 0, 0, 0);
    LGKB();
    if (i + 3 < stepsPerZ) stage(cur, ks0 + i + 3);
    cur = (cur == 2) ? 0 : cur + 1;
  }

  const size_t zoff = (size_t)z * mrows * Nout;
  const int colb = nt * 128 + wc * 64 + (lane & 15);
  const int rowb = mt * 128 + wr * 64 + ((lane >> 4) << 2);
#pragma unroll
  for (int i = 0; i < 4; ++i)
#pragma unroll
    for (int j = 0; j < 4; ++j)
#pragma unroll
      for (int r = 0; r < 4; ++r)
        part[zoff + (size_t)(rowb + i * 16 + r) * Nout + colb + j * 16] = acc[i][j][r];
}

// ---- reduce split-K partials + bias ---------------------------------------
__global__ void k_reduce(const float* __restrict__ part, const float* __restrict__ bias,
                         float* __restrict__ out, int mrows, int Mout, int Nout, int sk) {
  int i = blockIdx.x * 256 + threadIdx.x;
  if (i >= Mout * Nout) return;
  int row = i / Nout, col = i - row * Nout;
  float s = bias[col];
  for (int z = 0; z < sk; ++z)
    s += part[(size_t)z * mrows * Nout + (size_t)row * Nout + col];
  out[i] = s;
}

// ---- conv BN stats from HWC f16, two-pass ---------------------------------
// pass 1: 324 blocks; block z sums positions [z*256, z*256+256) (82944=324*256)
__global__ void k_chan_stats_hwc(const f16* __restrict__ yH,
                                 float* __restrict__ psum, float* __restrict__ psq) {
  const int z = blockIdx.x, c = threadIdx.x;
  const f16* p = yH + (size_t)z * 256 * 256 + c;
  float s = 0.f, ss = 0.f;
#pragma unroll 4
  for (int i = 0; i < 256; ++i) {
    float v = (float)p[(size_t)i * 256];
    s += v; ss += v * v;
  }
  psum[z * 256 + c] = s;
  psq[z * 256 + c] = ss;
}

// pass 2: fold 324 partials per channel
__global__ void k_chan_stats_hwc_final(const float* __restrict__ psum,
                                       const float* __restrict__ psq,
                                       float* __restrict__ mean, float* __restrict__ istd) {
  const int c = threadIdx.x;
  float s = 0.f, ss = 0.f;
  for (int z = 0; z < 324; ++z) { s += psum[z * 256 + c]; ss += psq[z * 256 + c]; }
  float m = s * (1.f / 82944.f);
  float var = ss * (1.f / 82944.f) - m * m;
  mean[c] = m;
  istd[c] = rsqrtf(var + 1e-5f);
}

// ---- PrRoI separable weights + sparse-range metadata ----------------------
__global__ void k_wxy(const float* __restrict__ rois, int ntot, int P,
                      float* __restrict__ Wx, float* __restrict__ Wy,
                      float* __restrict__ area,
                      int* __restrict__ HLO, int* __restrict__ HCNT,
                      int* __restrict__ WLO) {
  int idx = blockIdx.x * blockDim.x + threadIdx.x;
  if (idx >= ntot) return;
  float rx = rois[idx * 4 + 0], ry = rois[idx * 4 + 1];
  float rw = rois[idx * 4 + 2], rh = rois[idx * 4 + 3];
  float x1 = rx * 0.125f, y1 = ry * 0.125f;
  float x2 = (rx + rw) * 0.125f, y2 = (ry + rh) * 0.125f;
  float bw = (x2 - x1) / P, bh = (y2 - y1) / P;
  area[idx] = bw * bh;
  int hlo = max(0, (int)ceilf(y1 - 1.f));
  int hhi = min(35, (int)floorf(y2 + 1.f));
  HLO[idx] = hlo;
  HCNT[idx] = max(0, hhi - hlo + 1);
  for (int q = 0; q < P; ++q) {
    float xlo = x1 + q * bw, ylo = y1 + q * bh;
    WLO[idx * P + q] = min(31, max(0, (int)ceilf(xlo - 1.f)));
    for (int g = 0; g < 36; ++g) {
      float fg = (float)g;
      Wx[(idx * P + q) * 36 + g] = hat_int(xlo + bw - fg) - hat_int(xlo - fg);
      Wy[(idx * P + q) * 36 + g] = hat_int(ylo + bh - fg) - hat_int(ylo - fg);
    }
  }
}

// ---- PrRoI pool from HWC f16 with fused BN+ReLU ---------------------------
// feat: yH [img][1296][256] f16 (raw conv out + bias); thread c applies
// v -> max(v*sc+sh, 0). Reads coalesced across lanes (consecutive channels).
// SPARSE: h restricted to active rows; 5-wide x windows (support <= 5 taps
// for P=5 (bw<=2.5) and P=7 (bw<=1.79); wave-uniform bounds).
template <int P, bool MOD>
__global__ __launch_bounds__(256) void k_pool(
    const f16* __restrict__ feat, const float* __restrict__ Wx,
    const float* __restrict__ Wy, const float* __restrict__ area,
    const int* __restrict__ HLO, const int* __restrict__ HCNT,
    const int* __restrict__ WLO,
    const float* __restrict__ mean, const float* __restrict__ istd,
    const float* __restrict__ g, const float* __restrict__ be,
    const float* __restrict__ mod, f16* __restrict__ outPk, int N) {
  const int s = blockIdx.x, n = blockIdx.y;
  const int idx = s * N + n;
  const int c = threadIdx.x;
  constexpr int KD = P * P * 256;
  __shared__ float sWx[P * 36], sWy[P * 36];
  __shared__ int sWLO[P];
  __shared__ int sH[2];
  for (int i = threadIdx.x; i < P * 36; i += 256) {
    sWx[i] = Wx[(size_t)idx * P * 36 + i];
    sWy[i] = Wy[(size_t)idx * P * 36 + i];
  }
  if (threadIdx.x < P) sWLO[threadIdx.x] = WLO[idx * P + threadIdx.x];
  if (threadIdx.x == 0) { sH[0] = HLO[idx]; sH[1] = HCNT[idx]; }
  __syncthreads();
  const float sc = istd[c] * g[c];
  const float sh = be[c] - mean[c] * sc;
  const f16* f = feat + (size_t)s * 1296 * 256 + c;
  float o[P][P] = {};
  const int hlo = sH[0], hcnt = sH[1];
  for (int hh = 0; hh < hcnt; ++hh) {
    const int h = hlo + hh;
    const f16* rp = f + (size_t)h * 36 * 256;
    float colsum[P];
#pragma unroll
    for (int q = 0; q < P; ++q) {
      const int w0 = sWLO[q];
      const f16* wp = rp + (size_t)w0 * 256;
      float v = 0.f;
#pragma unroll
      for (int j = 0; j < 5; ++j) {
        float x = fmaxf(fmaf((float)wp[j * 256], sc, sh), 0.f);
        v = fmaf(sWx[q * 36 + w0 + j], x, v);
      }
      colsum[q] = v;
    }
#pragma unroll
    for (int p = 0; p < P; ++p) {
      const float wy = sWy[p * 36 + h];
      if (wy != 0.f) {
#pragma unroll
        for (int q = 0; q < P; ++q) o[p][q] = fmaf(wy, colsum[q], o[p][q]);
      }
    }
  }
  float a = area[idx];
  float inv = (a > 0.f) ? 1.f / fmaxf(a, 1e-12f) : 0.f;
  float msc = MOD ? (mod[s * 256 + c] * inv) : inv;
  const int kbase = c * (P * P);
#pragma unroll
  for (int p = 0; p < P; ++p)
#pragma unroll
    for (int q = 0; q < P; ++q)
      outPk[pk_off(idx, kbase + p * P + q, KD)] = (f16)(o[p][q] * msc);
}

// ---- FC BN stats, two-pass deterministic ----------------------------------
__global__ void k_fc_stats_part(const float* __restrict__ y, int M, int Nf, int rpz,
                                float* __restrict__ psum, float* __restrict__ psq) {
  int col = blockIdx.x * 256 + threadIdx.x;
  int z = blockIdx.y;
  if (col >= Nf) return;
  int r0 = z * rpz;
  int r1 = min(M, r0 + rpz);
  float s = 0.f, ss = 0.f;
  for (int m = r0; m < r1; ++m) {
    float v = y[(size_t)m * Nf + col];
    s += v; ss += v * v;
  }
  psum[(size_t)z * Nf + col] = s;
  psq[(size_t)z * Nf + col] = ss;
}

__global__ void k_fc_stats_final(const float* __restrict__ psum, const float* __restrict__ psq,
                                 int nz, int Nf, int M,
                                 float* __restrict__ mean, float* __restrict__ istd) {
  int col = blockIdx.x * 256 + threadIdx.x;
  if (col >= Nf) return;
  float s = 0.f, ss = 0.f;
  for (int z = 0; z < nz; ++z) {
    s += psum[(size_t)z * Nf + col];
    ss += psq[(size_t)z * Nf + col];
  }
  float mu = s / (float)M;
  float var = ss / (float)M - mu * mu;
  mean[col] = mu;
  istd[col] = rsqrtf(var + 1e-5f);
}

// ---- FC BN+ReLU elementwise (fp32 in place) -------------------------------
__global__ void k_fc_bn_relu(float* __restrict__ y, const float* __restrict__ mean,
                             const float* __restrict__ istd, const float* __restrict__ g,
                             const float* __restrict__ be, int total, int Nf) {
  int i = blockIdx.x * 256 + threadIdx.x;
  if (i >= total) return;
  int col = i % Nf;
  float sc = istd[col] * g[col];
  float sh = be[col] - mean[col] * sc;
  y[i] = fmaxf(fmaf(y[i], sc, sh), 0.f);
}

// ---- FC BN+ReLU -> packed f16 (next GEMM's A operand) ---------------------
__global__ void k_fc_bn_relu_pk(const float* __restrict__ y, const float* __restrict__ mean,
                                const float* __restrict__ istd, const float* __restrict__ g,
                                const float* __restrict__ be, f16* __restrict__ xpk,
                                int total, int Nf) {
  int i = blockIdx.x * 256 + threadIdx.x;
  if (i >= total) return;
  int row = i / Nf, col = i - row * Nf;
  float sc = istd[col] * g[col];
  float sh = be[col] - mean[col] * sc;
  float v = fmaxf(fmaf(y[i], sc, sh), 0.f);
  xpk[pk_off(row, col, Nf)] = (f16)v;
}

// ---- IoU head -------------------------------------------------------------
__global__ void k_iou(const float* __restrict__ x, const float* __restrict__ w,
                      const float* __restrict__ b, float* __restrict__ out) {
  const int r = blockIdx.x, tid = threadIdx.x;
  float s = 0.f;
  for (int k = tid; k < 1024; k += 256) s = fmaf(x[(size_t)r * 1024 + k], w[k], s);
  __shared__ float red[256];
  red[tid] = s;
  __syncthreads();
  for (int o = 128; o > 0; o >>= 1) {
    if (tid < o) red[tid] += red[tid + o];
    __syncthreads();
  }
  if (tid == 0) out[r] = red[0] + b[0];
}

// ---------------------------------------------------------------------------
// Workspace layout (float offsets). Total ~46.37M floats = 185.5 MB.
// AH (HWC f16 conv out, 10.62M floats) lives at O_A; PART overlays O_A after
// AH is consumed; fc PSUM/PSQ + packed weights in A's tail.
// ---------------------------------------------------------------------------
static const size_t O_A      = 0;            // AH f16 / PART fp32
static const size_t O_PSUM   = 13000000;     // 65,536 (fc stats)
static const size_t O_PSQ    = 13065536;     // 65,536
static const size_t O_WPK2RT = 16000000;
static const size_t O_WPK2R  = 20000000;
static const size_t O_FT     = 21233664;     // 11,829,248 f16 FT2 / PHPK
static const size_t O_X2PK   = 21233664 + 6422528;
static const size_t O_WC     = 33062912;     //    294,912 conv w packed f16
static const size_t O_WPK1RT = 33357824;     //  6,422,528
static const size_t O_WPK1R  = 39780352;     //  3,276,800
static const size_t O_PRPK   = 43057152;     //    409,600
static const size_t O_Y1     = 43466752;     //  1,048,576
static const size_t O_Y2     = 44515328;     //  1,048,576
static const size_t O_MOD    = 45563904;     //     16,384
static const size_t O_WXR    = 45580288;     //     11,520
static const size_t O_WYR    = 45591808;     //     11,520
static const size_t O_ARR    = 45603328;     //         64
static const size_t O_WXT    = 45603392;     //    258,048
static const size_t O_WYT    = 45861440;     //    258,048
static const size_t O_ART    = 46119488;     //      1,024
static const size_t O_MEAN   = 46120512;     //      1,024
static const size_t O_ISTD   = 46121536;     //      1,024
static const size_t O_X1PK   = 46122560;     //     65,536
static const size_t O_META   = 46188096;     //      9,664 (ints)
static const size_t O_PSC    = 46197760;     //    165,888 (chan-stats partials)

extern "C" void kernel_launch(void* const* d_in, const int* in_sizes, int n_in,
                              void* d_out, int out_size, void* d_ws, size_t ws_size,
                              hipStream_t stream) {
  (void)in_sizes; (void)n_in; (void)out_size; (void)ws_size;
  const float* feat1  = (const float*)d_in[0];
  const float* feat2  = (const float*)d_in[1];
  const float* bb1    = (const float*)d_in[2];
  const float* props  = (const float*)d_in[3];
  const float* w_c1r  = (const float*)d_in[4];
  const float* b_c1r  = (const float*)d_in[5];
  const float* g_c1r  = (const float*)d_in[6];
  const float* be_c1r = (const float*)d_in[7];
  const float* w_c1t  = (const float*)d_in[8];
  const float* b_c1t  = (const float*)d_in[9];
  const float* g_c1t  = (const float*)d_in[10];
  const float* be_c1t = (const float*)d_in[11];
  const float* w_c2t  = (const float*)d_in[12];
  const float* b_c2t  = (const float*)d_in[13];
  const float* g_c2t  = (const float*)d_in[14];
  const float* be_c2t = (const float*)d_in[15];
  const float* w_f1r  = (const float*)d_in[16];
  const float* b_f1r  = (const float*)d_in[17];
  const float* g_f1r  = (const float*)d_in[18];
  const float* be_f1r = (const float*)d_in[19];
  const float* w_f2r  = (const float*)d_in[20];
  const float* b_f2r  = (const float*)d_in[21];
  const float* g_f2r  = (const float*)d_in[22];
  const float* be_f2r = (const float*)d_in[23];
  const float* w_f1rt = (const float*)d_in[24];
  const float* b_f1rt = (const float*)d_in[25];
  const float* g_f1rt = (const float*)d_in[26];
  const float* be_f1rt= (const float*)d_in[27];
  const float* w_f2rt = (const float*)d_in[28];
  const float* b_f2rt = (const float*)d_in[29];
  const float* g_f2rt = (const float*)d_in[30];
  const float* be_f2rt= (const float*)d_in[31];
  const float* w_iou  = (const float*)d_in[32];
  const float* b_iou  = (const float*)d_in[33];

  float* ws    = (float*)d_ws;
  f16*   AH    = (f16*)(ws + O_A);          // HWC f16 conv out
  float* PART  = ws + O_A;                  // overlays AH (after consumed)
  float* PSUM  = ws + O_PSUM;
  float* PSQ   = ws + O_PSQ;
  f16*   WPK2RT= (f16*)(ws + O_WPK2RT);
  f16*   WPK2R = (f16*)(ws + O_WPK2R);
  f16*   FT2   = (f16*)(ws + O_FT);
  f16*   PHPK  = FT2;                       // overlays FT2
  f16*   X2PK  = (f16*)(ws + O_X2PK);
  f16*   WC    = (f16*)(ws + O_WC);
  f16*   WPK1RT= (f16*)(ws + O_WPK1RT);
  f16*   WPK1R = (f16*)(ws + O_WPK1R);
  f16*   PRPK  = (f16*)(ws + O_PRPK);
  float* Y1    = ws + O_Y1;
  float* Y2    = ws + O_Y2;
  float* MODp  = ws + O_MOD;
  float* WXR   = ws + O_WXR;
  float* WYR   = ws + O_WYR;
  float* ARR   = ws + O_ARR;
  float* WXT   = ws + O_WXT;
  float* WYT   = ws + O_WYT;
  float* ART   = ws + O_ART;
  float* MEAN  = ws + O_MEAN;
  float* ISTD  = ws + O_ISTD;
  f16*   X1PK  = (f16*)(ws + O_X1PK);
  int*   META  = (int*)(ws + O_META);
  float* PSUMC = ws + O_PSC;                // 82,944
  float* PSQC  = ws + O_PSC + 82944;        // 82,944
  int* HLOR = META;          // 64
  int* HCNTR= META + 64;     // 64
  int* WLOR = META + 128;    // 320
  int* HLOT = META + 448;    // 1024
  int* HCNTT= META + 1472;   // 1024
  int* WLOT = META + 2496;   // 7168

  // ===== get_modulation branch =====
  k_border<<<64, 256, 0, stream>>>(FT2);
  k_pack_wc<<<2304, 256, 0, stream>>>(w_c1r, WC);
  k_pad<<<dim3(64, 36), 256, 0, stream>>>(feat1, FT2);
  k_conv_mfma<<<1408, 256, 0, stream>>>(WC, FT2, b_c1r, AH);
  k_chan_stats_hwc<<<324, 256, 0, stream>>>(AH, PSUMC, PSQC);
  k_chan_stats_hwc_final<<<1, 256, 0, stream>>>(PSUMC, PSQC, MEAN, ISTD);

  k_wxy<<<1, 64, 0, stream>>>(bb1, 64, 5, WXR, WYR, ARR, HLOR, HCNTR, WLOR);
  k_zero<<<400, 256, 0, stream>>>((float4*)PRPK, 102400);
  k_pool<5, false><<<dim3(64, 1), 256, 0, stream>>>(
      AH, WXR, WYR, ARR, HLOR, HCNTR, WLOR, MEAN, ISTD, g_c1r, be_c1r, nullptr, PRPK, 1);

  k_pack_w<<<25600, 256, 0, stream>>>(w_f1r, WPK1R, 6400, 6553600);
  k_gemm_f16pk<<<dim3(8, 1, 8), 256, 0, stream>>>(PRPK, WPK1R, PART, 6400, 1024, 25, 128);
  k_reduce<<<256, 256, 0, stream>>>(PART, b_f1r, Y1, 128, 64, 1024, 8);
  k_fc_stats_part<<<dim3(4, 8), 256, 0, stream>>>(Y1, 64, 1024, 8, PSUM, PSQ);
  k_fc_stats_final<<<4, 256, 0, stream>>>(PSUM, PSQ, 8, 1024, 64, MEAN, ISTD);
  k_zero<<<64, 256, 0, stream>>>((float4*)X1PK, 16384);
  k_fc_bn_relu_pk<<<256, 256, 0, stream>>>(Y1, MEAN, ISTD, g_f1r, be_f1r, X1PK, 64 * 1024, 1024);

  k_pack_w<<<1024, 256, 0, stream>>>(w_f2r, WPK2R, 1024, 262144);
  k_gemm_f16pk<<<dim3(2, 1, 4), 256, 0, stream>>>(X1PK, WPK2R, PART, 1024, 256, 8, 128);
  k_reduce<<<64, 256, 0, stream>>>(PART, b_f2r, MODp, 128, 64, 256, 4);
  k_fc_stats_part<<<dim3(1, 8), 256, 0, stream>>>(MODp, 64, 256, 8, PSUM, PSQ);
  k_fc_stats_final<<<1, 256, 0, stream>>>(PSUM, PSQ, 8, 256, 64, MEAN, ISTD);
  k_fc_bn_relu<<<64, 256, 0, stream>>>(MODp, MEAN, ISTD, g_f2r, be_f2r, 64 * 256, 256);

  // ===== get_iou_feat branch =====
  k_pack_wc<<<2304, 256, 0, stream>>>(w_c1t, WC);
  k_pad<<<dim3(64, 36), 256, 0, stream>>>(feat2, FT2);
  k_conv_mfma<<<1408, 256, 0, stream>>>(WC, FT2, b_c1t, AH);
  k_chan_stats_hwc<<<324, 256, 0, stream>>>(AH, PSUMC, PSQC);
  k_chan_stats_hwc_final<<<1, 256, 0, stream>>>(PSUMC, PSQC, MEAN, ISTD);
  k_pad2<<<dim3(64, 36), 256, 0, stream>>>(AH, FT2, MEAN, ISTD, g_c1t, be_c1t);

  k_pack_wc<<<2304, 256, 0, stream>>>(w_c2t, WC);
  k_conv_mfma<<<1408, 256, 0, stream>>>(WC, FT2, b_c2t, AH);
  k_chan_stats_hwc<<<324, 256, 0, stream>>>(AH, PSUMC, PSQC);
  k_chan_stats_hwc_final<<<1, 256, 0, stream>>>(PSUMC, PSQC, MEAN, ISTD);

  // ===== predict_iou =====
  k_wxy<<<16, 64, 0, stream>>>(props, 1024, 7, WXT, WYT, ART, HLOT, HCNTT, WLOT);
  k_pool<7, true><<<dim3(64, 16), 256, 0, stream>>>(
      AH, WXT, WYT, ART, HLOT, HCNTT, WLOT, MEAN, ISTD, g_c2t, be_c2t, MODp, PHPK, 16);

  k_pack_w<<<50176, 256, 0, stream>>>(w_f1rt, WPK1RT, 12544, 12845056);
  k_gemm_f16pk<<<dim3(8, 8, 8), 256, 0, stream>>>(PHPK, WPK1RT, PART, 12544, 1024, 49, 1024);
  k_reduce<<<4096, 256, 0, stream>>>(PART, b_f1rt, Y1, 1024, 1024, 1024, 8);
  k_fc_stats_part<<<dim3(4, 64), 256, 0, stream>>>(Y1, 1024, 1024, 16, PSUM, PSQ);
  k_fc_stats_final<<<4, 256, 0, stream>>>(PSUM, PSQ, 64, 1024, 1024, MEAN, ISTD);
  k_fc_bn_relu_pk<<<4096, 256, 0, stream>>>(Y1, MEAN, ISTD, g_f1rt, be_f1rt, X2PK, 1024 * 1024, 1024);

  k_pack_w<<<4096, 256, 0, stream>>>(w_f2rt, WPK2RT, 1024, 1048576);
  k_gemm_f16pk<<<dim3(8, 8, 4), 256, 0, stream>>>(X2PK, WPK2RT, PART, 1024, 1024, 8, 1024);
  k_reduce<<<4096, 256, 0, stream>>>(PART, b_f2rt, Y2, 1024, 1024, 1024, 4);
  k_fc_stats_part<<<dim3(4, 64), 256, 0, stream>>>(Y2, 1024, 1024, 16, PSUM, PSQ);
  k_fc_stats_final<<<4, 256, 0, stream>>>(PSUM, PSQ, 64, 1024, 1024, MEAN, ISTD);
  k_fc_bn_relu<<<4096, 256, 0, stream>>>(Y2, MEAN, ISTD, g_f2rt, be_f2rt, 1024 * 1024, 1024);

  k_iou<<<1024, 256, 0, stream>>>(Y2, w_iou, b_iou, (float*)d_out);
}

// Round 9
// 950.956 us; speedup vs baseline: 7.9202x; 1.1239x over previous
//
#include <hip/hip_runtime.h>
#include <cstddef>

// ---------------------------------------------------------------------------
// FPNIoUNetHR forward — round 9: dense pool writes + tiled LDS transposes
// (kill 64-line scatter stores / gather reads in pool + weight packing).
// S=64, C=256, H=W=36, N=16.
// ---------------------------------------------------------------------------

typedef _Float16 f16;
typedef __attribute__((ext_vector_type(4))) _Float16 f16x4;
typedef __attribute__((ext_vector_type(8))) _Float16 f16x8;
typedef __attribute__((ext_vector_type(4))) float f32x4;

__device__ __forceinline__ void gload16(const void* g, void* l) {
  __builtin_amdgcn_global_load_lds((const __attribute__((address_space(1))) void*)g,
                                   (__attribute__((address_space(3))) void*)l, 16, 0, 0);
}

#define WAITB(N) asm volatile("s_waitcnt vmcnt(" #N ")\n\ts_barrier" ::: "memory")
#define LGKB()   asm volatile("s_waitcnt lgkmcnt(0)\n\ts_barrier" ::: "memory")

static __device__ __forceinline__ float hat_int(float x) {
  float u = fminf(1.f, fmaxf(-1.f, x));
  float a = 0.5f * (1.f + u) * (1.f + u);
  float b = 0.5f + u - 0.5f * u * u;
  return (u <= 0.f) ? a : b;
}

// Packed GEMM operand layout: element (row,k) of a row-major [M][K] matrix ->
// [row/128][k/32][(k/8)%4][row%128][k%8]. One k-step chunk (128 rows x 32 k)
// is 8 KB contiguous, exactly the LDS image the MFMA frag reads want.
static __device__ __forceinline__ size_t pk_off(int row, int k, int K) {
  return (size_t)(row >> 7) * ((size_t)K * 128) + (size_t)(k >> 5) * 4096
       + (size_t)((((k >> 3) & 3) * 128 + (row & 127)) * 8 + (k & 7));
}

// ---- zero helper (float4 granularity) -------------------------------------
__global__ void k_zero(float4* __restrict__ p, int n4) {
  int i = blockIdx.x * 256 + threadIdx.x;
  if (i < n4) p[i] = float4{0.f, 0.f, 0.f, 0.f};
}

// ---- zero the 148 border positions of FT2 per image -----------------------
// FT2 layout: [img][koct(c/8)][1444(38x38)][c%8] f16
__global__ void k_border(f16* __restrict__ FT) {
  const int img = blockIdx.x;
  f16* base = FT + (size_t)img * 32 * 1444 * 8;
  for (int i = threadIdx.x; i < 148 * 256; i += 256) {
    int b = i >> 8, c = i & 255;
    int r, cc;
    if (b < 38)       { r = 0;          cc = b; }
    else if (b < 76)  { r = 37;         cc = b - 38; }
    else if (b < 112) { r = b - 76 + 1; cc = 0; }
    else              { r = b - 112 + 1; cc = 37; }
    base[((size_t)(c >> 3) * 1444 + r * 38 + cc) * 8 + (c & 7)] = (f16)0.f;
  }
}

// ---- pad fp32 CHW input -> FT2 f16 (model inputs feat1/feat2) -------------
__global__ void k_pad(const float* __restrict__ src, f16* __restrict__ FT) {
  const int img = blockIdx.x, h = blockIdx.y, c = threadIdx.x;
  const float* sp = src + ((size_t)img * 256 + c) * 1296 + h * 36;
  f16* op = FT + (((size_t)img * 32 + (c >> 3)) * 1444 + (h + 1) * 38 + 1) * 8 + (c & 7);
#pragma unroll 4
  for (int w = 0; w < 36; ++w) op[w * 8] = (f16)sp[w];
}

// ---- pad HWC f16 conv output + BN+ReLU -> FT2 f16 -------------------------
__global__ void k_pad2(const f16* __restrict__ yH, f16* __restrict__ FT,
                       const float* __restrict__ mean, const float* __restrict__ istd,
                       const float* __restrict__ g, const float* __restrict__ be) {
  const int img = blockIdx.x, h = blockIdx.y, c = threadIdx.x;
  const float sc = istd[c] * g[c];
  const float sh = be[c] - mean[c] * sc;
  const f16* sp = yH + ((size_t)img * 1296 + h * 36) * 256 + c;
  f16* op = FT + (((size_t)img * 32 + (c >> 3)) * 1444 + (h + 1) * 38 + 1) * 8 + (c & 7);
#pragma unroll 4
  for (int w = 0; w < 36; ++w) {
    float v = fmaxf(fmaf((float)sp[w * 256], sc, sh), 0.f);
    op[w * 8] = (f16)v;
  }
}

// ---- conv weights [256][256][3][3] fp32 -> packed f16 ---------------------
// dst: [oct(oc/128)][ks(0..71)][koct(0..3)][row128][kj8], k = t*256 + c
__global__ void k_pack_wc(const float* __restrict__ w, f16* __restrict__ dst) {
  int i = blockIdx.x * 256 + threadIdx.x;   // < 589,824
  int oct = i / 294912;
  int r = i - oct * 294912;
  int ks = r >> 12;
  int r2 = r & 4095;
  int koct = r2 >> 10;
  int r3 = r2 & 1023;
  int row = r3 >> 3, kj = r3 & 7;
  int k = ks * 32 + koct * 8 + kj;
  int t = k >> 8, c = k & 255;
  int oc = oct * 128 + row;
  dst[i] = (f16)w[(oc * 256 + c) * 9 + t];
}

// ---- tiled LDS transpose: row-major [M][K] -> pk layout -------------------
// grid (K/256, ceil(M/128)), 256 threads. Coalesced reads AND writes.
// Rows >= M are skipped on the write side (dst pre-zeroed where needed).
__global__ __launch_bounds__(256) void k_packx_h(
    const f16* __restrict__ src, f16* __restrict__ dst, int M, int K) {
  __shared__ f16 sT[128][264];   // +16B pad
  const int k0 = blockIdx.x * 256, r0 = blockIdx.y * 128;
  const int t = threadIdx.x;
  const int rl = t >> 5, kk = (t & 31) * 8;
  for (int rnd = 0; rnd < 16; ++rnd) {
    const int row_l = rl + rnd * 8;
    const int row = r0 + row_l;
    if (row < M) {
      f16x8 v = *reinterpret_cast<const f16x8*>(src + (size_t)row * K + k0 + kk);
      *reinterpret_cast<f16x8*>(&sT[row_l][kk]) = v;
    }
  }
  __syncthreads();
  const size_t base = (size_t)(r0 >> 7) * ((size_t)K * 128) + (size_t)(k0 >> 5) * 4096;
#pragma unroll
  for (int cs = 0; cs < 8; ++cs) {
#pragma unroll
    for (int half = 0; half < 2; ++half) {
      const int e = half * 256 + t;
      const int koct = e >> 7, row_l = e & 127;
      if (r0 + row_l < M) {
        f16x8 v = *reinterpret_cast<const f16x8*>(&sT[row_l][cs * 32 + koct * 8]);
        *reinterpret_cast<f16x8*>(dst + base + (size_t)cs * 4096 + e * 8) = v;
      }
    }
  }
}

__global__ __launch_bounds__(256) void k_packx_f(
    const float* __restrict__ src, f16* __restrict__ dst, int M, int K) {
  __shared__ f16 sT[128][264];
  const int k0 = blockIdx.x * 256, r0 = blockIdx.y * 128;
  const int t = threadIdx.x;
  const int rl = t >> 5, kk = (t & 31) * 8;
  for (int rnd = 0; rnd < 16; ++rnd) {
    const int row_l = rl + rnd * 8;
    const int row = r0 + row_l;
    if (row < M) {
      const float4* sp = reinterpret_cast<const float4*>(src + (size_t)row * K + k0 + kk);
      float4 a = sp[0], b = sp[1];
      f16* o = &sT[row_l][kk];
      o[0] = (f16)a.x; o[1] = (f16)a.y; o[2] = (f16)a.z; o[3] = (f16)a.w;
      o[4] = (f16)b.x; o[5] = (f16)b.y; o[6] = (f16)b.z; o[7] = (f16)b.w;
    }
  }
  __syncthreads();
  const size_t base = (size_t)(r0 >> 7) * ((size_t)K * 128) + (size_t)(k0 >> 5) * 4096;
#pragma unroll
  for (int cs = 0; cs < 8; ++cs) {
#pragma unroll
    for (int half = 0; half < 2; ++half) {
      const int e = half * 256 + t;
      const int koct = e >> 7, row_l = e & 127;
      if (r0 + row_l < M) {
        f16x8 v = *reinterpret_cast<const f16x8*>(&sT[row_l][cs * 32 + koct * 8]);
        *reinterpret_cast<f16x8*>(dst + base + (size_t)cs * 4096 + e * 8) = v;
      }
    }
  }
}

// ---- 3x3 conv via MFMA implicit GEMM, 3-deep counted-vmcnt pipeline -------
// FT2 [img][32 koct][1444][8] f16, Wpk packed, out yH [img][1296][256] f16.
__global__ __launch_bounds__(256) void k_conv_mfma(
    const f16* __restrict__ Wpk, const f16* __restrict__ FT2,
    const float* __restrict__ bias, f16* __restrict__ yH) {
  __shared__ f16x8 sA[1536];   // 3 buffers x 512 (8 KB each)
  __shared__ f16x8 sB[1536];
  const int bid = blockIdx.x;
  const int orig = (bid & 7) * 176 + (bid >> 3);   // bijective: 1408 % 8 == 0
  const int img = orig / 22;
  const int rem = orig - img * 22;
  const int oct = rem / 11;
  const int pt  = rem - oct * 11;
  const int m0 = oct * 128;
  const int p0 = pt * 128;
  const int tid = threadIdx.x;
  const int lane = tid & 63;
  const int wv = tid >> 6;
  const int wr = wv >> 1, wc = wv & 1;

  const f16* aBase = Wpk + (size_t)oct * 294912 + wv * 1024 + lane * 8;
  const f16* ftImg = FT2 + (size_t)img * 32 * 1444 * 8;
  int pos0 = p0 + lane;
  int pc0 = min(pos0, 1295);
  int pc1 = min(pos0 + 64, 1295);
  int pb0 = (pc0 / 36) * 38 + (pc0 % 36);
  int pb1 = (pc1 / 36) * 38 + (pc1 % 36);

  const int loff = wv * 2048 + lane * 16;

  auto stage = [&](int buf, int ks) {
    const int t = ks >> 3;
    const int dy = t / 3, dx = t - dy * 3;
    const int cs = ks & 7;
    const int dyx = dy * 38 + dx;
    char* lA = (char*)sA + buf * 8192 + loff;
    char* lB = (char*)sB + buf * 8192 + loff;
    const f16* ap = aBase + (size_t)ks * 4096;
    const f16* bp = ftImg + ((size_t)(cs * 4 + wv) * 1444 + dyx) * 8;
    gload16(ap, lA);
    gload16(ap + 512, lA + 1024);
    gload16(bp + pb0 * 8, lB);
    gload16(bp + pb1 * 8, lB + 1024);
  };

  f32x4 acc[4][4] = {};
  const int fidxA = ((lane >> 4) << 7) + wr * 64 + (lane & 15);
  const int fidxB = ((lane >> 4) << 7) + wc * 64 + (lane & 15);

  stage(0, 0); stage(1, 1); stage(2, 2);
  int cur = 0;
  for (int ks = 0; ks < 72; ++ks) {
    const int r = 71 - ks;
    if (r >= 2)      WAITB(8);
    else if (r == 1) WAITB(4);
    else             WAITB(0);
    const int base = cur * 512;
    f16x8 af[4], bf[4];
#pragma unroll
    for (int i = 0; i < 4; ++i) {
      af[i] = sA[base + fidxA + i * 16];
      bf[i] = sB[base + fidxB + i * 16];
    }
#pragma unroll
    for (int i = 0; i < 4; ++i)
#pragma unroll
      for (int j = 0; j < 4; ++j)
        acc[i][j] = __builtin_amdgcn_mfma_f32_16x16x32_f16(af[i], bf[j], acc[i][j], 0, 0, 0);
    LGKB();
    if (ks + 3 < 72) stage(cur, ks + 3);
    cur = (cur == 2) ? 0 : cur + 1;
  }

  const int colb = p0 + wc * 64 + (lane & 15);
  const int rowb = m0 + wr * 64 + ((lane >> 4) << 2);
  f16* yb = yH + (size_t)img * 1296 * 256;
#pragma unroll
  for (int i = 0; i < 4; ++i) {
    const int oc0 = rowb + i * 16;
    float b0 = bias[oc0], b1 = bias[oc0 + 1], b2 = bias[oc0 + 2], b3 = bias[oc0 + 3];
#pragma unroll
    for (int j = 0; j < 4; ++j) {
      const int col = colb + j * 16;
      if (col < 1296) {
        f16x4 v;
        v[0] = (f16)(acc[i][j][0] + b0);
        v[1] = (f16)(acc[i][j][1] + b1);
        v[2] = (f16)(acc[i][j][2] + b2);
        v[3] = (f16)(acc[i][j][3] + b3);
        *reinterpret_cast<f16x4*>(yb + (size_t)col * 256 + oc0) = v;
      }
    }
  }
}

// ---- packed split-K f16 MFMA GEMM, 3-deep counted-vmcnt pipeline ----------
__global__ __launch_bounds__(256) void k_gemm_f16pk(
    const f16* __restrict__ Apk, const f16* __restrict__ Bpk,
    float* __restrict__ part, int K, int Nout, int stepsPerZ, int mrows) {
  __shared__ f16x8 sA[1536];
  __shared__ f16x8 sB[1536];
  const int nt = blockIdx.x, mt = blockIdx.y, z = blockIdx.z;
  const int tid = threadIdx.x;
  const int lane = tid & 63;
  const int wv = tid >> 6;
  const int wr = wv >> 1, wc = wv & 1;

  const f16* aC = Apk + (size_t)mt * K * 128 + wv * 1024 + lane * 8;
  const f16* bC = Bpk + (size_t)nt * K * 128 + wv * 1024 + lane * 8;
  const int loff = wv * 2048 + lane * 16;

  auto stage = [&](int buf, int ks) {
    char* lA = (char*)sA + buf * 8192 + loff;
    char* lB = (char*)sB + buf * 8192 + loff;
    const f16* ap = aC + (size_t)ks * 4096;
    const f16* bp = bC + (size_t)ks * 4096;
    gload16(ap, lA);
    gload16(ap + 512, lA + 1024);
    gload16(bp, lB);
    gload16(bp + 512, lB + 1024);
  };

  f32x4 acc[4][4] = {};
  const int fidxA = ((lane >> 4) << 7) + wr * 64 + (lane & 15);
  const int fidxB = ((lane >> 4) << 7) + wc * 64 + (lane & 15);

  const int ks0 = z * stepsPerZ;
  stage(0, ks0); stage(1, ks0 + 1); stage(2, ks0 + 2);
  int cur = 0;
  for (int i = 0; i < stepsPerZ; ++i) {
    const int r = stepsPerZ - 1 - i;
    if (r >= 2)      WAITB(8);
    else if (r == 1) WAITB(4);
    else             WAITB(0);
    const int base = cur * 512;
    f16x8 af[4], bf[4];
#pragma unroll
    for (int j = 0; j < 4; ++j) {
      af[j] = sA[base + fidxA + j * 16];
      bf[j] = sB[base + fidxB + j * 16];
    }
#pragma unroll
    for (int ii = 0; ii < 4; ++ii)
#pragma unroll
      for (int jj = 0; jj < 4; ++jj)
        acc[ii][jj] = __builtin_amdgcn_mfma_f32_16x16x32_f16(af[ii], bf[jj], acc[ii][jj], 0, 0, 0);
    LGKB();
    if (i + 3 < stepsPerZ) stage(cur, ks0 + i + 3);
    cur = (cur == 2) ? 0 : cur + 1;
  }

  const size_t zoff = (size_t)z * mrows * Nout;
  const int colb = nt * 128 + wc * 64 + (lane & 15);
  const int rowb = mt * 128 + wr * 64 + ((lane >> 4) << 2);
#pragma unroll
  for (int i = 0; i < 4; ++i)
#pragma unroll
    for (int j = 0; j < 4; ++j)
#pragma unroll
      for (int r = 0; r < 4; ++r)
        part[zoff + (size_t)(rowb + i * 16 + r) * Nout + colb + j * 16] = acc[i][j][r];
}

// ---- reduce split-K partials + bias ---------------------------------------
__global__ void k_reduce(const float* __restrict__ part, const float* __restrict__ bias,
                         float* __restrict__ out, int mrows, int Mout, int Nout, int sk) {
  int i = blockIdx.x * 256 + threadIdx.x;
  if (i >= Mout * Nout) return;
  int row = i / Nout, col = i - row * Nout;
  float s = bias[col];
  for (int z = 0; z < sk; ++z)
    s += part[(size_t)z * mrows * Nout + (size_t)row * Nout + col];
  out[i] = s;
}

// ---- conv BN stats from HWC f16, two-pass ---------------------------------
__global__ void k_chan_stats_hwc(const f16* __restrict__ yH,
                                 float* __restrict__ psum, float* __restrict__ psq) {
  const int z = blockIdx.x, c = threadIdx.x;
  const f16* p = yH + (size_t)z * 256 * 256 + c;
  float s = 0.f, ss = 0.f;
#pragma unroll 4
  for (int i = 0; i < 256; ++i) {
    float v = (float)p[(size_t)i * 256];
    s += v; ss += v * v;
  }
  psum[z * 256 + c] = s;
  psq[z * 256 + c] = ss;
}

__global__ void k_chan_stats_hwc_final(const float* __restrict__ psum,
                                       const float* __restrict__ psq,
                                       float* __restrict__ mean, float* __restrict__ istd) {
  const int c = threadIdx.x;
  float s = 0.f, ss = 0.f;
  for (int z = 0; z < 324; ++z) { s += psum[z * 256 + c]; ss += psq[z * 256 + c]; }
  float m = s * (1.f / 82944.f);
  float var = ss * (1.f / 82944.f) - m * m;
  mean[c] = m;
  istd[c] = rsqrtf(var + 1e-5f);
}

// ---- PrRoI separable weights + sparse-range metadata ----------------------
__global__ void k_wxy(const float* __restrict__ rois, int ntot, int P,
                      float* __restrict__ Wx, float* __restrict__ Wy,
                      float* __restrict__ area,
                      int* __restrict__ HLO, int* __restrict__ HCNT,
                      int* __restrict__ WLO) {
  int idx = blockIdx.x * blockDim.x + threadIdx.x;
  if (idx >= ntot) return;
  float rx = rois[idx * 4 + 0], ry = rois[idx * 4 + 1];
  float rw = rois[idx * 4 + 2], rh = rois[idx * 4 + 3];
  float x1 = rx * 0.125f, y1 = ry * 0.125f;
  float x2 = (rx + rw) * 0.125f, y2 = (ry + rh) * 0.125f;
  float bw = (x2 - x1) / P, bh = (y2 - y1) / P;
  area[idx] = bw * bh;
  int hlo = max(0, (int)ceilf(y1 - 1.f));
  int hhi = min(35, (int)floorf(y2 + 1.f));
  HLO[idx] = hlo;
  HCNT[idx] = max(0, hhi - hlo + 1);
  for (int q = 0; q < P; ++q) {
    float xlo = x1 + q * bw, ylo = y1 + q * bh;
    WLO[idx * P + q] = min(31, max(0, (int)ceilf(xlo - 1.f)));
    for (int g = 0; g < 36; ++g) {
      float fg = (float)g;
      Wx[(idx * P + q) * 36 + g] = hat_int(xlo + bw - fg) - hat_int(xlo - fg);
      Wy[(idx * P + q) * 36 + g] = hat_int(ylo + bh - fg) - hat_int(ylo - fg);
    }
  }
}

// ---- PrRoI pool from HWC f16 with fused BN+ReLU, DENSE row-major output ---
// feat: yH [img][1296][256] f16 (raw conv out + bias); thread c applies
// v -> max(v*sc+sh, 0). Output: out[idx][P*P*256] row-major (k = c*P*P+p*P+q),
// staged through LDS so global writes are fully coalesced.
template <int P, bool MOD>
__global__ __launch_bounds__(256) void k_pool(
    const f16* __restrict__ feat, const float* __restrict__ Wx,
    const float* __restrict__ Wy, const float* __restrict__ area,
    const int* __restrict__ HLO, const int* __restrict__ HCNT,
    const int* __restrict__ WLO,
    const float* __restrict__ mean, const float* __restrict__ istd,
    const float* __restrict__ g, const float* __restrict__ be,
    const float* __restrict__ mod, f16* __restrict__ out, int N) {
  const int s = blockIdx.x, n = blockIdx.y;
  const int idx = s * N + n;
  const int c = threadIdx.x;
  constexpr int KD = P * P * 256;
  __shared__ f16 sOut[KD];
  __shared__ float sWx[P * 36], sWy[P * 36];
  __shared__ int sWLO[P];
  __shared__ int sH[2];
  for (int i = threadIdx.x; i < P * 36; i += 256) {
    sWx[i] = Wx[(size_t)idx * P * 36 + i];
    sWy[i] = Wy[(size_t)idx * P * 36 + i];
  }
  if (threadIdx.x < P) sWLO[threadIdx.x] = WLO[idx * P + threadIdx.x];
  if (threadIdx.x == 0) { sH[0] = HLO[idx]; sH[1] = HCNT[idx]; }
  __syncthreads();
  const float sc = istd[c] * g[c];
  const float sh = be[c] - mean[c] * sc;
  const f16* f = feat + (size_t)s * 1296 * 256 + c;
  float o[P][P] = {};
  const int hlo = sH[0], hcnt = sH[1];
  for (int hh = 0; hh < hcnt; ++hh) {
    const int h = hlo + hh;
    const f16* rp = f + (size_t)h * 36 * 256;
    float colsum[P];
#pragma unroll
    for (int q = 0; q < P; ++q) {
      const int w0 = sWLO[q];
      const f16* wp = rp + (size_t)w0 * 256;
      float v = 0.f;
#pragma unroll
      for (int j = 0; j < 5; ++j) {
        float x = fmaxf(fmaf((float)wp[j * 256], sc, sh), 0.f);
        v = fmaf(sWx[q * 36 + w0 + j], x, v);
      }
      colsum[q] = v;
    }
#pragma unroll
    for (int p = 0; p < P; ++p) {
      const float wy = sWy[p * 36 + h];
      if (wy != 0.f) {
#pragma unroll
        for (int q = 0; q < P; ++q) o[p][q] = fmaf(wy, colsum[q], o[p][q]);
      }
    }
  }
  float a = area[idx];
  float inv = (a > 0.f) ? 1.f / fmaxf(a, 1e-12f) : 0.f;
  float msc = MOD ? (mod[s * 256 + c] * inv) : inv;
  const int kbase = c * (P * P);
#pragma unroll
  for (int p = 0; p < P; ++p)
#pragma unroll
    for (int q = 0; q < P; ++q)
      sOut[kbase + p * P + q] = (f16)(o[p][q] * msc);
  __syncthreads();
  f16* op = out + (size_t)idx * KD;
  for (int j = threadIdx.x; j < KD; j += 256) op[j] = sOut[j];
}

// ---- FC BN stats, two-pass deterministic ----------------------------------
__global__ void k_fc_stats_part(const float* __restrict__ y, int M, int Nf, int rpz,
                                float* __restrict__ psum, float* __restrict__ psq) {
  int col = blockIdx.x * 256 + threadIdx.x;
  int z = blockIdx.y;
  if (col >= Nf) return;
  int r0 = z * rpz;
  int r1 = min(M, r0 + rpz);
  float s = 0.f, ss = 0.f;
  for (int m = r0; m < r1; ++m) {
    float v = y[(size_t)m * Nf + col];
    s += v; ss += v * v;
  }
  psum[(size_t)z * Nf + col] = s;
  psq[(size_t)z * Nf + col] = ss;
}

__global__ void k_fc_stats_final(const float* __restrict__ psum, const float* __restrict__ psq,
                                 int nz, int Nf, int M,
                                 float* __restrict__ mean, float* __restrict__ istd) {
  int col = blockIdx.x * 256 + threadIdx.x;
  if (col >= Nf) return;
  float s = 0.f, ss = 0.f;
  for (int z = 0; z < nz; ++z) {
    s += psum[(size_t)z * Nf + col];
    ss += psq[(size_t)z * Nf + col];
  }
  float mu = s / (float)M;
  float var = ss / (float)M - mu * mu;
  mean[col] = mu;
  istd[col] = rsqrtf(var + 1e-5f);
}

// ---- FC BN+ReLU elementwise (fp32 in place) -------------------------------
__global__ void k_fc_bn_relu(float* __restrict__ y, const float* __restrict__ mean,
                             const float* __restrict__ istd, const float* __restrict__ g,
                             const float* __restrict__ be, int total, int Nf) {
  int i = blockIdx.x * 256 + threadIdx.x;
  if (i >= total) return;
  int col = i % Nf;
  float sc = istd[col] * g[col];
  float sh = be[col] - mean[col] * sc;
  y[i] = fmaxf(fmaf(y[i], sc, sh), 0.f);
}

// ---- FC BN+ReLU -> packed f16 (next GEMM's A operand) ---------------------
__global__ void k_fc_bn_relu_pk(const float* __restrict__ y, const float* __restrict__ mean,
                                const float* __restrict__ istd, const float* __restrict__ g,
                                const float* __restrict__ be, f16* __restrict__ xpk,
                                int total, int Nf) {
  int i = blockIdx.x * 256 + threadIdx.x;
  if (i >= total) return;
  int row = i / Nf, col = i - row * Nf;
  float sc = istd[col] * g[col];
  float sh = be[col] - mean[col] * sc;
  float v = fmaxf(fmaf(y[i], sc, sh), 0.f);
  xpk[pk_off(row, col, Nf)] = (f16)v;
}

// ---- IoU head -------------------------------------------------------------
__global__ void k_iou(const float* __restrict__ x, const float* __restrict__ w,
                      const float* __restrict__ b, float* __restrict__ out) {
  const int r = blockIdx.x, tid = threadIdx.x;
  float s = 0.f;
  for (int k = tid; k < 1024; k += 256) s = fmaf(x[(size_t)r * 1024 + k], w[k], s);
  __shared__ float red[256];
  red[tid] = s;
  __syncthreads();
  for (int o = 128; o > 0; o >>= 1) {
    if (tid < o) red[tid] += red[tid + o];
    __syncthreads();
  }
  if (tid == 0) out[r] = red[0] + b[0];
}

// ---------------------------------------------------------------------------
// Workspace layout (float offsets). Total ~46.37M floats = 185.5 MB.
// A region lifetimes: AH (conv HWC out) 0..10.62M; POOLT (12M..18.42M) live
// only pool_t->packx (PSUM/PSQ/WPK2RT in that range are used strictly later);
// POOLR at 18.5M live only pool_r->packx; PART overlays 0.. after AH dies.
// ---------------------------------------------------------------------------
static const size_t O_A      = 0;
static const size_t O_POOLT  = 12000000;     // f16 [1024][12544] (6.42M fl)
static const size_t O_PSUM   = 13000000;     // fc stats (time-disjoint w/ POOLT)
static const size_t O_PSQ    = 13065536;
static const size_t O_WPK2RT = 16000000;
static const size_t O_POOLR  = 18500000;     // f16 [64][6400] (205K fl)
static const size_t O_WPK2R  = 20000000;
static const size_t O_FT     = 21233664;     // 11,829,248 f16 FT2 / PHPK
static const size_t O_X2PK   = 21233664 + 6422528;
static const size_t O_WC     = 33062912;
static const size_t O_WPK1RT = 33357824;
static const size_t O_WPK1R  = 39780352;
static const size_t O_PRPK   = 43057152;
static const size_t O_Y1     = 43466752;
static const size_t O_Y2     = 44515328;
static const size_t O_MOD    = 45563904;
static const size_t O_WXR    = 45580288;
static const size_t O_WYR    = 45591808;
static const size_t O_ARR    = 45603328;
static const size_t O_WXT    = 45603392;
static const size_t O_WYT    = 45861440;
static const size_t O_ART    = 46119488;
static const size_t O_MEAN   = 46120512;
static const size_t O_ISTD   = 46121536;
static const size_t O_X1PK   = 46122560;
static const size_t O_META   = 46188096;
static const size_t O_PSC    = 46197760;     // 165,888 (chan-stats partials)

extern "C" void kernel_launch(void* const* d_in, const int* in_sizes, int n_in,
                              void* d_out, int out_size, void* d_ws, size_t ws_size,
                              hipStream_t stream) {
  (void)in_sizes; (void)n_in; (void)out_size; (void)ws_size;
  const float* feat1  = (const float*)d_in[0];
  const float* feat2  = (const float*)d_in[1];
  const float* bb1    = (const float*)d_in[2];
  const float* props  = (const float*)d_in[3];
  const float* w_c1r  = (const float*)d_in[4];
  const float* b_c1r  = (const float*)d_in[5];
  const float* g_c1r  = (const float*)d_in[6];
  const float* be_c1r = (const float*)d_in[7];
  const float* w_c1t  = (const float*)d_in[8];
  const float* b_c1t  = (const float*)d_in[9];
  const float* g_c1t  = (const float*)d_in[10];
  const float* be_c1t = (const float*)d_in[11];
  const float* w_c2t  = (const float*)d_in[12];
  const float* b_c2t  = (const float*)d_in[13];
  const float* g_c2t  = (const float*)d_in[14];
  const float* be_c2t = (const float*)d_in[15];
  const float* w_f1r  = (const float*)d_in[16];
  const float* b_f1r  = (const float*)d_in[17];
  const float* g_f1r  = (const float*)d_in[18];
  const float* be_f1r = (const float*)d_in[19];
  const float* w_f2r  = (const float*)d_in[20];
  const float* b_f2r  = (const float*)d_in[21];
  const float* g_f2r  = (const float*)d_in[22];
  const float* be_f2r = (const float*)d_in[23];
  const float* w_f1rt = (const float*)d_in[24];
  const float* b_f1rt = (const float*)d_in[25];
  const float* g_f1rt = (const float*)d_in[26];
  const float* be_f1rt= (const float*)d_in[27];
  const float* w_f2rt = (const float*)d_in[28];
  const float* b_f2rt = (const float*)d_in[29];
  const float* g_f2rt = (const float*)d_in[30];
  const float* be_f2rt= (const float*)d_in[31];
  const float* w_iou  = (const float*)d_in[32];
  const float* b_iou  = (const float*)d_in[33];

  float* ws    = (float*)d_ws;
  f16*   AH    = (f16*)(ws + O_A);
  float* PART  = ws + O_A;
  f16*   POOLT = (f16*)(ws + O_POOLT);
  float* PSUM  = ws + O_PSUM;
  float* PSQ   = ws + O_PSQ;
  f16*   WPK2RT= (f16*)(ws + O_WPK2RT);
  f16*   POOLR = (f16*)(ws + O_POOLR);
  f16*   WPK2R = (f16*)(ws + O_WPK2R);
  f16*   FT2   = (f16*)(ws + O_FT);
  f16*   PHPK  = FT2;
  f16*   X2PK  = (f16*)(ws + O_X2PK);
  f16*   WC    = (f16*)(ws + O_WC);
  f16*   WPK1RT= (f16*)(ws + O_WPK1RT);
  f16*   WPK1R = (f16*)(ws + O_WPK1R);
  f16*   PRPK  = (f16*)(ws + O_PRPK);
  float* Y1    = ws + O_Y1;
  float* Y2    = ws + O_Y2;
  float* MODp  = ws + O_MOD;
  float* WXR   = ws + O_WXR;
  float* WYR   = ws + O_WYR;
  float* ARR   = ws + O_ARR;
  float* WXT   = ws + O_WXT;
  float* WYT   = ws + O_WYT;
  float* ART   = ws + O_ART;
  float* MEAN  = ws + O_MEAN;
  float* ISTD  = ws + O_ISTD;
  f16*   X1PK  = (f16*)(ws + O_X1PK);
  int*   META  = (int*)(ws + O_META);
  float* PSUMC = ws + O_PSC;
  float* PSQC  = ws + O_PSC + 82944;
  int* HLOR = META;
  int* HCNTR= META + 64;
  int* WLOR = META + 128;
  int* HLOT = META + 448;
  int* HCNTT= META + 1472;
  int* WLOT = META + 2496;

  // ===== get_modulation branch =====
  k_border<<<64, 256, 0, stream>>>(FT2);
  k_pack_wc<<<2304, 256, 0, stream>>>(w_c1r, WC);
  k_pad<<<dim3(64, 36), 256, 0, stream>>>(feat1, FT2);
  k_conv_mfma<<<1408, 256, 0, stream>>>(WC, FT2, b_c1r, AH);
  k_chan_stats_hwc<<<324, 256, 0, stream>>>(AH, PSUMC, PSQC);
  k_chan_stats_hwc_final<<<1, 256, 0, stream>>>(PSUMC, PSQC, MEAN, ISTD);

  k_wxy<<<1, 64, 0, stream>>>(bb1, 64, 5, WXR, WYR, ARR, HLOR, HCNTR, WLOR);
  k_zero<<<400, 256, 0, stream>>>((float4*)PRPK, 102400);
  k_pool<5, false><<<dim3(64, 1), 256, 0, stream>>>(
      AH, WXR, WYR, ARR, HLOR, HCNTR, WLOR, MEAN, ISTD, g_c1r, be_c1r, nullptr, POOLR, 1);
  k_packx_h<<<dim3(25, 1), 256, 0, stream>>>(POOLR, PRPK, 64, 6400);

  k_packx_f<<<dim3(25, 8), 256, 0, stream>>>(w_f1r, WPK1R, 1024, 6400);
  k_gemm_f16pk<<<dim3(8, 1, 8), 256, 0, stream>>>(PRPK, WPK1R, PART, 6400, 1024, 25, 128);
  k_reduce<<<256, 256, 0, stream>>>(PART, b_f1r, Y1, 128, 64, 1024, 8);
  k_fc_stats_part<<<dim3(4, 8), 256, 0, stream>>>(Y1, 64, 1024, 8, PSUM, PSQ);
  k_fc_stats_final<<<4, 256, 0, stream>>>(PSUM, PSQ, 8, 1024, 64, MEAN, ISTD);
  k_zero<<<64, 256, 0, stream>>>((float4*)X1PK, 16384);
  k_fc_bn_relu_pk<<<256, 256, 0, stream>>>(Y1, MEAN, ISTD, g_f1r, be_f1r, X1PK, 64 * 1024, 1024);

  k_packx_f<<<dim3(4, 2), 256, 0, stream>>>(w_f2r, WPK2R, 256, 1024);
  k_gemm_f16pk<<<dim3(2, 1, 4), 256, 0, stream>>>(X1PK, WPK2R, PART, 1024, 256, 8, 128);
  k_reduce<<<64, 256, 0, stream>>>(PART, b_f2r, MODp, 128, 64, 256, 4);
  k_fc_stats_part<<<dim3(1, 8), 256, 0, stream>>>(MODp, 64, 256, 8, PSUM, PSQ);
  k_fc_stats_final<<<1, 256, 0, stream>>>(PSUM, PSQ, 8, 256, 64, MEAN, ISTD);
  k_fc_bn_relu<<<64, 256, 0, stream>>>(MODp, MEAN, ISTD, g_f2r, be_f2r, 64 * 256, 256);

  // ===== get_iou_feat branch =====
  k_pack_wc<<<2304, 256, 0, stream>>>(w_c1t, WC);
  k_pad<<<dim3(64, 36), 256, 0, stream>>>(feat2, FT2);
  k_conv_mfma<<<1408, 256, 0, stream>>>(WC, FT2, b_c1t, AH);
  k_chan_stats_hwc<<<324, 256, 0, stream>>>(AH, PSUMC, PSQC);
  k_chan_stats_hwc_final<<<1, 256, 0, stream>>>(PSUMC, PSQC, MEAN, ISTD);
  k_pad2<<<dim3(64, 36), 256, 0, stream>>>(AH, FT2, MEAN, ISTD, g_c1t, be_c1t);

  k_pack_wc<<<2304, 256, 0, stream>>>(w_c2t, WC);
  k_conv_mfma<<<1408, 256, 0, stream>>>(WC, FT2, b_c2t, AH);
  k_chan_stats_hwc<<<324, 256, 0, stream>>>(AH, PSUMC, PSQC);
  k_chan_stats_hwc_final<<<1, 256, 0, stream>>>(PSUMC, PSQC, MEAN, ISTD);

  // ===== predict_iou =====
  k_wxy<<<16, 64, 0, stream>>>(props, 1024, 7, WXT, WYT, ART, HLOT, HCNTT, WLOT);
  k_pool<7, true><<<dim3(64, 16), 256, 0, stream>>>(
      AH, WXT, WYT, ART, HLOT, HCNTT, WLOT, MEAN, ISTD, g_c2t, be_c2t, MODp, POOLT, 16);
  k_packx_h<<<dim3(49, 8), 256, 0, stream>>>(POOLT, PHPK, 1024, 12544);

  k_packx_f<<<dim3(49, 8), 256, 0, stream>>>(w_f1rt, WPK1RT, 1024, 12544);
  k_gemm_f16pk<<<dim3(8, 8, 8), 256, 0, stream>>>(PHPK, WPK1RT, PART, 12544, 1024, 49, 1024);
  k_reduce<<<4096, 256, 0, stream>>>(PART, b_f1rt, Y1, 1024, 1024, 1024, 8);
  k_fc_stats_part<<<dim3(4, 64), 256, 0, stream>>>(Y1, 1024, 1024, 16, PSUM, PSQ);
  k_fc_stats_final<<<4, 256, 0, stream>>>(PSUM, PSQ, 64, 1024, 1024, MEAN, ISTD);
  k_fc_bn_relu_pk<<<4096, 256, 0, stream>>>(Y1, MEAN, ISTD, g_f1rt, be_f1rt, X2PK, 1024 * 1024, 1024);

  k_packx_f<<<dim3(4, 8), 256, 0, stream>>>(w_f2rt, WPK2RT, 1024, 1024);
  k_gemm_f16pk<<<dim3(8, 8, 4), 256, 0, stream>>>(X2PK, WPK2RT, PART, 1024, 1024, 8, 1024);
  k_reduce<<<4096, 256, 0, stream>>>(PART, b_f2rt, Y2, 1024, 1024, 1024, 4);
  k_fc_stats_part<<<dim3(4, 64), 256, 0, stream>>>(Y2, 1024, 1024, 16, PSUM, PSQ);
  k_fc_stats_final<<<4, 256, 0, stream>>>(PSUM, PSQ, 64, 1024, 1024, MEAN, ISTD);
  k_fc_bn_relu<<<4096, 256, 0, stream>>>(Y2, MEAN, ISTD, g_f2rt, be_f2rt, 1024 * 1024, 1024);

  k_iou<<<1024, 256, 0, stream>>>(Y2, w_iou, b_iou, (float*)d_out);
}